// Round 7
// baseline (1914.818 us; speedup 1.0000x reference)
//
#include <hip/hip_runtime.h>
#include <hip/hip_bf16.h>

// Problem constants (from reference)
#define NN 50000
#define EE 800000
#define GG 128
#define LL 4
#define TT 4
#define FF 20
#define DD 80
#define SCAN_B ((NN + 1023) / 1024)   // 49
#define TILE_N 32                     // nodes per k_preagg block (avg 512 slots)
static constexpr float AVG_LOG = 2.8332133440562162f; // ln(17)

typedef __fp16 half2v __attribute__((ext_vector_type(2)));

__device__ __forceinline__ float bf2f(unsigned short u) {
  return __uint_as_float((unsigned)u << 16);
}
__device__ __forceinline__ unsigned short f2bf(float f) {
  __hip_bfloat16 b = __float2bfloat16(f); // RNE
  return *(unsigned short*)&b;
}
__device__ __forceinline__ half2v pkrtz(float a, float b) {
#if __has_builtin(__builtin_amdgcn_cvt_pkrtz)
  return __builtin_amdgcn_cvt_pkrtz(a, b);
#else
  half2v h; h.x = (__fp16)a; h.y = (__fp16)b; return h;
#endif
}
__device__ __forceinline__ float fdot2(half2v a, half2v b, float c) {
#if __has_builtin(__builtin_amdgcn_fdot2)
  return __builtin_amdgcn_fdot2(a, b, c, false);
#else
  return fmaf((float)a.x, (float)b.x, fmaf((float)a.y, (float)b.y, c));
#endif
}
__device__ __forceinline__ half2v u2h2(unsigned int u) {
  return __builtin_bit_cast(half2v, u);
}
__device__ __forceinline__ unsigned int h22u(half2v h) {
  return __builtin_bit_cast(unsigned int, h);
}
__device__ __forceinline__ unsigned int packh2_rne(float a, float b) {
  half2v h; h.x = (__fp16)a; h.y = (__fp16)b; // RNE casts for weights
  return h22u(h);
}
__device__ __forceinline__ unsigned int pack_bf16(float a, float b) {
  return (unsigned int)f2bf(a) | ((unsigned int)f2bf(b) << 16);
}

// ---------------- h init: h[n,d] = sum_i atom_emb[i, x[n,i], d] ----------------
__global__ __launch_bounds__(256) void k_h(const int* __restrict__ x,
                                           const float* __restrict__ atom_emb,
                                           float* __restrict__ h) {
  int idx = blockIdx.x * 256 + threadIdx.x;
  if (idx >= NN * DD) return;
  int n = idx / DD, d = idx - n * DD;
  const int* xr = x + n * 9;
  float acc = 0.f;
#pragma unroll
  for (int i = 0; i < 9; ++i) {
    int v = xr[i];
    acc += atom_emb[(i * 16 + v) * DD + d];
  }
  h[idx] = acc;
}

// ---------------- degree count ----------------
__global__ __launch_bounds__(256) void k_deg(const int* __restrict__ ei, int* __restrict__ cnt) {
  int e = blockIdx.x * 256 + threadIdx.x;
  if (e >= EE) return;
  atomicAdd(&cnt[ei[EE + e]], 1); // dst = edge_index[1][e]
}

// ---------------- hierarchical exclusive scan ----------------
__global__ __launch_bounds__(1024) void k_scan_sum(const int* __restrict__ cnt, int* __restrict__ bsum) {
  __shared__ int red[1024];
  int tid = threadIdx.x;
  int i = blockIdx.x * 1024 + tid;
  red[tid] = (i < NN) ? cnt[i] : 0;
  __syncthreads();
  for (int off = 512; off > 0; off >>= 1) {
    if (tid < off) red[tid] += red[tid + off];
    __syncthreads();
  }
  if (tid == 0) bsum[blockIdx.x] = red[0];
}

__global__ void k_scan_top(const int* __restrict__ bsum, int* __restrict__ boff,
                           int* __restrict__ row_ptr) {
  if (threadIdx.x == 0 && blockIdx.x == 0) {
    int acc = 0;
    for (int b = 0; b < SCAN_B; ++b) { boff[b] = acc; acc += bsum[b]; }
    row_ptr[NN] = acc;
  }
}

__global__ __launch_bounds__(1024) void k_scan_apply(const int* __restrict__ cnt,
                                                     const int* __restrict__ boff,
                                                     int* __restrict__ row_ptr,
                                                     int* __restrict__ cursor) {
  __shared__ int sm[1024];
  int tid = threadIdx.x;
  int i = blockIdx.x * 1024 + tid;
  int v = (i < NN) ? cnt[i] : 0;
  sm[tid] = v;
  __syncthreads();
  for (int off = 1; off < 1024; off <<= 1) {
    int t = (tid >= off) ? sm[tid - off] : 0;
    __syncthreads();
    sm[tid] += t;
    __syncthreads();
  }
  int excl = boff[blockIdx.x] + sm[tid] - v;
  if (i < NN) { row_ptr[i] = excl; cursor[i] = excl; }
}

// ---------------- CSR fill: slot -> src / eid / dst (split arrays) ----------------
__global__ __launch_bounds__(256) void k_csrfill(const int* __restrict__ ei,
                                                 int* __restrict__ cursor,
                                                 int* __restrict__ csr_src,
                                                 int* __restrict__ csr_eid,
                                                 int* __restrict__ csr_dst) {
  int e = blockIdx.x * 256 + threadIdx.x;
  if (e >= EE) return;
  int dst = ei[EE + e];
  int slot = atomicAdd(&cursor[dst], 1);
  csr_src[slot] = ei[e];
  csr_eid[slot] = e;
  csr_dst[slot] = dst;
}

// ---------------- one-time edge_attr gather into CSR slot order, f16 pairs ----------------
__global__ __launch_bounds__(256) void k_eagather(const int* __restrict__ csr_eid,
                                                  const float* __restrict__ edge_attr,
                                                  unsigned int* __restrict__ ea16) {
  int sl = blockIdx.x * 256 + threadIdx.x;
  if (sl >= EE) return;
  int e = csr_eid[sl];
  const float4* ap = (const float4*)(edge_attr + (size_t)e * 16);
  uint4 o0, o1;
  float4 v0 = ap[0], v1 = ap[1], v2 = ap[2], v3 = ap[3];
  o0.x = packh2_rne(v0.x, v0.y); o0.y = packh2_rne(v0.z, v0.w);
  o0.z = packh2_rne(v1.x, v1.y); o0.w = packh2_rne(v1.z, v1.w);
  o1.x = packh2_rne(v2.x, v2.y); o1.y = packh2_rne(v2.z, v2.w);
  o1.z = packh2_rne(v3.x, v3.y); o1.w = packh2_rne(v3.z, v3.w);
  uint4* op = (uint4*)(ea16 + (size_t)sl * 8);
  op[0] = o0; op[1] = o1;
}

// ---------------- per-node params ----------------
__global__ __launch_bounds__(256) void k_nodeparams(const int* __restrict__ cnt,
                                                    float* __restrict__ inv_deg,
                                                    float* __restrict__ s1a,
                                                    float* __restrict__ s2a) {
  int n = blockIdx.x * 256 + threadIdx.x;
  if (n >= NN) return;
  int c = cnt[n];
  float deg = (c > 0) ? (float)c : 1.0f;
  inv_deg[n] = 1.0f / deg;
  float logd = logf(deg + 1.0f);
  s1a[n] = logd / AVG_LOG;
  s2a[n] = AVG_LOG / logd;
}

// ---------------- per-layer weight composition + f16 pair packing ----------------
__global__ __launch_bounds__(64) void k_wcomb(const float* __restrict__ edge_w,
                                              const float* __restrict__ edge_b,
                                              const float* __restrict__ pre_w1,
                                              const float* __restrict__ pre_b1,
                                              const float* __restrict__ pre_w2,
                                              unsigned int* __restrict__ wcpk,
                                              unsigned int* __restrict__ w2pk,
                                              float* __restrict__ biasc, int l) {
  int t = blockIdx.x;
  int wt = l * TT + t;
  const float* W1 = pre_w1 + (size_t)wt * 1200; // [60][20]
  const float* W2 = pre_w2 + (size_t)wt * 400;  // [20][20]
  const float* ew = edge_w + (size_t)l * 16 * FF;
  const float* eb = edge_b + (size_t)l * FF;
  int j = threadIdx.x;
  if (j >= FF) return;
  float col[16];
  for (int i = 0; i < 16; ++i) {
    float acc = 0.f;
#pragma unroll
    for (int f = 0; f < FF; ++f) acc = fmaf(ew[i * FF + f], W1[(40 + f) * FF + j], acc);
    col[i] = acc;
  }
#pragma unroll
  for (int i2 = 0; i2 < 8; ++i2)
    wcpk[((size_t)t * FF + j) * 8 + i2] = packh2_rne(col[2 * i2], col[2 * i2 + 1]);
#pragma unroll
  for (int i2 = 0; i2 < 10; ++i2)
    w2pk[((size_t)t * FF + j) * 10 + i2] = packh2_rne(W2[(2 * i2) * FF + j], W2[(2 * i2 + 1) * FF + j]);
  float b = pre_b1[wt * FF + j];
#pragma unroll
  for (int f = 0; f < FF; ++f) b = fmaf(eb[f], W1[(40 + f) * FF + j], b);
  biasc[t * FF + j] = b;
}

// ---------------- post-MLP weight packing: Q1 rows [20,260) + Q2 as f16 pairs ----------------
__global__ __launch_bounds__(64) void k_postpk(const float* __restrict__ post_w1,
                                               const float* __restrict__ post_w2,
                                               unsigned int* __restrict__ q1pk,
                                               unsigned int* __restrict__ q2pk, int l) {
  int t = blockIdx.x;
  int wt = l * TT + t;
  const float* Q1 = post_w1 + (size_t)wt * 5200;
  const float* Q2 = post_w2 + (size_t)wt * 400;
  int j = threadIdx.x;
  if (j >= FF) return;
  for (int i2 = 0; i2 < 120; ++i2) {
    int blk = i2 / 40, k = i2 - blk * 40;
    int r0 = 20 + 80 * blk + 2 * k;
    q1pk[((size_t)t * 120 + i2) * FF + j] = packh2_rne(Q1[r0 * FF + j], Q1[(r0 + 1) * FF + j]);
  }
#pragma unroll
  for (int i2 = 0; i2 < 10; ++i2)
    q2pk[((size_t)t * 10 + i2) * FF + j] = packh2_rne(Q2[(2 * i2) * FF + j], Q2[(2 * i2 + 1) * FF + j]);
}

// ---------------- per-node pre contributions (bf16 out) ----------------
__global__ __launch_bounds__(256) void k_prenode(
    const float* __restrict__ h, const float* __restrict__ pre_w1,
    const float* __restrict__ biasc,
    unsigned short* __restrict__ predD, unsigned short* __restrict__ predS, int l) {
  int tid = threadIdx.x;
  int t = tid >> 6, lane = tid & 63;
  int n = blockIdx.x * 64 + lane;
  if (n >= NN) return;
  int wt_u = __builtin_amdgcn_readfirstlane(l * TT + t);
  const float* W1 = pre_w1 + (size_t)wt_u * 1200;
  const float* bc = biasc + t * FF;
  float xt[FF];
  {
    const float4* pp = (const float4*)(h + (size_t)n * DD + t * FF);
#pragma unroll
    for (int i = 0; i < 5; ++i) { float4 v = pp[i]; xt[i*4]=v.x; xt[i*4+1]=v.y; xt[i*4+2]=v.z; xt[i*4+3]=v.w; }
  }
  float d[FF], s[FF];
#pragma unroll
  for (int j = 0; j < FF; ++j) { d[j] = bc[j]; s[j] = 0.f; }
#pragma unroll
  for (int i = 0; i < FF; ++i) {
    float a = xt[i];
#pragma unroll
    for (int j = 0; j < FF; ++j) {
      d[j] = fmaf(a, W1[i * FF + j], d[j]);
      s[j] = fmaf(a, W1[(FF + i) * FF + j], s[j]);
    }
  }
  ushort4* pd = (ushort4*)(predD + (size_t)n * DD + t * FF);
  ushort4* ps = (ushort4*)(predS + (size_t)n * DD + t * FF);
#pragma unroll
  for (int i = 0; i < 5; ++i) {
    pd[i] = make_ushort4(f2bf(d[i*4]), f2bf(d[i*4+1]), f2bf(d[i*4+2]), f2bf(d[i*4+3]));
    ps[i] = make_ushort4(f2bf(s[i*4]), f2bf(s[i*4+1]), f2bf(s[i*4+2]), f2bf(s[i*4+3]));
  }
}

// ---------------- FUSED edge pre-MLP + aggregation, tower-colocated ----------------
// Block = 256 = 4 waves; wave = tower; shared 32-node tile; 64-edge windows.
// All 4 waves walk the SAME slot window between barriers -> the 4x40B predS
// slices of each edge coalesce into the same cache lines (round-6 regression fix).
// Reduce: thread (t,lane) owns node=lane>>1, pairs (lane&1)*5..+4 (1280=256x5).
__global__ __launch_bounds__(256, 4) void k_preagg(
    const unsigned short* __restrict__ predD,
    const unsigned short* __restrict__ predS,
    const unsigned int* __restrict__ ea16,
    const int* __restrict__ csr_src,
    const int* __restrict__ csr_dst,
    const int* __restrict__ row_ptr,
    const float* __restrict__ inv_deg,
    const unsigned int* __restrict__ wcpk,
    const unsigned int* __restrict__ w2pk,
    const float* __restrict__ pre_b2,
    unsigned short* __restrict__ aggbuf,
    int l) {
  __shared__ int nbr[TILE_N + 1];
  __shared__ float dDs[TT][TILE_N * FF];      // 10.2 KB
  __shared__ unsigned int m2w[TT][64 * 11];   // 11.3 KB, stride-11: conflict-free
  int tid = threadIdx.x;
  int t = tid >> 6, lane = tid & 63;
  int t_u = __builtin_amdgcn_readfirstlane(t);
  int n0 = blockIdx.x * TILE_N;
  const unsigned int* Wcp = wcpk + (size_t)t_u * FF * 8;
  const unsigned int* W2p = w2pk + (size_t)t_u * FF * 10;
  const float* b2 = pre_b2 + (size_t)(l * TT + t_u) * FF;

  if (tid <= TILE_N) {
    int node = n0 + tid; if (node > NN) node = NN;
    nbr[tid] = row_ptr[node];
  }
  // stage dD: wave t stages its own tower slice (predD rows read once per tile)
  for (int i = lane; i < TILE_N * FF; i += 64) {
    int ni = i / FF, ch = i - ni * FF;
    int node = n0 + ni;
    dDs[t][i] = (node < NN) ? bf2f(predD[(size_t)node * DD + t_u * FF + ch]) : 0.f;
  }
  __syncthreads();
  int tbeg = nbr[0], tend = nbr[TILE_N];

  int nodr = lane >> 1;
  int pr0 = (lane & 1) * 5;
  int begR = nbr[nodr], endR = nbr[nodr + 1];
  float aS[5][2], aQ[5][2], aN[5][2], aX[5][2];
#pragma unroll
  for (int j = 0; j < 5; ++j) {
    aS[j][0] = 0.f; aS[j][1] = 0.f; aQ[j][0] = 0.f; aQ[j][1] = 0.f;
    aN[j][0] = 3.4e38f; aN[j][1] = 3.4e38f; aX[j][0] = -3.4e38f; aX[j][1] = -3.4e38f;
  }

  for (int wb = tbeg; wb < tend; wb += 64) {
    int p = wb + lane;
    if (p < tend) {
      int src = csr_src[p];
      int ni = csr_dst[p] - n0;
      float m1[FF];
      {
        const float4* dd = (const float4*)(&dDs[t][ni * FF]);
        const ushort4* qq = (const ushort4*)(predS + (size_t)src * DD + t_u * FF);
#pragma unroll
        for (int i = 0; i < 5; ++i) {
          float4 d4 = dd[i];
          ushort4 v = qq[i];
          m1[i*4+0] = d4.x + bf2f(v.x);
          m1[i*4+1] = d4.y + bf2f(v.y);
          m1[i*4+2] = d4.z + bf2f(v.z);
          m1[i*4+3] = d4.w + bf2f(v.w);
        }
      }
      half2v eap[8];
      {
        const uint4* ep = (const uint4*)(ea16 + (size_t)p * 8);
        uint4 e0 = ep[0], e1 = ep[1];
        eap[0] = u2h2(e0.x); eap[1] = u2h2(e0.y); eap[2] = u2h2(e0.z); eap[3] = u2h2(e0.w);
        eap[4] = u2h2(e1.x); eap[5] = u2h2(e1.y); eap[6] = u2h2(e1.z); eap[7] = u2h2(e1.w);
      }
#pragma unroll
      for (int j = 0; j < FF; ++j) {
        float c = m1[j];
#pragma unroll
        for (int i2 = 0; i2 < 8; ++i2) c = fdot2(eap[i2], u2h2(Wcp[j * 8 + i2]), c);
        m1[j] = c;
      }
      half2v mp[10];
#pragma unroll
      for (int pr = 0; pr < 10; ++pr)
        mp[pr] = pkrtz(fmaxf(m1[2*pr], 0.f), fmaxf(m1[2*pr+1], 0.f));
      float m2[FF];
#pragma unroll
      for (int j = 0; j < FF; ++j) {
        float c = b2[j];
#pragma unroll
        for (int i2 = 0; i2 < 10; ++i2) c = fdot2(mp[i2], u2h2(W2p[j * 10 + i2]), c);
        m2[j] = c;
      }
      unsigned int* row = &m2w[t][lane * 11];
#pragma unroll
      for (int pr = 0; pr < 10; ++pr) row[pr] = h22u(pkrtz(m2[2*pr], m2[2*pr+1]));
    }
    __syncthreads();
    int we = (wb + 64 < tend) ? (wb + 64) : tend;
    int lo = begR > wb ? begR : wb;
    int hi = endR < we ? endR : we;
    for (int s = lo; s < hi; ++s) {
      const unsigned int* row = &m2w[t][(s - wb) * 11 + pr0];
#pragma unroll
      for (int j = 0; j < 5; ++j) {
        half2v h2 = u2h2(row[j]);
        float v0 = (float)h2.x, v1 = (float)h2.y;
        aS[j][0] += v0; aQ[j][0] = fmaf(v0, v0, aQ[j][0]);
        aN[j][0] = fminf(aN[j][0], v0); aX[j][0] = fmaxf(aX[j][0], v0);
        aS[j][1] += v1; aQ[j][1] = fmaf(v1, v1, aQ[j][1]);
        aN[j][1] = fminf(aN[j][1], v1); aX[j][1] = fmaxf(aX[j][1], v1);
      }
    }
    __syncthreads();
  }

  int n = n0 + nodr;
  if (n < NN) {
    float inv = inv_deg[n];
    bool noe = (endR <= begR);
    unsigned short* ab = aggbuf + ((size_t)n * 4 + t_u) * 80;
#pragma unroll
    for (int j = 0; j < 5; ++j) {
      float mu0 = aS[j][0] * inv, mu1 = aS[j][1] * inv;
      float sd0 = sqrtf(fmaxf(aQ[j][0] * inv - mu0 * mu0, 0.f) + 1e-5f);
      float sd1 = sqrtf(fmaxf(aQ[j][1] * inv - mu1 * mu1, 0.f) + 1e-5f);
      float mn0 = noe ? 0.f : aN[j][0], mn1 = noe ? 0.f : aN[j][1];
      float mx0 = noe ? 0.f : aX[j][0], mx1 = noe ? 0.f : aX[j][1];
      ((unsigned int*)(ab))[pr0 + j]      = pack_bf16(mu0, mu1);
      ((unsigned int*)(ab + 20))[pr0 + j] = pack_bf16(mn0, mn1);
      ((unsigned int*)(ab + 40))[pr0 + j] = pack_bf16(mx0, mx1);
      ((unsigned int*)(ab + 60))[pr0 + j] = pack_bf16(sd0, sd1);
    }
  }
}

// ---------------- node-parallel post-MLP via dot2, register-preloaded activations ----------------
__global__ __launch_bounds__(256) void k_post2(
    const float* __restrict__ h, const unsigned short* __restrict__ aggbuf,
    const float* __restrict__ s1a, const float* __restrict__ s2a,
    const float* __restrict__ post_w1, const float* __restrict__ post_b1,
    const unsigned int* __restrict__ q1pk, const unsigned int* __restrict__ q2pk,
    const float* __restrict__ post_b2,
    float* __restrict__ out2, int l, int tiles) {
  int t = blockIdx.x / tiles;          // block-uniform tower
  int tile = blockIdx.x - t * tiles;
  int wt_u = l * TT + t;
  const float* Q1 = post_w1 + (size_t)wt_u * 5200;  // fp32 rows [0,20) for xt part
  const float* B1 = post_b1 + (size_t)wt_u * FF;
  const float* B2 = post_b2 + (size_t)wt_u * FF;
  const unsigned int* q1 = q1pk + (size_t)t * 120 * FF;
  const unsigned int* q2 = q2pk + (size_t)t * 10 * FF;
  int n = tile * 256 + threadIdx.x;
  if (n >= NN) return;
  float c1 = s1a[n], c2 = s2a[n];
  half2v c1p = pkrtz(c1, c1), c2p = pkrtz(c2, c2);
  float xt[FF];
  {
    const float4* pp = (const float4*)(h + (size_t)n * DD + t * FF);
#pragma unroll
    for (int i = 0; i < 5; ++i) { float4 v = pp[i]; xt[i*4]=v.x; xt[i*4+1]=v.y; xt[i*4+2]=v.z; xt[i*4+3]=v.w; }
  }
  half2v a0p[40];
  {
    const uint4* ap = (const uint4*)(aggbuf + ((size_t)n * 4 + t) * 80);
#pragma unroll
    for (int q = 0; q < 10; ++q) {
      uint4 v = ap[q];
      unsigned int w[4] = {v.x, v.y, v.z, v.w};
#pragma unroll
      for (int k = 0; k < 4; ++k) {
        unsigned int u = w[k];
        float lo = __uint_as_float(u << 16);
        float hi = __uint_as_float(u & 0xffff0000u);
        a0p[q * 4 + k] = pkrtz(lo, hi);
      }
    }
  }
  float o1[FF];
#pragma unroll
  for (int j = 0; j < FF; ++j) o1[j] = B1[j];
#pragma unroll
  for (int i = 0; i < FF; ++i) {
    float a = xt[i];
#pragma unroll
    for (int j = 0; j < FF; ++j) o1[j] = fmaf(a, Q1[i * FF + j], o1[j]);
  }
#pragma unroll 2
  for (int k = 0; k < 40; ++k) {
    half2v act = a0p[k];
    const unsigned int* wr = q1 + k * FF;
#pragma unroll
    for (int j = 0; j < FF; ++j) o1[j] = fdot2(act, u2h2(wr[j]), o1[j]);
  }
#pragma unroll 2
  for (int k = 0; k < 40; ++k) {
    half2v act = a0p[k] * c1p;
    const unsigned int* wr = q1 + (40 + k) * FF;
#pragma unroll
    for (int j = 0; j < FF; ++j) o1[j] = fdot2(act, u2h2(wr[j]), o1[j]);
  }
#pragma unroll 2
  for (int k = 0; k < 40; ++k) {
    half2v act = a0p[k] * c2p;
    const unsigned int* wr = q1 + (80 + k) * FF;
#pragma unroll
    for (int j = 0; j < FF; ++j) o1[j] = fdot2(act, u2h2(wr[j]), o1[j]);
  }
  half2v o1p[10];
#pragma unroll
  for (int i2 = 0; i2 < 10; ++i2)
    o1p[i2] = pkrtz(fmaxf(o1[2*i2], 0.f), fmaxf(o1[2*i2+1], 0.f));
  float o2[FF];
#pragma unroll
  for (int j = 0; j < FF; ++j) o2[j] = B2[j];
#pragma unroll 2
  for (int i2 = 0; i2 < 10; ++i2) {
    half2v act = o1p[i2];
    const unsigned int* wr = q2 + i2 * FF;
#pragma unroll
    for (int j = 0; j < FF; ++j) o2[j] = fdot2(act, u2h2(wr[j]), o2[j]);
  }
  float4* op = (float4*)(out2 + (size_t)n * DD + t * FF);
#pragma unroll
  for (int i = 0; i < 5; ++i) op[i] = make_float4(o2[i*4], o2[i*4+1], o2[i*4+2], o2[i*4+3]);
}

// ---------------- lin layer + BN column partial sums ----------------
__global__ __launch_bounds__(320) void k_lin(const float* __restrict__ out2,
                                             const float* __restrict__ lin_w,
                                             const float* __restrict__ lin_b,
                                             float* __restrict__ outl,
                                             float* __restrict__ colsum, int l) {
  __shared__ float Wl[DD * DD];
  __shared__ float rowbuf[4 * DD];
  __shared__ float red[320];
  int tid = threadIdx.x;
  for (int i = tid; i < DD * DD; i += 320) Wl[i] = lin_w[(size_t)l * DD * DD + i];
  __syncthreads();
  int nl = tid / DD, d = tid - nl * DD;
  float bias = lin_b[l * DD + d];
  float bsum = 0.f, bsq = 0.f;
  for (int base = blockIdx.x * 4; base < NN; base += gridDim.x * 4) {
    int gi = base * DD + tid;
    rowbuf[tid] = (gi < NN * DD) ? out2[gi] : 0.f;
    __syncthreads();
    int n = base + nl;
    if (n < NN) {
      float acc = bias;
#pragma unroll
      for (int i = 0; i < DD; ++i) acc = fmaf(rowbuf[nl * DD + i], Wl[i * DD + d], acc);
      outl[(size_t)n * DD + d] = acc;
      bsum += acc; bsq += acc * acc;
    }
    __syncthreads();
  }
  red[tid] = bsum;
  __syncthreads();
  if (tid < DD) {
    float s = red[tid] + red[tid + DD] + red[tid + 2 * DD] + red[tid + 3 * DD];
    atomicAdd(&colsum[d], s);
  }
  __syncthreads();
  red[tid] = bsq;
  __syncthreads();
  if (tid < DD) {
    float s = red[tid] + red[tid + DD] + red[tid + 2 * DD] + red[tid + 3 * DD];
    atomicAdd(&colsum[DD + d], s);
  }
}

// ---------------- BN finalize ----------------
__global__ __launch_bounds__(128) void k_bnfinal(const float* __restrict__ colsum,
                                                 const float* __restrict__ bn_g,
                                                 const float* __restrict__ bn_b,
                                                 float* __restrict__ bnsc, int l) {
  int d = threadIdx.x;
  if (d >= DD) return;
  float mu = colsum[d] * (1.0f / NN);
  float var = colsum[DD + d] * (1.0f / NN) - mu * mu;
  float sc = bn_g[l * DD + d] * rsqrtf(var + 1e-5f);
  bnsc[d] = sc;
  bnsc[DD + d] = bn_b[l * DD + d] - mu * sc;
}

// ---------------- BN apply + relu + residual into h ----------------
__global__ __launch_bounds__(256) void k_bnapply(const float* __restrict__ outl,
                                                 const float* __restrict__ bnsc,
                                                 float* __restrict__ h) {
  int idx = blockIdx.x * 256 + threadIdx.x;
  if (idx >= NN * DD) return;
  int d = idx % DD;
  float v = fmaf(outl[idx], bnsc[d], bnsc[DD + d]);
  h[idx] += fmaxf(v, 0.f);
}

// ---------------- graph pooling ----------------
__global__ __launch_bounds__(256) void k_gcnt(const int* __restrict__ batch, int* __restrict__ gcnt) {
  __shared__ int hcnt[GG];
  int tid = threadIdx.x;
  if (tid < GG) hcnt[tid] = 0;
  __syncthreads();
  int n = blockIdx.x * 256 + tid;
  if (n < NN) atomicAdd(&hcnt[batch[n]], 1);
  __syncthreads();
  if (tid < GG && hcnt[tid] > 0) atomicAdd(&gcnt[tid], hcnt[tid]);
}

__global__ void k_gstart(const int* __restrict__ gcnt, int* __restrict__ gstart) {
  if (threadIdx.x == 0 && blockIdx.x == 0) {
    int acc = 0;
    for (int g = 0; g < GG; ++g) { gstart[g] = acc; acc += gcnt[g]; }
  }
}

__global__ __launch_bounds__(320) void k_gmean(const float* __restrict__ h,
                                               const int* __restrict__ gstart,
                                               const int* __restrict__ gcnt,
                                               float* __restrict__ gbuf) {
  __shared__ float red[320];
  int g = blockIdx.x, tid = threadIdx.x;
  int nl = tid / DD, d = tid - nl * DD;
  int start = gstart[g], c = gcnt[g];
  float acc = 0.f;
  for (int r = start + nl; r < start + c; r += 4) acc += h[(size_t)r * DD + d];
  red[tid] = acc;
  __syncthreads();
  if (tid < DD) {
    float s = red[tid] + red[tid + DD] + red[tid + 2 * DD] + red[tid + 3 * DD];
    float cf = (c > 0) ? (float)c : 1.0f;
    gbuf[g * DD + tid] = s / cf;
  }
}

// ---------------- final MLP (tiny) ----------------
__global__ __launch_bounds__(64) void k_mlp(const float* __restrict__ gbuf,
                                            const float* __restrict__ w1, const float* __restrict__ b1,
                                            const float* __restrict__ w2, const float* __restrict__ b2,
                                            const float* __restrict__ w3, const float* __restrict__ b3,
                                            float* __restrict__ out) {
  __shared__ float row[DD];
  __shared__ float t1[40];
  __shared__ float t2[20];
  int g = blockIdx.x, tid = threadIdx.x;
  for (int i = tid; i < DD; i += 64) row[i] = gbuf[g * DD + i];
  __syncthreads();
  if (tid < 40) {
    float acc = b1[tid];
#pragma unroll
    for (int i = 0; i < DD; ++i) acc = fmaf(row[i], w1[i * 40 + tid], acc);
    t1[tid] = fmaxf(acc, 0.f);
  }
  __syncthreads();
  if (tid < 20) {
    float acc = b2[tid];
#pragma unroll
    for (int i = 0; i < 40; ++i) acc = fmaf(t1[i], w2[i * 20 + tid], acc);
    t2[tid] = fmaxf(acc, 0.f);
  }
  __syncthreads();
  if (tid == 0) {
    float acc = b3[0];
#pragma unroll
    for (int i = 0; i < 20; ++i) acc = fmaf(t2[i], w3[i], acc);
    out[g] = acc;
  }
}

extern "C" void kernel_launch(void* const* d_in, const int* in_sizes, int n_in,
                              void* d_out, int out_size, void* d_ws, size_t ws_size,
                              hipStream_t stream) {
  const int*   x         = (const int*)d_in[0];
  const int*   ei        = (const int*)d_in[1];
  const int*   batch     = (const int*)d_in[2];
  const float* edge_attr = (const float*)d_in[3];
  const float* atom_emb  = (const float*)d_in[4];
  const float* edge_w    = (const float*)d_in[5];
  const float* edge_b    = (const float*)d_in[6];
  const float* pre_w1    = (const float*)d_in[7];
  const float* pre_b1    = (const float*)d_in[8];
  const float* pre_w2    = (const float*)d_in[9];
  const float* pre_b2    = (const float*)d_in[10];
  const float* post_w1   = (const float*)d_in[11];
  const float* post_b1   = (const float*)d_in[12];
  const float* post_w2   = (const float*)d_in[13];
  const float* post_b2   = (const float*)d_in[14];
  const float* lin_w     = (const float*)d_in[15];
  const float* lin_b     = (const float*)d_in[16];
  const float* bn_g      = (const float*)d_in[17];
  const float* bn_b      = (const float*)d_in[18];
  const float* mlp_w1    = (const float*)d_in[19];
  const float* mlp_b1    = (const float*)d_in[20];
  const float* mlp_w2    = (const float*)d_in[21];
  const float* mlp_b2    = (const float*)d_in[22];
  const float* mlp_w3    = (const float*)d_in[23];
  const float* mlp_b3    = (const float*)d_in[24];
  float* out = (float*)d_out;

  // workspace carve-up (~116 MB)
  char* ws = (char*)d_ws;
  size_t off = 0;
  auto alloc = [&](size_t bytes) -> void* {
    void* p = ws + off;
    off += (bytes + 15) & ~(size_t)15;
    return p;
  };
  float* h       = (float*)alloc((size_t)NN * DD * 4);           // 16 MB
  float* out2    = (float*)alloc((size_t)NN * DD * 4);           // 16 MB
  unsigned short* predD = (unsigned short*)alloc((size_t)NN * DD * 2); // 8 MB bf16
  unsigned short* predS = (unsigned short*)alloc((size_t)NN * DD * 2); // 8 MB bf16
  int*   csr_src = (int*)alloc((size_t)EE * 4);                  // 3.2 MB
  int*   csr_eid = (int*)alloc((size_t)EE * 4);                  // 3.2 MB
  int*   csr_dst = (int*)alloc((size_t)EE * 4);                  // 3.2 MB
  unsigned int* ea16 = (unsigned int*)alloc((size_t)EE * 8 * 4); // 25.6 MB f16 CSR-ordered ea
  int*   row_ptr = (int*)alloc((size_t)(NN + 1) * 4);
  int*   cnt     = (int*)alloc((size_t)NN * 4);
  int*   cursor  = (int*)alloc((size_t)NN * 4);
  float* inv_deg = (float*)alloc((size_t)NN * 4);
  float* s1a     = (float*)alloc((size_t)NN * 4);
  float* s2a     = (float*)alloc((size_t)NN * 4);
  float* colsum  = (float*)alloc(2 * DD * 4);
  float* bnsc    = (float*)alloc(2 * DD * 4);
  float* gbuf    = (float*)alloc((size_t)GG * DD * 4);
  unsigned int* wcpk  = (unsigned int*)alloc((size_t)TT * FF * 8 * 4);
  unsigned int* w2pk  = (unsigned int*)alloc((size_t)TT * FF * 10 * 4);
  unsigned int* q1pk  = (unsigned int*)alloc((size_t)TT * 120 * FF * 4);
  unsigned int* q2pk  = (unsigned int*)alloc((size_t)TT * 10 * FF * 4);
  float* biasc   = (float*)alloc((size_t)TT * FF * 4);
  int*   bsum    = (int*)alloc((size_t)SCAN_B * 4);
  int*   boff    = (int*)alloc((size_t)SCAN_B * 4);
  int*   gcnt    = (int*)alloc((size_t)GG * 4);
  int*   gstart  = (int*)alloc((size_t)(GG + 1) * 4);
  unsigned short* aggbuf = (unsigned short*)alloc((size_t)NN * 4 * 80 * 2); // 32 MB bf16
  float* outl = (float*)aggbuf; // alias: aggbuf dead after k_post2; outl dead before next k_preagg
  (void)in_sizes; (void)n_in; (void)out_size; (void)ws_size;

  hipMemsetAsync(cnt, 0, (size_t)NN * 4, stream);
  k_h<<<(NN * DD + 255) / 256, 256, 0, stream>>>(x, atom_emb, h);
  k_deg<<<(EE + 255) / 256, 256, 0, stream>>>(ei, cnt);
  k_scan_sum<<<SCAN_B, 1024, 0, stream>>>(cnt, bsum);
  k_scan_top<<<1, 64, 0, stream>>>(bsum, boff, row_ptr);
  k_scan_apply<<<SCAN_B, 1024, 0, stream>>>(cnt, boff, row_ptr, cursor);
  k_csrfill<<<(EE + 255) / 256, 256, 0, stream>>>(ei, cursor, csr_src, csr_eid, csr_dst);
  k_eagather<<<(EE + 255) / 256, 256, 0, stream>>>(csr_eid, edge_attr, ea16);
  k_nodeparams<<<(NN + 255) / 256, 256, 0, stream>>>(cnt, inv_deg, s1a, s2a);

  int tilesA = (NN + TILE_N - 1) / TILE_N;   // 1563
  int tilesP = (NN + 255) / 256;             // 196
  for (int l = 0; l < LL; ++l) {
    k_wcomb<<<TT, 64, 0, stream>>>(edge_w, edge_b, pre_w1, pre_b1, pre_w2, wcpk, w2pk, biasc, l);
    k_postpk<<<TT, 64, 0, stream>>>(post_w1, post_w2, q1pk, q2pk, l);
    k_prenode<<<(NN + 63) / 64, 256, 0, stream>>>(h, pre_w1, biasc, predD, predS, l);
    k_preagg<<<tilesA, 256, 0, stream>>>(predD, predS, ea16, csr_src, csr_dst, row_ptr,
        inv_deg, wcpk, w2pk, pre_b2, aggbuf, l);
    k_post2<<<tilesP * TT, 256, 0, stream>>>(h, aggbuf, s1a, s2a,
        post_w1, post_b1, q1pk, q2pk, post_b2, out2, l, tilesP);
    hipMemsetAsync(colsum, 0, 2 * DD * 4, stream);
    k_lin<<<512, 320, 0, stream>>>(out2, lin_w, lin_b, outl, colsum, l);
    k_bnfinal<<<1, 128, 0, stream>>>(colsum, bn_g, bn_b, bnsc, l);
    k_bnapply<<<(NN * DD + 255) / 256, 256, 0, stream>>>(outl, bnsc, h);
  }

  hipMemsetAsync(gcnt, 0, (size_t)GG * 4, stream);
  k_gcnt<<<(NN + 255) / 256, 256, 0, stream>>>(batch, gcnt);
  k_gstart<<<1, 64, 0, stream>>>(gcnt, gstart);
  k_gmean<<<GG, 320, 0, stream>>>(h, gstart, gcnt, gbuf);
  k_mlp<<<GG, 64, 0, stream>>>(gbuf, mlp_w1, mlp_b1, mlp_w2, mlp_b2, mlp_w3, mlp_b3, out);
}

// Round 8
// 1472.272 us; speedup vs baseline: 1.3006x; 1.3006x over previous
//
#include <hip/hip_runtime.h>
#include <hip/hip_bf16.h>

// Problem constants (from reference)
#define NN 50000
#define EE 800000
#define GG 128
#define LL 4
#define TT 4
#define FF 20
#define DD 80
#define SCAN_B ((NN + 1023) / 1024)   // 49
#define TILE_N 16                     // nodes per k_preagg tile (avg 256 slots)
#define ITEMS (TILE_N * 10)           // 160 (node, ch-pair) reduce items per tower
static constexpr float AVG_LOG = 2.8332133440562162f; // ln(17)

typedef __fp16 half2v __attribute__((ext_vector_type(2)));

__device__ __forceinline__ float bf2f(unsigned short u) {
  return __uint_as_float((unsigned)u << 16);
}
__device__ __forceinline__ unsigned short f2bf(float f) {
  __hip_bfloat16 b = __float2bfloat16(f); // RNE
  return *(unsigned short*)&b;
}
__device__ __forceinline__ half2v pkrtz(float a, float b) {
#if __has_builtin(__builtin_amdgcn_cvt_pkrtz)
  return __builtin_amdgcn_cvt_pkrtz(a, b);
#else
  half2v h; h.x = (__fp16)a; h.y = (__fp16)b; return h;
#endif
}
__device__ __forceinline__ float fdot2(half2v a, half2v b, float c) {
#if __has_builtin(__builtin_amdgcn_fdot2)
  return __builtin_amdgcn_fdot2(a, b, c, false);
#else
  return fmaf((float)a.x, (float)b.x, fmaf((float)a.y, (float)b.y, c));
#endif
}
__device__ __forceinline__ half2v u2h2(unsigned int u) {
  return __builtin_bit_cast(half2v, u);
}
__device__ __forceinline__ unsigned int h22u(half2v h) {
  return __builtin_bit_cast(unsigned int, h);
}
__device__ __forceinline__ unsigned int packh2_rne(float a, float b) {
  half2v h; h.x = (__fp16)a; h.y = (__fp16)b; // RNE casts for weights
  return h22u(h);
}
__device__ __forceinline__ unsigned int pack_bf16(float a, float b) {
  return (unsigned int)f2bf(a) | ((unsigned int)f2bf(b) << 16);
}

// ---------------- h init: h[n,d] = sum_i atom_emb[i, x[n,i], d] ----------------
__global__ __launch_bounds__(256) void k_h(const int* __restrict__ x,
                                           const float* __restrict__ atom_emb,
                                           float* __restrict__ h) {
  int idx = blockIdx.x * 256 + threadIdx.x;
  if (idx >= NN * DD) return;
  int n = idx / DD, d = idx - n * DD;
  const int* xr = x + n * 9;
  float acc = 0.f;
#pragma unroll
  for (int i = 0; i < 9; ++i) {
    int v = xr[i];
    acc += atom_emb[(i * 16 + v) * DD + d];
  }
  h[idx] = acc;
}

// ---------------- degree count ----------------
__global__ __launch_bounds__(256) void k_deg(const int* __restrict__ ei, int* __restrict__ cnt) {
  int e = blockIdx.x * 256 + threadIdx.x;
  if (e >= EE) return;
  atomicAdd(&cnt[ei[EE + e]], 1); // dst = edge_index[1][e]
}

// ---------------- hierarchical exclusive scan ----------------
__global__ __launch_bounds__(1024) void k_scan_sum(const int* __restrict__ cnt, int* __restrict__ bsum) {
  __shared__ int red[1024];
  int tid = threadIdx.x;
  int i = blockIdx.x * 1024 + tid;
  red[tid] = (i < NN) ? cnt[i] : 0;
  __syncthreads();
  for (int off = 512; off > 0; off >>= 1) {
    if (tid < off) red[tid] += red[tid + off];
    __syncthreads();
  }
  if (tid == 0) bsum[blockIdx.x] = red[0];
}

__global__ void k_scan_top(const int* __restrict__ bsum, int* __restrict__ boff,
                           int* __restrict__ row_ptr) {
  if (threadIdx.x == 0 && blockIdx.x == 0) {
    int acc = 0;
    for (int b = 0; b < SCAN_B; ++b) { boff[b] = acc; acc += bsum[b]; }
    row_ptr[NN] = acc;
  }
}

__global__ __launch_bounds__(1024) void k_scan_apply(const int* __restrict__ cnt,
                                                     const int* __restrict__ boff,
                                                     int* __restrict__ row_ptr,
                                                     int* __restrict__ cursor) {
  __shared__ int sm[1024];
  int tid = threadIdx.x;
  int i = blockIdx.x * 1024 + tid;
  int v = (i < NN) ? cnt[i] : 0;
  sm[tid] = v;
  __syncthreads();
  for (int off = 1; off < 1024; off <<= 1) {
    int t = (tid >= off) ? sm[tid - off] : 0;
    __syncthreads();
    sm[tid] += t;
    __syncthreads();
  }
  int excl = boff[blockIdx.x] + sm[tid] - v;
  if (i < NN) { row_ptr[i] = excl; cursor[i] = excl; }
}

// ---------------- CSR fill: slot -> src / eid / dst (split arrays) ----------------
__global__ __launch_bounds__(256) void k_csrfill(const int* __restrict__ ei,
                                                 int* __restrict__ cursor,
                                                 int* __restrict__ csr_src,
                                                 int* __restrict__ csr_eid,
                                                 int* __restrict__ csr_dst) {
  int e = blockIdx.x * 256 + threadIdx.x;
  if (e >= EE) return;
  int dst = ei[EE + e];
  int slot = atomicAdd(&cursor[dst], 1);
  csr_src[slot] = ei[e];
  csr_eid[slot] = e;
  csr_dst[slot] = dst;
}

// ---------------- one-time edge_attr gather into CSR slot order, f16 pairs ----------------
__global__ __launch_bounds__(256) void k_eagather(const int* __restrict__ csr_eid,
                                                  const float* __restrict__ edge_attr,
                                                  unsigned int* __restrict__ ea16) {
  int sl = blockIdx.x * 256 + threadIdx.x;
  if (sl >= EE) return;
  int e = csr_eid[sl];
  const float4* ap = (const float4*)(edge_attr + (size_t)e * 16);
  uint4 o0, o1;
  float4 v0 = ap[0], v1 = ap[1], v2 = ap[2], v3 = ap[3];
  o0.x = packh2_rne(v0.x, v0.y); o0.y = packh2_rne(v0.z, v0.w);
  o0.z = packh2_rne(v1.x, v1.y); o0.w = packh2_rne(v1.z, v1.w);
  o1.x = packh2_rne(v2.x, v2.y); o1.y = packh2_rne(v2.z, v2.w);
  o1.z = packh2_rne(v3.x, v3.y); o1.w = packh2_rne(v3.z, v3.w);
  uint4* op = (uint4*)(ea16 + (size_t)sl * 8);
  op[0] = o0; op[1] = o1;
}

// ---------------- per-node params ----------------
__global__ __launch_bounds__(256) void k_nodeparams(const int* __restrict__ cnt,
                                                    float* __restrict__ inv_deg,
                                                    float* __restrict__ s1a,
                                                    float* __restrict__ s2a) {
  int n = blockIdx.x * 256 + threadIdx.x;
  if (n >= NN) return;
  int c = cnt[n];
  float deg = (c > 0) ? (float)c : 1.0f;
  inv_deg[n] = 1.0f / deg;
  float logd = logf(deg + 1.0f);
  s1a[n] = logd / AVG_LOG;
  s2a[n] = AVG_LOG / logd;
}

// ---------------- per-layer weight composition + f16 pair packing ----------------
__global__ __launch_bounds__(64) void k_wcomb(const float* __restrict__ edge_w,
                                              const float* __restrict__ edge_b,
                                              const float* __restrict__ pre_w1,
                                              const float* __restrict__ pre_b1,
                                              const float* __restrict__ pre_w2,
                                              unsigned int* __restrict__ wcpk,
                                              unsigned int* __restrict__ w2pk,
                                              float* __restrict__ biasc, int l) {
  int t = blockIdx.x;
  int wt = l * TT + t;
  const float* W1 = pre_w1 + (size_t)wt * 1200; // [60][20]
  const float* W2 = pre_w2 + (size_t)wt * 400;  // [20][20]
  const float* ew = edge_w + (size_t)l * 16 * FF;
  const float* eb = edge_b + (size_t)l * FF;
  int j = threadIdx.x;
  if (j >= FF) return;
  float col[16];
  for (int i = 0; i < 16; ++i) {
    float acc = 0.f;
#pragma unroll
    for (int f = 0; f < FF; ++f) acc = fmaf(ew[i * FF + f], W1[(40 + f) * FF + j], acc);
    col[i] = acc;
  }
#pragma unroll
  for (int i2 = 0; i2 < 8; ++i2)
    wcpk[((size_t)t * FF + j) * 8 + i2] = packh2_rne(col[2 * i2], col[2 * i2 + 1]);
#pragma unroll
  for (int i2 = 0; i2 < 10; ++i2)
    w2pk[((size_t)t * FF + j) * 10 + i2] = packh2_rne(W2[(2 * i2) * FF + j], W2[(2 * i2 + 1) * FF + j]);
  float b = pre_b1[wt * FF + j];
#pragma unroll
  for (int f = 0; f < FF; ++f) b = fmaf(eb[f], W1[(40 + f) * FF + j], b);
  biasc[t * FF + j] = b;
}

// ---------------- post-MLP weight packing: Q1 rows [20,260) + Q2 as f16 pairs ----------------
__global__ __launch_bounds__(64) void k_postpk(const float* __restrict__ post_w1,
                                               const float* __restrict__ post_w2,
                                               unsigned int* __restrict__ q1pk,
                                               unsigned int* __restrict__ q2pk, int l) {
  int t = blockIdx.x;
  int wt = l * TT + t;
  const float* Q1 = post_w1 + (size_t)wt * 5200;
  const float* Q2 = post_w2 + (size_t)wt * 400;
  int j = threadIdx.x;
  if (j >= FF) return;
  for (int i2 = 0; i2 < 120; ++i2) {
    int blk = i2 / 40, k = i2 - blk * 40;
    int r0 = 20 + 80 * blk + 2 * k;
    q1pk[((size_t)t * 120 + i2) * FF + j] = packh2_rne(Q1[r0 * FF + j], Q1[(r0 + 1) * FF + j]);
  }
#pragma unroll
  for (int i2 = 0; i2 < 10; ++i2)
    q2pk[((size_t)t * 10 + i2) * FF + j] = packh2_rne(Q2[(2 * i2) * FF + j], Q2[(2 * i2 + 1) * FF + j]);
}

// ---------------- per-node pre contributions (bf16 out) ----------------
__global__ __launch_bounds__(256) void k_prenode(
    const float* __restrict__ h, const float* __restrict__ pre_w1,
    const float* __restrict__ biasc,
    unsigned short* __restrict__ predD, unsigned short* __restrict__ predS, int l) {
  int tid = threadIdx.x;
  int t = tid >> 6, lane = tid & 63;
  int n = blockIdx.x * 64 + lane;
  if (n >= NN) return;
  int wt_u = __builtin_amdgcn_readfirstlane(l * TT + t);
  const float* W1 = pre_w1 + (size_t)wt_u * 1200;
  const float* bc = biasc + t * FF;
  float xt[FF];
  {
    const float4* pp = (const float4*)(h + (size_t)n * DD + t * FF);
#pragma unroll
    for (int i = 0; i < 5; ++i) { float4 v = pp[i]; xt[i*4]=v.x; xt[i*4+1]=v.y; xt[i*4+2]=v.z; xt[i*4+3]=v.w; }
  }
  float d[FF], s[FF];
#pragma unroll
  for (int j = 0; j < FF; ++j) { d[j] = bc[j]; s[j] = 0.f; }
#pragma unroll
  for (int i = 0; i < FF; ++i) {
    float a = xt[i];
#pragma unroll
    for (int j = 0; j < FF; ++j) {
      d[j] = fmaf(a, W1[i * FF + j], d[j]);
      s[j] = fmaf(a, W1[(FF + i) * FF + j], s[j]);
    }
  }
  ushort4* pd = (ushort4*)(predD + (size_t)n * DD + t * FF);
  ushort4* ps = (ushort4*)(predS + (size_t)n * DD + t * FF);
#pragma unroll
  for (int i = 0; i < 5; ++i) {
    pd[i] = make_ushort4(f2bf(d[i*4]), f2bf(d[i*4+1]), f2bf(d[i*4+2]), f2bf(d[i*4+3]));
    ps[i] = make_ushort4(f2bf(s[i*4]), f2bf(s[i*4+1]), f2bf(s[i*4+2]), f2bf(s[i*4+3]));
  }
}

// ---------------- FUSED edge pre-MLP + aggregation, tower-colocated, balanced reduce ----------------
// Block = 256 = 4 waves; wave = tower; shared 16-node tile; 64-edge windows.
// All 4 waves walk the SAME slot window between barriers -> 4x40B predS slices
// of each edge coalesce (round-7 FETCH fix, kept).
// Reduce: per wave, 160 items = (node = item/10, pair = item%10); lane owns
// items {lane, lane+64, lane+128} -> each node's 10 pairs spread over 10 lanes
// (round-7 serial-reduce fix: no 5x-per-lane pair serialization, and a lane's
// 2-3 items are DIFFERENT nodes so degree tails average out).
__global__ __launch_bounds__(256, 4) void k_preagg(
    const unsigned short* __restrict__ predD,
    const unsigned short* __restrict__ predS,
    const unsigned int* __restrict__ ea16,
    const int* __restrict__ csr_src,
    const int* __restrict__ csr_dst,
    const int* __restrict__ row_ptr,
    const float* __restrict__ inv_deg,
    const unsigned int* __restrict__ wcpk,
    const unsigned int* __restrict__ w2pk,
    const float* __restrict__ pre_b2,
    unsigned short* __restrict__ aggbuf,
    int l) {
  __shared__ int nbr[TILE_N + 1];
  __shared__ float dDs[TT][TILE_N * FF];      // 5.1 KB
  __shared__ unsigned int m2w[TT][64 * 11];   // 11.3 KB, stride-11: conflict-free
  int tid = threadIdx.x;
  int t = tid >> 6, lane = tid & 63;
  int t_u = __builtin_amdgcn_readfirstlane(t);
  int n0 = blockIdx.x * TILE_N;
  const unsigned int* Wcp = wcpk + (size_t)t_u * FF * 8;
  const unsigned int* W2p = w2pk + (size_t)t_u * FF * 10;
  const float* b2 = pre_b2 + (size_t)(l * TT + t_u) * FF;

  if (tid <= TILE_N) {
    int node = n0 + tid; if (node > NN) node = NN;
    nbr[tid] = row_ptr[node];
  }
  // stage dD: wave t stages its own tower slice (predD rows read once per tile)
  for (int i = lane; i < TILE_N * FF; i += 64) {
    int ni = i / FF, ch = i - ni * FF;
    int node = n0 + ni;
    dDs[t][i] = (node < NN) ? bf2f(predD[(size_t)node * DD + t_u * FF + ch]) : 0.f;
  }
  __syncthreads();
  int tbeg = nbr[0], tend = nbr[TILE_N];

  // reduce item setup: items {lane, lane+64, lane+128} (item < 160)
  int itN[3], itP[3], itB[3], itE[3];
#pragma unroll
  for (int k = 0; k < 3; ++k) {
    int it = lane + 64 * k;
    bool v = it < ITEMS;
    int nd = v ? (it / 10) : 0;
    itN[k] = nd;
    itP[k] = v ? (it - nd * 10) : 0;
    itB[k] = v ? nbr[nd] : 0;
    itE[k] = v ? nbr[nd + 1] : 0;  // invalid item -> empty range
  }
  float sS[3][2], sQ[3][2], sN[3][2], sX[3][2];
#pragma unroll
  for (int k = 0; k < 3; ++k) {
    sS[k][0] = 0.f; sS[k][1] = 0.f; sQ[k][0] = 0.f; sQ[k][1] = 0.f;
    sN[k][0] = 3.4e38f; sN[k][1] = 3.4e38f; sX[k][0] = -3.4e38f; sX[k][1] = -3.4e38f;
  }

  for (int wb = tbeg; wb < tend; wb += 64) {
    int p = wb + lane;
    if (p < tend) {
      int src = csr_src[p];
      int ni = csr_dst[p] - n0;
      float m1[FF];
      {
        const float4* dd = (const float4*)(&dDs[t][ni * FF]);
        const ushort4* qq = (const ushort4*)(predS + (size_t)src * DD + t_u * FF);
#pragma unroll
        for (int i = 0; i < 5; ++i) {
          float4 d4 = dd[i];
          ushort4 v = qq[i];
          m1[i*4+0] = d4.x + bf2f(v.x);
          m1[i*4+1] = d4.y + bf2f(v.y);
          m1[i*4+2] = d4.z + bf2f(v.z);
          m1[i*4+3] = d4.w + bf2f(v.w);
        }
      }
      half2v eap[8];
      {
        const uint4* ep = (const uint4*)(ea16 + (size_t)p * 8);
        uint4 e0 = ep[0], e1 = ep[1];
        eap[0] = u2h2(e0.x); eap[1] = u2h2(e0.y); eap[2] = u2h2(e0.z); eap[3] = u2h2(e0.w);
        eap[4] = u2h2(e1.x); eap[5] = u2h2(e1.y); eap[6] = u2h2(e1.z); eap[7] = u2h2(e1.w);
      }
#pragma unroll
      for (int j = 0; j < FF; ++j) {
        float c = m1[j];
#pragma unroll
        for (int i2 = 0; i2 < 8; ++i2) c = fdot2(eap[i2], u2h2(Wcp[j * 8 + i2]), c);
        m1[j] = c;
      }
      half2v mp[10];
#pragma unroll
      for (int pr = 0; pr < 10; ++pr)
        mp[pr] = pkrtz(fmaxf(m1[2*pr], 0.f), fmaxf(m1[2*pr+1], 0.f));
      float m2[FF];
#pragma unroll
      for (int j = 0; j < FF; ++j) {
        float c = b2[j];
#pragma unroll
        for (int i2 = 0; i2 < 10; ++i2) c = fdot2(mp[i2], u2h2(W2p[j * 10 + i2]), c);
        m2[j] = c;
      }
      unsigned int* row = &m2w[t][lane * 11];
#pragma unroll
      for (int pr = 0; pr < 10; ++pr) row[pr] = h22u(pkrtz(m2[2*pr], m2[2*pr+1]));
    }
    __syncthreads();
    int we = (wb + 64 < tend) ? (wb + 64) : tend;
#pragma unroll
    for (int k = 0; k < 3; ++k) {
      int lo = itB[k] > wb ? itB[k] : wb;
      int hi = itE[k] < we ? itE[k] : we;
      for (int s = lo; s < hi; ++s) {
        half2v h2 = u2h2(m2w[t][(s - wb) * 11 + itP[k]]);
        float v0 = (float)h2.x, v1 = (float)h2.y;
        sS[k][0] += v0; sQ[k][0] = fmaf(v0, v0, sQ[k][0]);
        sN[k][0] = fminf(sN[k][0], v0); sX[k][0] = fmaxf(sX[k][0], v0);
        sS[k][1] += v1; sQ[k][1] = fmaf(v1, v1, sQ[k][1]);
        sN[k][1] = fminf(sN[k][1], v1); sX[k][1] = fmaxf(sX[k][1], v1);
      }
    }
    __syncthreads();
  }

  // finalize
#pragma unroll
  for (int k = 0; k < 3; ++k) {
    int it = lane + 64 * k;
    if (it < ITEMS) {
      int n = n0 + itN[k];
      if (n < NN) {
        float inv = inv_deg[n];
        bool noe = (itE[k] <= itB[k]);
        float mu0 = sS[k][0] * inv, mu1 = sS[k][1] * inv;
        float sd0 = sqrtf(fmaxf(sQ[k][0] * inv - mu0 * mu0, 0.f) + 1e-5f);
        float sd1 = sqrtf(fmaxf(sQ[k][1] * inv - mu1 * mu1, 0.f) + 1e-5f);
        float mn0 = noe ? 0.f : sN[k][0], mn1 = noe ? 0.f : sN[k][1];
        float mx0 = noe ? 0.f : sX[k][0], mx1 = noe ? 0.f : sX[k][1];
        unsigned short* ab = aggbuf + ((size_t)n * 4 + t_u) * 80;
        ((unsigned int*)(ab))[itP[k]]      = pack_bf16(mu0, mu1);
        ((unsigned int*)(ab + 20))[itP[k]] = pack_bf16(mn0, mn1);
        ((unsigned int*)(ab + 40))[itP[k]] = pack_bf16(mx0, mx1);
        ((unsigned int*)(ab + 60))[itP[k]] = pack_bf16(sd0, sd1);
      }
    }
  }
}

// ---------------- node-parallel post-MLP via dot2, register-preloaded activations ----------------
__global__ __launch_bounds__(256) void k_post2(
    const float* __restrict__ h, const unsigned short* __restrict__ aggbuf,
    const float* __restrict__ s1a, const float* __restrict__ s2a,
    const float* __restrict__ post_w1, const float* __restrict__ post_b1,
    const unsigned int* __restrict__ q1pk, const unsigned int* __restrict__ q2pk,
    const float* __restrict__ post_b2,
    float* __restrict__ out2, int l, int tiles) {
  int t = blockIdx.x / tiles;          // block-uniform tower
  int tile = blockIdx.x - t * tiles;
  int wt_u = l * TT + t;
  const float* Q1 = post_w1 + (size_t)wt_u * 5200;  // fp32 rows [0,20) for xt part
  const float* B1 = post_b1 + (size_t)wt_u * FF;
  const float* B2 = post_b2 + (size_t)wt_u * FF;
  const unsigned int* q1 = q1pk + (size_t)t * 120 * FF;
  const unsigned int* q2 = q2pk + (size_t)t * 10 * FF;
  int n = tile * 256 + threadIdx.x;
  if (n >= NN) return;
  float c1 = s1a[n], c2 = s2a[n];
  half2v c1p = pkrtz(c1, c1), c2p = pkrtz(c2, c2);
  float xt[FF];
  {
    const float4* pp = (const float4*)(h + (size_t)n * DD + t * FF);
#pragma unroll
    for (int i = 0; i < 5; ++i) { float4 v = pp[i]; xt[i*4]=v.x; xt[i*4+1]=v.y; xt[i*4+2]=v.z; xt[i*4+3]=v.w; }
  }
  half2v a0p[40];
  {
    const uint4* ap = (const uint4*)(aggbuf + ((size_t)n * 4 + t) * 80);
#pragma unroll
    for (int q = 0; q < 10; ++q) {
      uint4 v = ap[q];
      unsigned int w[4] = {v.x, v.y, v.z, v.w};
#pragma unroll
      for (int k = 0; k < 4; ++k) {
        unsigned int u = w[k];
        float lo = __uint_as_float(u << 16);
        float hi = __uint_as_float(u & 0xffff0000u);
        a0p[q * 4 + k] = pkrtz(lo, hi);
      }
    }
  }
  float o1[FF];
#pragma unroll
  for (int j = 0; j < FF; ++j) o1[j] = B1[j];
#pragma unroll
  for (int i = 0; i < FF; ++i) {
    float a = xt[i];
#pragma unroll
    for (int j = 0; j < FF; ++j) o1[j] = fmaf(a, Q1[i * FF + j], o1[j]);
  }
#pragma unroll 2
  for (int k = 0; k < 40; ++k) {
    half2v act = a0p[k];
    const unsigned int* wr = q1 + k * FF;
#pragma unroll
    for (int j = 0; j < FF; ++j) o1[j] = fdot2(act, u2h2(wr[j]), o1[j]);
  }
#pragma unroll 2
  for (int k = 0; k < 40; ++k) {
    half2v act = a0p[k] * c1p;
    const unsigned int* wr = q1 + (40 + k) * FF;
#pragma unroll
    for (int j = 0; j < FF; ++j) o1[j] = fdot2(act, u2h2(wr[j]), o1[j]);
  }
#pragma unroll 2
  for (int k = 0; k < 40; ++k) {
    half2v act = a0p[k] * c2p;
    const unsigned int* wr = q1 + (80 + k) * FF;
#pragma unroll
    for (int j = 0; j < FF; ++j) o1[j] = fdot2(act, u2h2(wr[j]), o1[j]);
  }
  half2v o1p[10];
#pragma unroll
  for (int i2 = 0; i2 < 10; ++i2)
    o1p[i2] = pkrtz(fmaxf(o1[2*i2], 0.f), fmaxf(o1[2*i2+1], 0.f));
  float o2[FF];
#pragma unroll
  for (int j = 0; j < FF; ++j) o2[j] = B2[j];
#pragma unroll 2
  for (int i2 = 0; i2 < 10; ++i2) {
    half2v act = o1p[i2];
    const unsigned int* wr = q2 + i2 * FF;
#pragma unroll
    for (int j = 0; j < FF; ++j) o2[j] = fdot2(act, u2h2(wr[j]), o2[j]);
  }
  float4* op = (float4*)(out2 + (size_t)n * DD + t * FF);
#pragma unroll
  for (int i = 0; i < 5; ++i) op[i] = make_float4(o2[i*4], o2[i*4+1], o2[i*4+2], o2[i*4+3]);
}

// ---------------- lin layer + BN column partial sums ----------------
__global__ __launch_bounds__(320) void k_lin(const float* __restrict__ out2,
                                             const float* __restrict__ lin_w,
                                             const float* __restrict__ lin_b,
                                             float* __restrict__ outl,
                                             float* __restrict__ colsum, int l) {
  __shared__ float Wl[DD * DD];
  __shared__ float rowbuf[4 * DD];
  __shared__ float red[320];
  int tid = threadIdx.x;
  for (int i = tid; i < DD * DD; i += 320) Wl[i] = lin_w[(size_t)l * DD * DD + i];
  __syncthreads();
  int nl = tid / DD, d = tid - nl * DD;
  float bias = lin_b[l * DD + d];
  float bsum = 0.f, bsq = 0.f;
  for (int base = blockIdx.x * 4; base < NN; base += gridDim.x * 4) {
    int gi = base * DD + tid;
    rowbuf[tid] = (gi < NN * DD) ? out2[gi] : 0.f;
    __syncthreads();
    int n = base + nl;
    if (n < NN) {
      float acc = bias;
#pragma unroll
      for (int i = 0; i < DD; ++i) acc = fmaf(rowbuf[nl * DD + i], Wl[i * DD + d], acc);
      outl[(size_t)n * DD + d] = acc;
      bsum += acc; bsq += acc * acc;
    }
    __syncthreads();
  }
  red[tid] = bsum;
  __syncthreads();
  if (tid < DD) {
    float s = red[tid] + red[tid + DD] + red[tid + 2 * DD] + red[tid + 3 * DD];
    atomicAdd(&colsum[d], s);
  }
  __syncthreads();
  red[tid] = bsq;
  __syncthreads();
  if (tid < DD) {
    float s = red[tid] + red[tid + DD] + red[tid + 2 * DD] + red[tid + 3 * DD];
    atomicAdd(&colsum[DD + d], s);
  }
}

// ---------------- BN finalize ----------------
__global__ __launch_bounds__(128) void k_bnfinal(const float* __restrict__ colsum,
                                                 const float* __restrict__ bn_g,
                                                 const float* __restrict__ bn_b,
                                                 float* __restrict__ bnsc, int l) {
  int d = threadIdx.x;
  if (d >= DD) return;
  float mu = colsum[d] * (1.0f / NN);
  float var = colsum[DD + d] * (1.0f / NN) - mu * mu;
  float sc = bn_g[l * DD + d] * rsqrtf(var + 1e-5f);
  bnsc[d] = sc;
  bnsc[DD + d] = bn_b[l * DD + d] - mu * sc;
}

// ---------------- BN apply + relu + residual into h ----------------
__global__ __launch_bounds__(256) void k_bnapply(const float* __restrict__ outl,
                                                 const float* __restrict__ bnsc,
                                                 float* __restrict__ h) {
  int idx = blockIdx.x * 256 + threadIdx.x;
  if (idx >= NN * DD) return;
  int d = idx % DD;
  float v = fmaf(outl[idx], bnsc[d], bnsc[DD + d]);
  h[idx] += fmaxf(v, 0.f);
}

// ---------------- graph pooling ----------------
__global__ __launch_bounds__(256) void k_gcnt(const int* __restrict__ batch, int* __restrict__ gcnt) {
  __shared__ int hcnt[GG];
  int tid = threadIdx.x;
  if (tid < GG) hcnt[tid] = 0;
  __syncthreads();
  int n = blockIdx.x * 256 + tid;
  if (n < NN) atomicAdd(&hcnt[batch[n]], 1);
  __syncthreads();
  if (tid < GG && hcnt[tid] > 0) atomicAdd(&gcnt[tid], hcnt[tid]);
}

__global__ void k_gstart(const int* __restrict__ gcnt, int* __restrict__ gstart) {
  if (threadIdx.x == 0 && blockIdx.x == 0) {
    int acc = 0;
    for (int g = 0; g < GG; ++g) { gstart[g] = acc; acc += gcnt[g]; }
  }
}

__global__ __launch_bounds__(320) void k_gmean(const float* __restrict__ h,
                                               const int* __restrict__ gstart,
                                               const int* __restrict__ gcnt,
                                               float* __restrict__ gbuf) {
  __shared__ float red[320];
  int g = blockIdx.x, tid = threadIdx.x;
  int nl = tid / DD, d = tid - nl * DD;
  int start = gstart[g], c = gcnt[g];
  float acc = 0.f;
  for (int r = start + nl; r < start + c; r += 4) acc += h[(size_t)r * DD + d];
  red[tid] = acc;
  __syncthreads();
  if (tid < DD) {
    float s = red[tid] + red[tid + DD] + red[tid + 2 * DD] + red[tid + 3 * DD];
    float cf = (c > 0) ? (float)c : 1.0f;
    gbuf[g * DD + tid] = s / cf;
  }
}

// ---------------- final MLP (tiny) ----------------
__global__ __launch_bounds__(64) void k_mlp(const float* __restrict__ gbuf,
                                            const float* __restrict__ w1, const float* __restrict__ b1,
                                            const float* __restrict__ w2, const float* __restrict__ b2,
                                            const float* __restrict__ w3, const float* __restrict__ b3,
                                            float* __restrict__ out) {
  __shared__ float row[DD];
  __shared__ float t1[40];
  __shared__ float t2[20];
  int g = blockIdx.x, tid = threadIdx.x;
  for (int i = tid; i < DD; i += 64) row[i] = gbuf[g * DD + i];
  __syncthreads();
  if (tid < 40) {
    float acc = b1[tid];
#pragma unroll
    for (int i = 0; i < DD; ++i) acc = fmaf(row[i], w1[i * 40 + tid], acc);
    t1[tid] = fmaxf(acc, 0.f);
  }
  __syncthreads();
  if (tid < 20) {
    float acc = b2[tid];
#pragma unroll
    for (int i = 0; i < 40; ++i) acc = fmaf(t1[i], w2[i * 20 + tid], acc);
    t2[tid] = fmaxf(acc, 0.f);
  }
  __syncthreads();
  if (tid == 0) {
    float acc = b3[0];
#pragma unroll
    for (int i = 0; i < 20; ++i) acc = fmaf(t2[i], w3[i], acc);
    out[g] = acc;
  }
}

extern "C" void kernel_launch(void* const* d_in, const int* in_sizes, int n_in,
                              void* d_out, int out_size, void* d_ws, size_t ws_size,
                              hipStream_t stream) {
  const int*   x         = (const int*)d_in[0];
  const int*   ei        = (const int*)d_in[1];
  const int*   batch     = (const int*)d_in[2];
  const float* edge_attr = (const float*)d_in[3];
  const float* atom_emb  = (const float*)d_in[4];
  const float* edge_w    = (const float*)d_in[5];
  const float* edge_b    = (const float*)d_in[6];
  const float* pre_w1    = (const float*)d_in[7];
  const float* pre_b1    = (const float*)d_in[8];
  const float* pre_w2    = (const float*)d_in[9];
  const float* pre_b2    = (const float*)d_in[10];
  const float* post_w1   = (const float*)d_in[11];
  const float* post_b1   = (const float*)d_in[12];
  const float* post_w2   = (const float*)d_in[13];
  const float* post_b2   = (const float*)d_in[14];
  const float* lin_w     = (const float*)d_in[15];
  const float* lin_b     = (const float*)d_in[16];
  const float* bn_g      = (const float*)d_in[17];
  const float* bn_b      = (const float*)d_in[18];
  const float* mlp_w1    = (const float*)d_in[19];
  const float* mlp_b1    = (const float*)d_in[20];
  const float* mlp_w2    = (const float*)d_in[21];
  const float* mlp_b2    = (const float*)d_in[22];
  const float* mlp_w3    = (const float*)d_in[23];
  const float* mlp_b3    = (const float*)d_in[24];
  float* out = (float*)d_out;

  // workspace carve-up (~116 MB)
  char* ws = (char*)d_ws;
  size_t off = 0;
  auto alloc = [&](size_t bytes) -> void* {
    void* p = ws + off;
    off += (bytes + 15) & ~(size_t)15;
    return p;
  };
  float* h       = (float*)alloc((size_t)NN * DD * 4);           // 16 MB
  float* out2    = (float*)alloc((size_t)NN * DD * 4);           // 16 MB
  unsigned short* predD = (unsigned short*)alloc((size_t)NN * DD * 2); // 8 MB bf16
  unsigned short* predS = (unsigned short*)alloc((size_t)NN * DD * 2); // 8 MB bf16
  int*   csr_src = (int*)alloc((size_t)EE * 4);                  // 3.2 MB
  int*   csr_eid = (int*)alloc((size_t)EE * 4);                  // 3.2 MB
  int*   csr_dst = (int*)alloc((size_t)EE * 4);                  // 3.2 MB
  unsigned int* ea16 = (unsigned int*)alloc((size_t)EE * 8 * 4); // 25.6 MB f16 CSR-ordered ea
  int*   row_ptr = (int*)alloc((size_t)(NN + 1) * 4);
  int*   cnt     = (int*)alloc((size_t)NN * 4);
  int*   cursor  = (int*)alloc((size_t)NN * 4);
  float* inv_deg = (float*)alloc((size_t)NN * 4);
  float* s1a     = (float*)alloc((size_t)NN * 4);
  float* s2a     = (float*)alloc((size_t)NN * 4);
  float* colsum  = (float*)alloc(2 * DD * 4);
  float* bnsc    = (float*)alloc(2 * DD * 4);
  float* gbuf    = (float*)alloc((size_t)GG * DD * 4);
  unsigned int* wcpk  = (unsigned int*)alloc((size_t)TT * FF * 8 * 4);
  unsigned int* w2pk  = (unsigned int*)alloc((size_t)TT * FF * 10 * 4);
  unsigned int* q1pk  = (unsigned int*)alloc((size_t)TT * 120 * FF * 4);
  unsigned int* q2pk  = (unsigned int*)alloc((size_t)TT * 10 * FF * 4);
  float* biasc   = (float*)alloc((size_t)TT * FF * 4);
  int*   bsum    = (int*)alloc((size_t)SCAN_B * 4);
  int*   boff    = (int*)alloc((size_t)SCAN_B * 4);
  int*   gcnt    = (int*)alloc((size_t)GG * 4);
  int*   gstart  = (int*)alloc((size_t)(GG + 1) * 4);
  unsigned short* aggbuf = (unsigned short*)alloc((size_t)NN * 4 * 80 * 2); // 32 MB bf16
  float* outl = (float*)aggbuf; // alias: aggbuf dead after k_post2; outl dead before next k_preagg
  (void)in_sizes; (void)n_in; (void)out_size; (void)ws_size;

  hipMemsetAsync(cnt, 0, (size_t)NN * 4, stream);
  k_h<<<(NN * DD + 255) / 256, 256, 0, stream>>>(x, atom_emb, h);
  k_deg<<<(EE + 255) / 256, 256, 0, stream>>>(ei, cnt);
  k_scan_sum<<<SCAN_B, 1024, 0, stream>>>(cnt, bsum);
  k_scan_top<<<1, 64, 0, stream>>>(bsum, boff, row_ptr);
  k_scan_apply<<<SCAN_B, 1024, 0, stream>>>(cnt, boff, row_ptr, cursor);
  k_csrfill<<<(EE + 255) / 256, 256, 0, stream>>>(ei, cursor, csr_src, csr_eid, csr_dst);
  k_eagather<<<(EE + 255) / 256, 256, 0, stream>>>(csr_eid, edge_attr, ea16);
  k_nodeparams<<<(NN + 255) / 256, 256, 0, stream>>>(cnt, inv_deg, s1a, s2a);

  int tilesA = (NN + TILE_N - 1) / TILE_N;   // 3125
  int tilesP = (NN + 255) / 256;             // 196
  for (int l = 0; l < LL; ++l) {
    k_wcomb<<<TT, 64, 0, stream>>>(edge_w, edge_b, pre_w1, pre_b1, pre_w2, wcpk, w2pk, biasc, l);
    k_postpk<<<TT, 64, 0, stream>>>(post_w1, post_w2, q1pk, q2pk, l);
    k_prenode<<<(NN + 63) / 64, 256, 0, stream>>>(h, pre_w1, biasc, predD, predS, l);
    k_preagg<<<tilesA, 256, 0, stream>>>(predD, predS, ea16, csr_src, csr_dst, row_ptr,
        inv_deg, wcpk, w2pk, pre_b2, aggbuf, l);
    k_post2<<<tilesP * TT, 256, 0, stream>>>(h, aggbuf, s1a, s2a,
        post_w1, post_b1, q1pk, q2pk, post_b2, out2, l, tilesP);
    hipMemsetAsync(colsum, 0, 2 * DD * 4, stream);
    k_lin<<<512, 320, 0, stream>>>(out2, lin_w, lin_b, outl, colsum, l);
    k_bnfinal<<<1, 128, 0, stream>>>(colsum, bn_g, bn_b, bnsc, l);
    k_bnapply<<<(NN * DD + 255) / 256, 256, 0, stream>>>(outl, bnsc, h);
  }

  hipMemsetAsync(gcnt, 0, (size_t)GG * 4, stream);
  k_gcnt<<<(NN + 255) / 256, 256, 0, stream>>>(batch, gcnt);
  k_gstart<<<1, 64, 0, stream>>>(gcnt, gstart);
  k_gmean<<<GG, 320, 0, stream>>>(h, gstart, gcnt, gbuf);
  k_mlp<<<GG, 64, 0, stream>>>(gbuf, mlp_w1, mlp_b1, mlp_w2, mlp_b2, mlp_w3, mlp_b3, out);
}

// Round 9
// 1447.240 us; speedup vs baseline: 1.3231x; 1.0173x over previous
//
#include <hip/hip_runtime.h>
#include <hip/hip_bf16.h>

// Problem constants (from reference)
#define NN 50000
#define EE 800000
#define GG 128
#define LL 4
#define TT 4
#define FF 20
#define DD 80
#define SCAN_B ((NN + 1023) / 1024)   // 49
#define TILE_N 16                     // nodes per k_preagg tile (avg 256 slots)
#define ITEMS (TILE_N * 10)           // 160 (node, ch-pair) reduce items per tower
static constexpr float AVG_LOG = 2.8332133440562162f; // ln(17)

typedef __fp16 half2v __attribute__((ext_vector_type(2)));

__device__ __forceinline__ float bf2f(unsigned short u) {
  return __uint_as_float((unsigned)u << 16);
}
__device__ __forceinline__ unsigned short f2bf(float f) {
  __hip_bfloat16 b = __float2bfloat16(f); // RNE
  return *(unsigned short*)&b;
}
__device__ __forceinline__ half2v pkrtz(float a, float b) {
#if __has_builtin(__builtin_amdgcn_cvt_pkrtz)
  return __builtin_amdgcn_cvt_pkrtz(a, b);
#else
  half2v h; h.x = (__fp16)a; h.y = (__fp16)b; return h;
#endif
}
__device__ __forceinline__ float fdot2(half2v a, half2v b, float c) {
#if __has_builtin(__builtin_amdgcn_fdot2)
  return __builtin_amdgcn_fdot2(a, b, c, false);
#else
  return fmaf((float)a.x, (float)b.x, fmaf((float)a.y, (float)b.y, c));
#endif
}
__device__ __forceinline__ half2v u2h2(unsigned int u) {
  return __builtin_bit_cast(half2v, u);
}
__device__ __forceinline__ unsigned int h22u(half2v h) {
  return __builtin_bit_cast(unsigned int, h);
}
__device__ __forceinline__ unsigned int packh2_rne(float a, float b) {
  half2v h; h.x = (__fp16)a; h.y = (__fp16)b; // RNE casts for weights
  return h22u(h);
}
__device__ __forceinline__ unsigned int pack_bf16(float a, float b) {
  return (unsigned int)f2bf(a) | ((unsigned int)f2bf(b) << 16);
}

// ---------------- h init: h[n,d] = sum_i atom_emb[i, x[n,i], d] ----------------
__global__ __launch_bounds__(256) void k_h(const int* __restrict__ x,
                                           const float* __restrict__ atom_emb,
                                           float* __restrict__ h) {
  int idx = blockIdx.x * 256 + threadIdx.x;
  if (idx >= NN * DD) return;
  int n = idx / DD, d = idx - n * DD;
  const int* xr = x + n * 9;
  float acc = 0.f;
#pragma unroll
  for (int i = 0; i < 9; ++i) {
    int v = xr[i];
    acc += atom_emb[(i * 16 + v) * DD + d];
  }
  h[idx] = acc;
}

// ---------------- degree count ----------------
__global__ __launch_bounds__(256) void k_deg(const int* __restrict__ ei, int* __restrict__ cnt) {
  int e = blockIdx.x * 256 + threadIdx.x;
  if (e >= EE) return;
  atomicAdd(&cnt[ei[EE + e]], 1); // dst = edge_index[1][e]
}

// ---------------- hierarchical exclusive scan ----------------
__global__ __launch_bounds__(1024) void k_scan_sum(const int* __restrict__ cnt, int* __restrict__ bsum) {
  __shared__ int red[1024];
  int tid = threadIdx.x;
  int i = blockIdx.x * 1024 + tid;
  red[tid] = (i < NN) ? cnt[i] : 0;
  __syncthreads();
  for (int off = 512; off > 0; off >>= 1) {
    if (tid < off) red[tid] += red[tid + off];
    __syncthreads();
  }
  if (tid == 0) bsum[blockIdx.x] = red[0];
}

__global__ void k_scan_top(const int* __restrict__ bsum, int* __restrict__ boff,
                           int* __restrict__ row_ptr) {
  if (threadIdx.x == 0 && blockIdx.x == 0) {
    int acc = 0;
    for (int b = 0; b < SCAN_B; ++b) { boff[b] = acc; acc += bsum[b]; }
    row_ptr[NN] = acc;
  }
}

__global__ __launch_bounds__(1024) void k_scan_apply(const int* __restrict__ cnt,
                                                     const int* __restrict__ boff,
                                                     int* __restrict__ row_ptr,
                                                     int* __restrict__ cursor) {
  __shared__ int sm[1024];
  int tid = threadIdx.x;
  int i = blockIdx.x * 1024 + tid;
  int v = (i < NN) ? cnt[i] : 0;
  sm[tid] = v;
  __syncthreads();
  for (int off = 1; off < 1024; off <<= 1) {
    int t = (tid >= off) ? sm[tid - off] : 0;
    __syncthreads();
    sm[tid] += t;
    __syncthreads();
  }
  int excl = boff[blockIdx.x] + sm[tid] - v;
  if (i < NN) { row_ptr[i] = excl; cursor[i] = excl; }
}

// ---------------- CSR fill: slot -> src / eid / dst (split arrays) ----------------
__global__ __launch_bounds__(256) void k_csrfill(const int* __restrict__ ei,
                                                 int* __restrict__ cursor,
                                                 int* __restrict__ csr_src,
                                                 int* __restrict__ csr_eid,
                                                 int* __restrict__ csr_dst) {
  int e = blockIdx.x * 256 + threadIdx.x;
  if (e >= EE) return;
  int dst = ei[EE + e];
  int slot = atomicAdd(&cursor[dst], 1);
  csr_src[slot] = ei[e];
  csr_eid[slot] = e;
  csr_dst[slot] = dst;
}

// ---------------- one-time edge_attr gather into CSR slot order, f16 pairs ----------------
__global__ __launch_bounds__(256) void k_eagather(const int* __restrict__ csr_eid,
                                                  const float* __restrict__ edge_attr,
                                                  unsigned int* __restrict__ ea16) {
  int sl = blockIdx.x * 256 + threadIdx.x;
  if (sl >= EE) return;
  int e = csr_eid[sl];
  const float4* ap = (const float4*)(edge_attr + (size_t)e * 16);
  uint4 o0, o1;
  float4 v0 = ap[0], v1 = ap[1], v2 = ap[2], v3 = ap[3];
  o0.x = packh2_rne(v0.x, v0.y); o0.y = packh2_rne(v0.z, v0.w);
  o0.z = packh2_rne(v1.x, v1.y); o0.w = packh2_rne(v1.z, v1.w);
  o1.x = packh2_rne(v2.x, v2.y); o1.y = packh2_rne(v2.z, v2.w);
  o1.z = packh2_rne(v3.x, v3.y); o1.w = packh2_rne(v3.z, v3.w);
  uint4* op = (uint4*)(ea16 + (size_t)sl * 8);
  op[0] = o0; op[1] = o1;
}

// ---------------- per-node params ----------------
__global__ __launch_bounds__(256) void k_nodeparams(const int* __restrict__ cnt,
                                                    float* __restrict__ inv_deg,
                                                    float* __restrict__ s1a,
                                                    float* __restrict__ s2a) {
  int n = blockIdx.x * 256 + threadIdx.x;
  if (n >= NN) return;
  int c = cnt[n];
  float deg = (c > 0) ? (float)c : 1.0f;
  inv_deg[n] = 1.0f / deg;
  float logd = logf(deg + 1.0f);
  s1a[n] = logd / AVG_LOG;
  s2a[n] = AVG_LOG / logd;
}

// ---------------- per-layer weight composition + f16 pair packing ----------------
__global__ __launch_bounds__(64) void k_wcomb(const float* __restrict__ edge_w,
                                              const float* __restrict__ edge_b,
                                              const float* __restrict__ pre_w1,
                                              const float* __restrict__ pre_b1,
                                              const float* __restrict__ pre_w2,
                                              unsigned int* __restrict__ wcpk,
                                              unsigned int* __restrict__ w2pk,
                                              float* __restrict__ biasc, int l) {
  int t = blockIdx.x;
  int wt = l * TT + t;
  const float* W1 = pre_w1 + (size_t)wt * 1200; // [60][20]
  const float* W2 = pre_w2 + (size_t)wt * 400;  // [20][20]
  const float* ew = edge_w + (size_t)l * 16 * FF;
  const float* eb = edge_b + (size_t)l * FF;
  int j = threadIdx.x;
  if (j >= FF) return;
  float col[16];
  for (int i = 0; i < 16; ++i) {
    float acc = 0.f;
#pragma unroll
    for (int f = 0; f < FF; ++f) acc = fmaf(ew[i * FF + f], W1[(40 + f) * FF + j], acc);
    col[i] = acc;
  }
#pragma unroll
  for (int i2 = 0; i2 < 8; ++i2)
    wcpk[((size_t)t * FF + j) * 8 + i2] = packh2_rne(col[2 * i2], col[2 * i2 + 1]);
#pragma unroll
  for (int i2 = 0; i2 < 10; ++i2)
    w2pk[((size_t)t * FF + j) * 10 + i2] = packh2_rne(W2[(2 * i2) * FF + j], W2[(2 * i2 + 1) * FF + j]);
  float b = pre_b1[wt * FF + j];
#pragma unroll
  for (int f = 0; f < FF; ++f) b = fmaf(eb[f], W1[(40 + f) * FF + j], b);
  biasc[t * FF + j] = b;
}

// ---------------- post-MLP weight packing: Q1 rows [20,260) + Q2 as f16 pairs ----------------
__global__ __launch_bounds__(64) void k_postpk(const float* __restrict__ post_w1,
                                               const float* __restrict__ post_w2,
                                               unsigned int* __restrict__ q1pk,
                                               unsigned int* __restrict__ q2pk, int l) {
  int t = blockIdx.x;
  int wt = l * TT + t;
  const float* Q1 = post_w1 + (size_t)wt * 5200;
  const float* Q2 = post_w2 + (size_t)wt * 400;
  int j = threadIdx.x;
  if (j >= FF) return;
  for (int i2 = 0; i2 < 120; ++i2) {
    int blk = i2 / 40, k = i2 - blk * 40;
    int r0 = 20 + 80 * blk + 2 * k;
    q1pk[((size_t)t * 120 + i2) * FF + j] = packh2_rne(Q1[r0 * FF + j], Q1[(r0 + 1) * FF + j]);
  }
#pragma unroll
  for (int i2 = 0; i2 < 10; ++i2)
    q2pk[((size_t)t * 10 + i2) * FF + j] = packh2_rne(Q2[(2 * i2) * FF + j], Q2[(2 * i2 + 1) * FF + j]);
}

// ---------------- per-node pre contributions (bf16 out) ----------------
__global__ __launch_bounds__(256) void k_prenode(
    const float* __restrict__ h, const float* __restrict__ pre_w1,
    const float* __restrict__ biasc,
    unsigned short* __restrict__ predD, unsigned short* __restrict__ predS, int l) {
  int tid = threadIdx.x;
  int t = tid >> 6, lane = tid & 63;
  int n = blockIdx.x * 64 + lane;
  if (n >= NN) return;
  int wt_u = __builtin_amdgcn_readfirstlane(l * TT + t);
  const float* W1 = pre_w1 + (size_t)wt_u * 1200;
  const float* bc = biasc + t * FF;
  float xt[FF];
  {
    const float4* pp = (const float4*)(h + (size_t)n * DD + t * FF);
#pragma unroll
    for (int i = 0; i < 5; ++i) { float4 v = pp[i]; xt[i*4]=v.x; xt[i*4+1]=v.y; xt[i*4+2]=v.z; xt[i*4+3]=v.w; }
  }
  float d[FF], s[FF];
#pragma unroll
  for (int j = 0; j < FF; ++j) { d[j] = bc[j]; s[j] = 0.f; }
#pragma unroll
  for (int i = 0; i < FF; ++i) {
    float a = xt[i];
#pragma unroll
    for (int j = 0; j < FF; ++j) {
      d[j] = fmaf(a, W1[i * FF + j], d[j]);
      s[j] = fmaf(a, W1[(FF + i) * FF + j], s[j]);
    }
  }
  ushort4* pd = (ushort4*)(predD + (size_t)n * DD + t * FF);
  ushort4* ps = (ushort4*)(predS + (size_t)n * DD + t * FF);
#pragma unroll
  for (int i = 0; i < 5; ++i) {
    pd[i] = make_ushort4(f2bf(d[i*4]), f2bf(d[i*4+1]), f2bf(d[i*4+2]), f2bf(d[i*4+3]));
    ps[i] = make_ushort4(f2bf(s[i*4]), f2bf(s[i*4+1]), f2bf(s[i*4+2]), f2bf(s[i*4+3]));
  }
}

// ---------------- FUSED edge pre-MLP + aggregation, tower-colocated, balanced reduce ----------------
__global__ __launch_bounds__(256, 4) void k_preagg(
    const unsigned short* __restrict__ predD,
    const unsigned short* __restrict__ predS,
    const unsigned int* __restrict__ ea16,
    const int* __restrict__ csr_src,
    const int* __restrict__ csr_dst,
    const int* __restrict__ row_ptr,
    const float* __restrict__ inv_deg,
    const unsigned int* __restrict__ wcpk,
    const unsigned int* __restrict__ w2pk,
    const float* __restrict__ pre_b2,
    unsigned short* __restrict__ aggbuf,
    int l) {
  __shared__ int nbr[TILE_N + 1];
  __shared__ float dDs[TT][TILE_N * FF];      // 5.1 KB
  __shared__ unsigned int m2w[TT][64 * 11];   // 11.3 KB, stride-11: conflict-free
  int tid = threadIdx.x;
  int t = tid >> 6, lane = tid & 63;
  int t_u = __builtin_amdgcn_readfirstlane(t);
  int n0 = blockIdx.x * TILE_N;
  const unsigned int* Wcp = wcpk + (size_t)t_u * FF * 8;
  const unsigned int* W2p = w2pk + (size_t)t_u * FF * 10;
  const float* b2 = pre_b2 + (size_t)(l * TT + t_u) * FF;

  if (tid <= TILE_N) {
    int node = n0 + tid; if (node > NN) node = NN;
    nbr[tid] = row_ptr[node];
  }
  for (int i = lane; i < TILE_N * FF; i += 64) {
    int ni = i / FF, ch = i - ni * FF;
    int node = n0 + ni;
    dDs[t][i] = (node < NN) ? bf2f(predD[(size_t)node * DD + t_u * FF + ch]) : 0.f;
  }
  __syncthreads();
  int tbeg = nbr[0], tend = nbr[TILE_N];

  int itN[3], itP[3], itB[3], itE[3];
#pragma unroll
  for (int k = 0; k < 3; ++k) {
    int it = lane + 64 * k;
    bool v = it < ITEMS;
    int nd = v ? (it / 10) : 0;
    itN[k] = nd;
    itP[k] = v ? (it - nd * 10) : 0;
    itB[k] = v ? nbr[nd] : 0;
    itE[k] = v ? nbr[nd + 1] : 0;
  }
  float sS[3][2], sQ[3][2], sN[3][2], sX[3][2];
#pragma unroll
  for (int k = 0; k < 3; ++k) {
    sS[k][0] = 0.f; sS[k][1] = 0.f; sQ[k][0] = 0.f; sQ[k][1] = 0.f;
    sN[k][0] = 3.4e38f; sN[k][1] = 3.4e38f; sX[k][0] = -3.4e38f; sX[k][1] = -3.4e38f;
  }

  for (int wb = tbeg; wb < tend; wb += 64) {
    int p = wb + lane;
    if (p < tend) {
      int src = csr_src[p];
      int ni = csr_dst[p] - n0;
      float m1[FF];
      {
        const float4* dd = (const float4*)(&dDs[t][ni * FF]);
        const ushort4* qq = (const ushort4*)(predS + (size_t)src * DD + t_u * FF);
#pragma unroll
        for (int i = 0; i < 5; ++i) {
          float4 d4 = dd[i];
          ushort4 v = qq[i];
          m1[i*4+0] = d4.x + bf2f(v.x);
          m1[i*4+1] = d4.y + bf2f(v.y);
          m1[i*4+2] = d4.z + bf2f(v.z);
          m1[i*4+3] = d4.w + bf2f(v.w);
        }
      }
      half2v eap[8];
      {
        const uint4* ep = (const uint4*)(ea16 + (size_t)p * 8);
        uint4 e0 = ep[0], e1 = ep[1];
        eap[0] = u2h2(e0.x); eap[1] = u2h2(e0.y); eap[2] = u2h2(e0.z); eap[3] = u2h2(e0.w);
        eap[4] = u2h2(e1.x); eap[5] = u2h2(e1.y); eap[6] = u2h2(e1.z); eap[7] = u2h2(e1.w);
      }
#pragma unroll
      for (int j = 0; j < FF; ++j) {
        float c = m1[j];
#pragma unroll
        for (int i2 = 0; i2 < 8; ++i2) c = fdot2(eap[i2], u2h2(Wcp[j * 8 + i2]), c);
        m1[j] = c;
      }
      half2v mp[10];
#pragma unroll
      for (int pr = 0; pr < 10; ++pr)
        mp[pr] = pkrtz(fmaxf(m1[2*pr], 0.f), fmaxf(m1[2*pr+1], 0.f));
      float m2[FF];
#pragma unroll
      for (int j = 0; j < FF; ++j) {
        float c = b2[j];
#pragma unroll
        for (int i2 = 0; i2 < 10; ++i2) c = fdot2(mp[i2], u2h2(W2p[j * 10 + i2]), c);
        m2[j] = c;
      }
      unsigned int* row = &m2w[t][lane * 11];
#pragma unroll
      for (int pr = 0; pr < 10; ++pr) row[pr] = h22u(pkrtz(m2[2*pr], m2[2*pr+1]));
    }
    __syncthreads();
    int we = (wb + 64 < tend) ? (wb + 64) : tend;
#pragma unroll
    for (int k = 0; k < 3; ++k) {
      int lo = itB[k] > wb ? itB[k] : wb;
      int hi = itE[k] < we ? itE[k] : we;
      for (int s = lo; s < hi; ++s) {
        half2v h2 = u2h2(m2w[t][(s - wb) * 11 + itP[k]]);
        float v0 = (float)h2.x, v1 = (float)h2.y;
        sS[k][0] += v0; sQ[k][0] = fmaf(v0, v0, sQ[k][0]);
        sN[k][0] = fminf(sN[k][0], v0); sX[k][0] = fmaxf(sX[k][0], v0);
        sS[k][1] += v1; sQ[k][1] = fmaf(v1, v1, sQ[k][1]);
        sN[k][1] = fminf(sN[k][1], v1); sX[k][1] = fmaxf(sX[k][1], v1);
      }
    }
    __syncthreads();
  }

#pragma unroll
  for (int k = 0; k < 3; ++k) {
    int it = lane + 64 * k;
    if (it < ITEMS) {
      int n = n0 + itN[k];
      if (n < NN) {
        float inv = inv_deg[n];
        bool noe = (itE[k] <= itB[k]);
        float mu0 = sS[k][0] * inv, mu1 = sS[k][1] * inv;
        float sd0 = sqrtf(fmaxf(sQ[k][0] * inv - mu0 * mu0, 0.f) + 1e-5f);
        float sd1 = sqrtf(fmaxf(sQ[k][1] * inv - mu1 * mu1, 0.f) + 1e-5f);
        float mn0 = noe ? 0.f : sN[k][0], mn1 = noe ? 0.f : sN[k][1];
        float mx0 = noe ? 0.f : sX[k][0], mx1 = noe ? 0.f : sX[k][1];
        unsigned short* ab = aggbuf + ((size_t)n * 4 + t_u) * 80;
        ((unsigned int*)(ab))[itP[k]]      = pack_bf16(mu0, mu1);
        ((unsigned int*)(ab + 20))[itP[k]] = pack_bf16(mn0, mn1);
        ((unsigned int*)(ab + 40))[itP[k]] = pack_bf16(mx0, mx1);
        ((unsigned int*)(ab + 60))[itP[k]] = pack_bf16(sd0, sd1);
      }
    }
  }
}

// ---------------- FUSED post-MLP + lin + BN colsum ----------------
// Block = 64 nodes x 4 towers (wave = tower). Phase A: post2 via dot2 into LDS
// rows[64][80] (out2 never touches HBM: -32 MB/layer). Phase B: 80x80 lin from
// LDS Wl. Phase C: BN colsum via LDS transpose reduce (pad-65), 1 atomic/d/block.
__global__ __launch_bounds__(256) void k_postlin(
    const float* __restrict__ h, const unsigned short* __restrict__ aggbuf,
    const float* __restrict__ s1a, const float* __restrict__ s2a,
    const float* __restrict__ post_w1, const float* __restrict__ post_b1,
    const unsigned int* __restrict__ q1pk, const unsigned int* __restrict__ q2pk,
    const float* __restrict__ post_b2,
    const float* __restrict__ lin_w, const float* __restrict__ lin_b,
    float* __restrict__ outl, float* __restrict__ colsum, int l) {
  __shared__ float Wl[DD * DD];       // 25.6 KB
  __shared__ float rows[DD * 65];     // 20.8 KB: [node*80+d] in A/B, [d*65+nl] in C
  int tid = threadIdx.x;
  int t = tid >> 6, lane = tid & 63;
  int t_u = __builtin_amdgcn_readfirstlane(t);
  int wt_u = __builtin_amdgcn_readfirstlane(l * TT + t);
  int n = blockIdx.x * 64 + lane;

  // issue Wl loads first so they overlap phase-A compute
  {
    const float4* src = (const float4*)(lin_w + (size_t)l * DD * DD);
    float4* dst = (float4*)Wl;
    for (int i = tid; i < DD * DD / 4; i += 256) dst[i] = src[i];
  }

  // ---- phase A: post2 for (node=lane, tower=t) ----
  const float* Q1 = post_w1 + (size_t)wt_u * 5200;
  const float* B1 = post_b1 + (size_t)wt_u * FF;
  const float* B2 = post_b2 + (size_t)wt_u * FF;
  const unsigned int* q1 = q1pk + (size_t)t_u * 120 * FF;
  const unsigned int* q2 = q2pk + (size_t)t_u * 10 * FF;
  if (n < NN) {
    float c1 = s1a[n], c2 = s2a[n];
    half2v c1p = pkrtz(c1, c1), c2p = pkrtz(c2, c2);
    float xt[FF];
    {
      const float4* pp = (const float4*)(h + (size_t)n * DD + t_u * FF);
#pragma unroll
      for (int i = 0; i < 5; ++i) { float4 v = pp[i]; xt[i*4]=v.x; xt[i*4+1]=v.y; xt[i*4+2]=v.z; xt[i*4+3]=v.w; }
    }
    half2v a0p[40];
    {
      const uint4* ap = (const uint4*)(aggbuf + ((size_t)n * 4 + t_u) * 80);
#pragma unroll
      for (int q = 0; q < 10; ++q) {
        uint4 v = ap[q];
        unsigned int w[4] = {v.x, v.y, v.z, v.w};
#pragma unroll
        for (int k = 0; k < 4; ++k) {
          unsigned int u = w[k];
          float lo = __uint_as_float(u << 16);
          float hi = __uint_as_float(u & 0xffff0000u);
          a0p[q * 4 + k] = pkrtz(lo, hi);
        }
      }
    }
    float o1[FF];
#pragma unroll
    for (int j = 0; j < FF; ++j) o1[j] = B1[j];
#pragma unroll
    for (int i = 0; i < FF; ++i) {
      float a = xt[i];
#pragma unroll
      for (int j = 0; j < FF; ++j) o1[j] = fmaf(a, Q1[i * FF + j], o1[j]);
    }
#pragma unroll 2
    for (int k = 0; k < 40; ++k) {
      half2v act = a0p[k];
      const unsigned int* wr = q1 + k * FF;
#pragma unroll
      for (int j = 0; j < FF; ++j) o1[j] = fdot2(act, u2h2(wr[j]), o1[j]);
    }
#pragma unroll 2
    for (int k = 0; k < 40; ++k) {
      half2v act = a0p[k] * c1p;
      const unsigned int* wr = q1 + (40 + k) * FF;
#pragma unroll
      for (int j = 0; j < FF; ++j) o1[j] = fdot2(act, u2h2(wr[j]), o1[j]);
    }
#pragma unroll 2
    for (int k = 0; k < 40; ++k) {
      half2v act = a0p[k] * c2p;
      const unsigned int* wr = q1 + (80 + k) * FF;
#pragma unroll
      for (int j = 0; j < FF; ++j) o1[j] = fdot2(act, u2h2(wr[j]), o1[j]);
    }
    half2v o1p[10];
#pragma unroll
    for (int i2 = 0; i2 < 10; ++i2)
      o1p[i2] = pkrtz(fmaxf(o1[2*i2], 0.f), fmaxf(o1[2*i2+1], 0.f));
    float o2[FF];
#pragma unroll
    for (int j = 0; j < FF; ++j) o2[j] = B2[j];
#pragma unroll 2
    for (int i2 = 0; i2 < 10; ++i2) {
      half2v act = o1p[i2];
      const unsigned int* wr = q2 + i2 * FF;
#pragma unroll
      for (int j = 0; j < FF; ++j) o2[j] = fdot2(act, u2h2(wr[j]), o2[j]);
    }
#pragma unroll
    for (int j = 0; j < FF; ++j) rows[lane * DD + t_u * FF + j] = o2[j];
  } else {
#pragma unroll
    for (int j = 0; j < FF; ++j) rows[lane * DD + t_u * FF + j] = 0.f;
  }
  __syncthreads();

  // ---- phase B: lin 80x80 from LDS ----
  int nl = tid >> 2;              // node index in block [0,64)
  int d0 = (tid & 3) * FF;        // output channel base
  int n2 = blockIdx.x * 64 + nl;
  float acc[FF];
#pragma unroll
  for (int j = 0; j < FF; ++j) acc[j] = lin_b[l * DD + d0 + j];
  for (int i = 0; i < DD; ++i) {
    float r = rows[nl * DD + i];
    const float* wl = &Wl[i * DD + d0];
#pragma unroll
    for (int j = 0; j < FF; ++j) acc[j] = fmaf(r, wl[j], acc[j]);
  }
  if (n2 < NN) {
    float4* op = (float4*)(outl + (size_t)n2 * DD + d0);
#pragma unroll
    for (int i = 0; i < 5; ++i) op[i] = make_float4(acc[i*4], acc[i*4+1], acc[i*4+2], acc[i*4+3]);
  }
  __syncthreads();   // all reads of rows done before phase C overwrites

  // ---- phase C: BN colsum (two-pass LDS transpose reduce) ----
  bool valid = (n2 < NN);
#pragma unroll
  for (int j = 0; j < FF; ++j) rows[(d0 + j) * 65 + nl] = valid ? acc[j] : 0.f;
  __syncthreads();
  if (tid < DD) {
    float s = 0.f;
    for (int k = 0; k < 64; ++k) s += rows[tid * 65 + k];
    atomicAdd(&colsum[tid], s);
  }
  __syncthreads();
#pragma unroll
  for (int j = 0; j < FF; ++j) rows[(d0 + j) * 65 + nl] = valid ? acc[j] * acc[j] : 0.f;
  __syncthreads();
  if (tid < DD) {
    float s = 0.f;
    for (int k = 0; k < 64; ++k) s += rows[tid * 65 + k];
    atomicAdd(&colsum[DD + tid], s);
  }
}

// ---------------- BN finalize ----------------
__global__ __launch_bounds__(128) void k_bnfinal(const float* __restrict__ colsum,
                                                 const float* __restrict__ bn_g,
                                                 const float* __restrict__ bn_b,
                                                 float* __restrict__ bnsc, int l) {
  int d = threadIdx.x;
  if (d >= DD) return;
  float mu = colsum[d] * (1.0f / NN);
  float var = colsum[DD + d] * (1.0f / NN) - mu * mu;
  float sc = bn_g[l * DD + d] * rsqrtf(var + 1e-5f);
  bnsc[d] = sc;
  bnsc[DD + d] = bn_b[l * DD + d] - mu * sc;
}

// ---------------- BN apply + relu + residual into h ----------------
__global__ __launch_bounds__(256) void k_bnapply(const float* __restrict__ outl,
                                                 const float* __restrict__ bnsc,
                                                 float* __restrict__ h) {
  int idx = blockIdx.x * 256 + threadIdx.x;
  if (idx >= NN * DD) return;
  int d = idx % DD;
  float v = fmaf(outl[idx], bnsc[d], bnsc[DD + d]);
  h[idx] += fmaxf(v, 0.f);
}

// ---------------- graph pooling ----------------
__global__ __launch_bounds__(256) void k_gcnt(const int* __restrict__ batch, int* __restrict__ gcnt) {
  __shared__ int hcnt[GG];
  int tid = threadIdx.x;
  if (tid < GG) hcnt[tid] = 0;
  __syncthreads();
  int n = blockIdx.x * 256 + tid;
  if (n < NN) atomicAdd(&hcnt[batch[n]], 1);
  __syncthreads();
  if (tid < GG && hcnt[tid] > 0) atomicAdd(&gcnt[tid], hcnt[tid]);
}

__global__ void k_gstart(const int* __restrict__ gcnt, int* __restrict__ gstart) {
  if (threadIdx.x == 0 && blockIdx.x == 0) {
    int acc = 0;
    for (int g = 0; g < GG; ++g) { gstart[g] = acc; acc += gcnt[g]; }
  }
}

__global__ __launch_bounds__(320) void k_gmean(const float* __restrict__ h,
                                               const int* __restrict__ gstart,
                                               const int* __restrict__ gcnt,
                                               float* __restrict__ gbuf) {
  __shared__ float red[320];
  int g = blockIdx.x, tid = threadIdx.x;
  int nl = tid / DD, d = tid - nl * DD;
  int start = gstart[g], c = gcnt[g];
  float acc = 0.f;
  for (int r = start + nl; r < start + c; r += 4) acc += h[(size_t)r * DD + d];
  red[tid] = acc;
  __syncthreads();
  if (tid < DD) {
    float s = red[tid] + red[tid + DD] + red[tid + 2 * DD] + red[tid + 3 * DD];
    float cf = (c > 0) ? (float)c : 1.0f;
    gbuf[g * DD + tid] = s / cf;
  }
}

// ---------------- final MLP (tiny) ----------------
__global__ __launch_bounds__(64) void k_mlp(const float* __restrict__ gbuf,
                                            const float* __restrict__ w1, const float* __restrict__ b1,
                                            const float* __restrict__ w2, const float* __restrict__ b2,
                                            const float* __restrict__ w3, const float* __restrict__ b3,
                                            float* __restrict__ out) {
  __shared__ float row[DD];
  __shared__ float t1[40];
  __shared__ float t2[20];
  int g = blockIdx.x, tid = threadIdx.x;
  for (int i = tid; i < DD; i += 64) row[i] = gbuf[g * DD + i];
  __syncthreads();
  if (tid < 40) {
    float acc = b1[tid];
#pragma unroll
    for (int i = 0; i < DD; ++i) acc = fmaf(row[i], w1[i * 40 + tid], acc);
    t1[tid] = fmaxf(acc, 0.f);
  }
  __syncthreads();
  if (tid < 20) {
    float acc = b2[tid];
#pragma unroll
    for (int i = 0; i < 40; ++i) acc = fmaf(t1[i], w2[i * 20 + tid], acc);
    t2[tid] = fmaxf(acc, 0.f);
  }
  __syncthreads();
  if (tid == 0) {
    float acc = b3[0];
#pragma unroll
    for (int i = 0; i < 20; ++i) acc = fmaf(t2[i], w3[i], acc);
    out[g] = acc;
  }
}

extern "C" void kernel_launch(void* const* d_in, const int* in_sizes, int n_in,
                              void* d_out, int out_size, void* d_ws, size_t ws_size,
                              hipStream_t stream) {
  const int*   x         = (const int*)d_in[0];
  const int*   ei        = (const int*)d_in[1];
  const int*   batch     = (const int*)d_in[2];
  const float* edge_attr = (const float*)d_in[3];
  const float* atom_emb  = (const float*)d_in[4];
  const float* edge_w    = (const float*)d_in[5];
  const float* edge_b    = (const float*)d_in[6];
  const float* pre_w1    = (const float*)d_in[7];
  const float* pre_b1    = (const float*)d_in[8];
  const float* pre_w2    = (const float*)d_in[9];
  const float* pre_b2    = (const float*)d_in[10];
  const float* post_w1   = (const float*)d_in[11];
  const float* post_b1   = (const float*)d_in[12];
  const float* post_w2   = (const float*)d_in[13];
  const float* post_b2   = (const float*)d_in[14];
  const float* lin_w     = (const float*)d_in[15];
  const float* lin_b     = (const float*)d_in[16];
  const float* bn_g      = (const float*)d_in[17];
  const float* bn_b      = (const float*)d_in[18];
  const float* mlp_w1    = (const float*)d_in[19];
  const float* mlp_b1    = (const float*)d_in[20];
  const float* mlp_w2    = (const float*)d_in[21];
  const float* mlp_b2    = (const float*)d_in[22];
  const float* mlp_w3    = (const float*)d_in[23];
  const float* mlp_b3    = (const float*)d_in[24];
  float* out = (float*)d_out;

  // workspace carve-up (~116 MB)
  char* ws = (char*)d_ws;
  size_t off = 0;
  auto alloc = [&](size_t bytes) -> void* {
    void* p = ws + off;
    off += (bytes + 15) & ~(size_t)15;
    return p;
  };
  float* h       = (float*)alloc((size_t)NN * DD * 4);           // 16 MB
  float* outl    = (float*)alloc((size_t)NN * DD * 4);           // 16 MB (post-lin output)
  unsigned short* predD = (unsigned short*)alloc((size_t)NN * DD * 2); // 8 MB bf16
  unsigned short* predS = (unsigned short*)alloc((size_t)NN * DD * 2); // 8 MB bf16
  int*   csr_src = (int*)alloc((size_t)EE * 4);                  // 3.2 MB
  int*   csr_eid = (int*)alloc((size_t)EE * 4);                  // 3.2 MB
  int*   csr_dst = (int*)alloc((size_t)EE * 4);                  // 3.2 MB
  unsigned int* ea16 = (unsigned int*)alloc((size_t)EE * 8 * 4); // 25.6 MB f16 CSR-ordered ea
  int*   row_ptr = (int*)alloc((size_t)(NN + 1) * 4);
  int*   cnt     = (int*)alloc((size_t)NN * 4);
  int*   cursor  = (int*)alloc((size_t)NN * 4);
  float* inv_deg = (float*)alloc((size_t)NN * 4);
  float* s1a     = (float*)alloc((size_t)NN * 4);
  float* s2a     = (float*)alloc((size_t)NN * 4);
  float* colsum  = (float*)alloc(2 * DD * 4);
  float* bnsc    = (float*)alloc(2 * DD * 4);
  float* gbuf    = (float*)alloc((size_t)GG * DD * 4);
  unsigned int* wcpk  = (unsigned int*)alloc((size_t)TT * FF * 8 * 4);
  unsigned int* w2pk  = (unsigned int*)alloc((size_t)TT * FF * 10 * 4);
  unsigned int* q1pk  = (unsigned int*)alloc((size_t)TT * 120 * FF * 4);
  unsigned int* q2pk  = (unsigned int*)alloc((size_t)TT * 10 * FF * 4);
  float* biasc   = (float*)alloc((size_t)TT * FF * 4);
  int*   bsum    = (int*)alloc((size_t)SCAN_B * 4);
  int*   boff    = (int*)alloc((size_t)SCAN_B * 4);
  int*   gcnt    = (int*)alloc((size_t)GG * 4);
  int*   gstart  = (int*)alloc((size_t)(GG + 1) * 4);
  unsigned short* aggbuf = (unsigned short*)alloc((size_t)NN * 4 * 80 * 2); // 32 MB bf16
  (void)in_sizes; (void)n_in; (void)out_size; (void)ws_size;

  hipMemsetAsync(cnt, 0, (size_t)NN * 4, stream);
  k_h<<<(NN * DD + 255) / 256, 256, 0, stream>>>(x, atom_emb, h);
  k_deg<<<(EE + 255) / 256, 256, 0, stream>>>(ei, cnt);
  k_scan_sum<<<SCAN_B, 1024, 0, stream>>>(cnt, bsum);
  k_scan_top<<<1, 64, 0, stream>>>(bsum, boff, row_ptr);
  k_scan_apply<<<SCAN_B, 1024, 0, stream>>>(cnt, boff, row_ptr, cursor);
  k_csrfill<<<(EE + 255) / 256, 256, 0, stream>>>(ei, cursor, csr_src, csr_eid, csr_dst);
  k_eagather<<<(EE + 255) / 256, 256, 0, stream>>>(csr_eid, edge_attr, ea16);
  k_nodeparams<<<(NN + 255) / 256, 256, 0, stream>>>(cnt, inv_deg, s1a, s2a);

  int tilesA = (NN + TILE_N - 1) / TILE_N;   // 3125
  int blocksPL = (NN + 63) / 64;             // 782
  for (int l = 0; l < LL; ++l) {
    k_wcomb<<<TT, 64, 0, stream>>>(edge_w, edge_b, pre_w1, pre_b1, pre_w2, wcpk, w2pk, biasc, l);
    k_postpk<<<TT, 64, 0, stream>>>(post_w1, post_w2, q1pk, q2pk, l);
    k_prenode<<<(NN + 63) / 64, 256, 0, stream>>>(h, pre_w1, biasc, predD, predS, l);
    k_preagg<<<tilesA, 256, 0, stream>>>(predD, predS, ea16, csr_src, csr_dst, row_ptr,
        inv_deg, wcpk, w2pk, pre_b2, aggbuf, l);
    hipMemsetAsync(colsum, 0, 2 * DD * 4, stream);
    k_postlin<<<blocksPL, 256, 0, stream>>>(h, aggbuf, s1a, s2a,
        post_w1, post_b1, q1pk, q2pk, post_b2, lin_w, lin_b, outl, colsum, l);
    k_bnfinal<<<1, 128, 0, stream>>>(colsum, bn_g, bn_b, bnsc, l);
    k_bnapply<<<(NN * DD + 255) / 256, 256, 0, stream>>>(outl, bnsc, h);
  }

  hipMemsetAsync(gcnt, 0, (size_t)GG * 4, stream);
  k_gcnt<<<(NN + 255) / 256, 256, 0, stream>>>(batch, gcnt);
  k_gstart<<<1, 64, 0, stream>>>(gcnt, gstart);
  k_gmean<<<GG, 320, 0, stream>>>(h, gstart, gcnt, gbuf);
  k_mlp<<<GG, 64, 0, stream>>>(gbuf, mlp_w1, mlp_b1, mlp_w2, mlp_b2, mlp_w3, mlp_b3, out);
}

// Round 10
// 1415.899 us; speedup vs baseline: 1.3524x; 1.0221x over previous
//
#include <hip/hip_runtime.h>
#include <hip/hip_bf16.h>

// Problem constants (from reference)
#define NN 50000
#define EE 800000
#define GG 128
#define LL 4
#define TT 4
#define FF 20
#define DD 80
#define SCAN_B ((NN + 1023) / 1024)   // 49
#define TILE_N 16                     // nodes per k_preagg tile (avg 256 slots)
#define ITEMS (TILE_N * 10)           // 160 (node, ch-pair) reduce items per tower
static constexpr float AVG_LOG = 2.8332133440562162f; // ln(17)

typedef __fp16 half2v __attribute__((ext_vector_type(2)));

__device__ __forceinline__ float bf2f(unsigned short u) {
  return __uint_as_float((unsigned)u << 16);
}
__device__ __forceinline__ unsigned short f2bf(float f) {
  __hip_bfloat16 b = __float2bfloat16(f); // RNE
  return *(unsigned short*)&b;
}
__device__ __forceinline__ half2v pkrtz(float a, float b) {
#if __has_builtin(__builtin_amdgcn_cvt_pkrtz)
  return __builtin_amdgcn_cvt_pkrtz(a, b);
#else
  half2v h; h.x = (__fp16)a; h.y = (__fp16)b; return h;
#endif
}
__device__ __forceinline__ float fdot2(half2v a, half2v b, float c) {
#if __has_builtin(__builtin_amdgcn_fdot2)
  return __builtin_amdgcn_fdot2(a, b, c, false);
#else
  return fmaf((float)a.x, (float)b.x, fmaf((float)a.y, (float)b.y, c));
#endif
}
__device__ __forceinline__ half2v u2h2(unsigned int u) {
  return __builtin_bit_cast(half2v, u);
}
__device__ __forceinline__ unsigned int h22u(half2v h) {
  return __builtin_bit_cast(unsigned int, h);
}
__device__ __forceinline__ unsigned int packh2_rne(float a, float b) {
  half2v h; h.x = (__fp16)a; h.y = (__fp16)b; // RNE casts for weights
  return h22u(h);
}
__device__ __forceinline__ unsigned int pack_bf16(float a, float b) {
  return (unsigned int)f2bf(a) | ((unsigned int)f2bf(b) << 16);
}

// ---------------- h init: h[n,d] = sum_i atom_emb[i, x[n,i], d] ----------------
__global__ __launch_bounds__(256) void k_h(const int* __restrict__ x,
                                           const float* __restrict__ atom_emb,
                                           float* __restrict__ h) {
  int idx = blockIdx.x * 256 + threadIdx.x;
  if (idx >= NN * DD) return;
  int n = idx / DD, d = idx - n * DD;
  const int* xr = x + n * 9;
  float acc = 0.f;
#pragma unroll
  for (int i = 0; i < 9; ++i) {
    int v = xr[i];
    acc += atom_emb[(i * 16 + v) * DD + d];
  }
  h[idx] = acc;
}

// ---------------- degree count ----------------
__global__ __launch_bounds__(256) void k_deg(const int* __restrict__ ei, int* __restrict__ cnt) {
  int e = blockIdx.x * 256 + threadIdx.x;
  if (e >= EE) return;
  atomicAdd(&cnt[ei[EE + e]], 1); // dst = edge_index[1][e]
}

// ---------------- hierarchical exclusive scan ----------------
__global__ __launch_bounds__(1024) void k_scan_sum(const int* __restrict__ cnt, int* __restrict__ bsum) {
  __shared__ int red[1024];
  int tid = threadIdx.x;
  int i = blockIdx.x * 1024 + tid;
  red[tid] = (i < NN) ? cnt[i] : 0;
  __syncthreads();
  for (int off = 512; off > 0; off >>= 1) {
    if (tid < off) red[tid] += red[tid + off];
    __syncthreads();
  }
  if (tid == 0) bsum[blockIdx.x] = red[0];
}

__global__ void k_scan_top(const int* __restrict__ bsum, int* __restrict__ boff,
                           int* __restrict__ row_ptr) {
  if (threadIdx.x == 0 && blockIdx.x == 0) {
    int acc = 0;
    for (int b = 0; b < SCAN_B; ++b) { boff[b] = acc; acc += bsum[b]; }
    row_ptr[NN] = acc;
  }
}

__global__ __launch_bounds__(1024) void k_scan_apply(const int* __restrict__ cnt,
                                                     const int* __restrict__ boff,
                                                     int* __restrict__ row_ptr,
                                                     int* __restrict__ cursor) {
  __shared__ int sm[1024];
  int tid = threadIdx.x;
  int i = blockIdx.x * 1024 + tid;
  int v = (i < NN) ? cnt[i] : 0;
  sm[tid] = v;
  __syncthreads();
  for (int off = 1; off < 1024; off <<= 1) {
    int t = (tid >= off) ? sm[tid - off] : 0;
    __syncthreads();
    sm[tid] += t;
    __syncthreads();
  }
  int excl = boff[blockIdx.x] + sm[tid] - v;
  if (i < NN) { row_ptr[i] = excl; cursor[i] = excl; }
}

// ---------------- CSR fill: slot -> src / eid / dst (split arrays) ----------------
__global__ __launch_bounds__(256) void k_csrfill(const int* __restrict__ ei,
                                                 int* __restrict__ cursor,
                                                 int* __restrict__ csr_src,
                                                 int* __restrict__ csr_eid,
                                                 int* __restrict__ csr_dst) {
  int e = blockIdx.x * 256 + threadIdx.x;
  if (e >= EE) return;
  int dst = ei[EE + e];
  int slot = atomicAdd(&cursor[dst], 1);
  csr_src[slot] = ei[e];
  csr_eid[slot] = e;
  csr_dst[slot] = dst;
}

// ---------------- one-time edge_attr gather into CSR slot order, f16 pairs ----------------
__global__ __launch_bounds__(256) void k_eagather(const int* __restrict__ csr_eid,
                                                  const float* __restrict__ edge_attr,
                                                  unsigned int* __restrict__ ea16) {
  int sl = blockIdx.x * 256 + threadIdx.x;
  if (sl >= EE) return;
  int e = csr_eid[sl];
  const float4* ap = (const float4*)(edge_attr + (size_t)e * 16);
  uint4 o0, o1;
  float4 v0 = ap[0], v1 = ap[1], v2 = ap[2], v3 = ap[3];
  o0.x = packh2_rne(v0.x, v0.y); o0.y = packh2_rne(v0.z, v0.w);
  o0.z = packh2_rne(v1.x, v1.y); o0.w = packh2_rne(v1.z, v1.w);
  o1.x = packh2_rne(v2.x, v2.y); o1.y = packh2_rne(v2.z, v2.w);
  o1.z = packh2_rne(v3.x, v3.y); o1.w = packh2_rne(v3.z, v3.w);
  uint4* op = (uint4*)(ea16 + (size_t)sl * 8);
  op[0] = o0; op[1] = o1;
}

// ---------------- per-node params ----------------
__global__ __launch_bounds__(256) void k_nodeparams(const int* __restrict__ cnt,
                                                    float* __restrict__ inv_deg,
                                                    float* __restrict__ s1a,
                                                    float* __restrict__ s2a) {
  int n = blockIdx.x * 256 + threadIdx.x;
  if (n >= NN) return;
  int c = cnt[n];
  float deg = (c > 0) ? (float)c : 1.0f;
  inv_deg[n] = 1.0f / deg;
  float logd = logf(deg + 1.0f);
  s1a[n] = logd / AVG_LOG;
  s2a[n] = AVG_LOG / logd;
}

// ---------------- per-layer weight composition + ALL f16 packing + colsum zero ----------------
// Merged k_wcomb + k_postpk (+ colsum reset): one launch per layer.
__global__ __launch_bounds__(64) void k_wcomb(const float* __restrict__ edge_w,
                                              const float* __restrict__ edge_b,
                                              const float* __restrict__ pre_w1,
                                              const float* __restrict__ pre_b1,
                                              const float* __restrict__ pre_w2,
                                              const float* __restrict__ post_w1,
                                              const float* __restrict__ post_w2,
                                              unsigned int* __restrict__ wcpk,
                                              unsigned int* __restrict__ w2pk,
                                              unsigned int* __restrict__ q1pk,
                                              unsigned int* __restrict__ q2pk,
                                              float* __restrict__ biasc,
                                              float* __restrict__ colsum, int l) {
  int t = blockIdx.x;
  int wt = l * TT + t;
  int j = threadIdx.x;
  if (t == 0) {
    for (int i = threadIdx.x; i < 2 * DD; i += 64) colsum[i] = 0.f;
  }
  if (j >= FF) return;
  const float* W1 = pre_w1 + (size_t)wt * 1200; // [60][20]
  const float* W2 = pre_w2 + (size_t)wt * 400;  // [20][20]
  const float* ew = edge_w + (size_t)l * 16 * FF;
  const float* eb = edge_b + (size_t)l * FF;
  float col[16];
  for (int i = 0; i < 16; ++i) {
    float acc = 0.f;
#pragma unroll
    for (int f = 0; f < FF; ++f) acc = fmaf(ew[i * FF + f], W1[(40 + f) * FF + j], acc);
    col[i] = acc;
  }
#pragma unroll
  for (int i2 = 0; i2 < 8; ++i2)
    wcpk[((size_t)t * FF + j) * 8 + i2] = packh2_rne(col[2 * i2], col[2 * i2 + 1]);
#pragma unroll
  for (int i2 = 0; i2 < 10; ++i2)
    w2pk[((size_t)t * FF + j) * 10 + i2] = packh2_rne(W2[(2 * i2) * FF + j], W2[(2 * i2 + 1) * FF + j]);
  float b = pre_b1[wt * FF + j];
#pragma unroll
  for (int f = 0; f < FF; ++f) b = fmaf(eb[f], W1[(40 + f) * FF + j], b);
  biasc[t * FF + j] = b;
  // post-MLP packing (former k_postpk)
  const float* Q1 = post_w1 + (size_t)wt * 5200;
  const float* Q2 = post_w2 + (size_t)wt * 400;
  for (int i2 = 0; i2 < 120; ++i2) {
    int blk = i2 / 40, k = i2 - blk * 40;
    int r0 = 20 + 80 * blk + 2 * k;
    q1pk[((size_t)t * 120 + i2) * FF + j] = packh2_rne(Q1[r0 * FF + j], Q1[(r0 + 1) * FF + j]);
  }
#pragma unroll
  for (int i2 = 0; i2 < 10; ++i2)
    q2pk[((size_t)t * 10 + i2) * FF + j] = packh2_rne(Q2[(2 * i2) * FF + j], Q2[(2 * i2 + 1) * FF + j]);
}

// ---------------- per-node pre contributions (bf16 out) ----------------
__global__ __launch_bounds__(256) void k_prenode(
    const float* __restrict__ h, const float* __restrict__ pre_w1,
    const float* __restrict__ biasc,
    unsigned short* __restrict__ predD, unsigned short* __restrict__ predS, int l) {
  int tid = threadIdx.x;
  int t = tid >> 6, lane = tid & 63;
  int n = blockIdx.x * 64 + lane;
  if (n >= NN) return;
  int wt_u = __builtin_amdgcn_readfirstlane(l * TT + t);
  const float* W1 = pre_w1 + (size_t)wt_u * 1200;
  const float* bc = biasc + t * FF;
  float xt[FF];
  {
    const float4* pp = (const float4*)(h + (size_t)n * DD + t * FF);
#pragma unroll
    for (int i = 0; i < 5; ++i) { float4 v = pp[i]; xt[i*4]=v.x; xt[i*4+1]=v.y; xt[i*4+2]=v.z; xt[i*4+3]=v.w; }
  }
  float d[FF], s[FF];
#pragma unroll
  for (int j = 0; j < FF; ++j) { d[j] = bc[j]; s[j] = 0.f; }
#pragma unroll
  for (int i = 0; i < FF; ++i) {
    float a = xt[i];
#pragma unroll
    for (int j = 0; j < FF; ++j) {
      d[j] = fmaf(a, W1[i * FF + j], d[j]);
      s[j] = fmaf(a, W1[(FF + i) * FF + j], s[j]);
    }
  }
  ushort4* pd = (ushort4*)(predD + (size_t)n * DD + t * FF);
  ushort4* ps = (ushort4*)(predS + (size_t)n * DD + t * FF);
#pragma unroll
  for (int i = 0; i < 5; ++i) {
    pd[i] = make_ushort4(f2bf(d[i*4]), f2bf(d[i*4+1]), f2bf(d[i*4+2]), f2bf(d[i*4+3]));
    ps[i] = make_ushort4(f2bf(s[i*4]), f2bf(s[i*4+1]), f2bf(s[i*4+2]), f2bf(s[i*4+3]));
  }
}

// ---------------- FUSED edge pre-MLP + aggregation, tower-colocated, balanced reduce ----------------
__global__ __launch_bounds__(256, 4) void k_preagg(
    const unsigned short* __restrict__ predD,
    const unsigned short* __restrict__ predS,
    const unsigned int* __restrict__ ea16,
    const int* __restrict__ csr_src,
    const int* __restrict__ csr_dst,
    const int* __restrict__ row_ptr,
    const float* __restrict__ inv_deg,
    const unsigned int* __restrict__ wcpk,
    const unsigned int* __restrict__ w2pk,
    const float* __restrict__ pre_b2,
    unsigned short* __restrict__ aggbuf,
    int l) {
  __shared__ int nbr[TILE_N + 1];
  __shared__ float dDs[TT][TILE_N * FF];      // 5.1 KB
  __shared__ unsigned int m2w[TT][64 * 11];   // 11.3 KB, stride-11: conflict-free
  int tid = threadIdx.x;
  int t = tid >> 6, lane = tid & 63;
  int t_u = __builtin_amdgcn_readfirstlane(t);
  int n0 = blockIdx.x * TILE_N;
  const unsigned int* Wcp = wcpk + (size_t)t_u * FF * 8;
  const unsigned int* W2p = w2pk + (size_t)t_u * FF * 10;
  const float* b2 = pre_b2 + (size_t)(l * TT + t_u) * FF;

  if (tid <= TILE_N) {
    int node = n0 + tid; if (node > NN) node = NN;
    nbr[tid] = row_ptr[node];
  }
  for (int i = lane; i < TILE_N * FF; i += 64) {
    int ni = i / FF, ch = i - ni * FF;
    int node = n0 + ni;
    dDs[t][i] = (node < NN) ? bf2f(predD[(size_t)node * DD + t_u * FF + ch]) : 0.f;
  }
  __syncthreads();
  int tbeg = nbr[0], tend = nbr[TILE_N];

  int itN[3], itP[3], itB[3], itE[3];
#pragma unroll
  for (int k = 0; k < 3; ++k) {
    int it = lane + 64 * k;
    bool v = it < ITEMS;
    int nd = v ? (it / 10) : 0;
    itN[k] = nd;
    itP[k] = v ? (it - nd * 10) : 0;
    itB[k] = v ? nbr[nd] : 0;
    itE[k] = v ? nbr[nd + 1] : 0;
  }
  float sS[3][2], sQ[3][2], sN[3][2], sX[3][2];
#pragma unroll
  for (int k = 0; k < 3; ++k) {
    sS[k][0] = 0.f; sS[k][1] = 0.f; sQ[k][0] = 0.f; sQ[k][1] = 0.f;
    sN[k][0] = 3.4e38f; sN[k][1] = 3.4e38f; sX[k][0] = -3.4e38f; sX[k][1] = -3.4e38f;
  }

  for (int wb = tbeg; wb < tend; wb += 64) {
    int p = wb + lane;
    if (p < tend) {
      int src = csr_src[p];
      int ni = csr_dst[p] - n0;
      float m1[FF];
      {
        const float4* dd = (const float4*)(&dDs[t][ni * FF]);
        const ushort4* qq = (const ushort4*)(predS + (size_t)src * DD + t_u * FF);
#pragma unroll
        for (int i = 0; i < 5; ++i) {
          float4 d4 = dd[i];
          ushort4 v = qq[i];
          m1[i*4+0] = d4.x + bf2f(v.x);
          m1[i*4+1] = d4.y + bf2f(v.y);
          m1[i*4+2] = d4.z + bf2f(v.z);
          m1[i*4+3] = d4.w + bf2f(v.w);
        }
      }
      half2v eap[8];
      {
        const uint4* ep = (const uint4*)(ea16 + (size_t)p * 8);
        uint4 e0 = ep[0], e1 = ep[1];
        eap[0] = u2h2(e0.x); eap[1] = u2h2(e0.y); eap[2] = u2h2(e0.z); eap[3] = u2h2(e0.w);
        eap[4] = u2h2(e1.x); eap[5] = u2h2(e1.y); eap[6] = u2h2(e1.z); eap[7] = u2h2(e1.w);
      }
#pragma unroll
      for (int j = 0; j < FF; ++j) {
        float c = m1[j];
#pragma unroll
        for (int i2 = 0; i2 < 8; ++i2) c = fdot2(eap[i2], u2h2(Wcp[j * 8 + i2]), c);
        m1[j] = c;
      }
      half2v mp[10];
#pragma unroll
      for (int pr = 0; pr < 10; ++pr)
        mp[pr] = pkrtz(fmaxf(m1[2*pr], 0.f), fmaxf(m1[2*pr+1], 0.f));
      float m2[FF];
#pragma unroll
      for (int j = 0; j < FF; ++j) {
        float c = b2[j];
#pragma unroll
        for (int i2 = 0; i2 < 10; ++i2) c = fdot2(mp[i2], u2h2(W2p[j * 10 + i2]), c);
        m2[j] = c;
      }
      unsigned int* row = &m2w[t][lane * 11];
#pragma unroll
      for (int pr = 0; pr < 10; ++pr) row[pr] = h22u(pkrtz(m2[2*pr], m2[2*pr+1]));
    }
    __syncthreads();
    int we = (wb + 64 < tend) ? (wb + 64) : tend;
#pragma unroll
    for (int k = 0; k < 3; ++k) {
      int lo = itB[k] > wb ? itB[k] : wb;
      int hi = itE[k] < we ? itE[k] : we;
      for (int s = lo; s < hi; ++s) {
        half2v h2 = u2h2(m2w[t][(s - wb) * 11 + itP[k]]);
        float v0 = (float)h2.x, v1 = (float)h2.y;
        sS[k][0] += v0; sQ[k][0] = fmaf(v0, v0, sQ[k][0]);
        sN[k][0] = fminf(sN[k][0], v0); sX[k][0] = fmaxf(sX[k][0], v0);
        sS[k][1] += v1; sQ[k][1] = fmaf(v1, v1, sQ[k][1]);
        sN[k][1] = fminf(sN[k][1], v1); sX[k][1] = fmaxf(sX[k][1], v1);
      }
    }
    __syncthreads();
  }

#pragma unroll
  for (int k = 0; k < 3; ++k) {
    int it = lane + 64 * k;
    if (it < ITEMS) {
      int n = n0 + itN[k];
      if (n < NN) {
        float inv = inv_deg[n];
        bool noe = (itE[k] <= itB[k]);
        float mu0 = sS[k][0] * inv, mu1 = sS[k][1] * inv;
        float sd0 = sqrtf(fmaxf(sQ[k][0] * inv - mu0 * mu0, 0.f) + 1e-5f);
        float sd1 = sqrtf(fmaxf(sQ[k][1] * inv - mu1 * mu1, 0.f) + 1e-5f);
        float mn0 = noe ? 0.f : sN[k][0], mn1 = noe ? 0.f : sN[k][1];
        float mx0 = noe ? 0.f : sX[k][0], mx1 = noe ? 0.f : sX[k][1];
        unsigned short* ab = aggbuf + ((size_t)n * 4 + t_u) * 80;
        ((unsigned int*)(ab))[itP[k]]      = pack_bf16(mu0, mu1);
        ((unsigned int*)(ab + 20))[itP[k]] = pack_bf16(mn0, mn1);
        ((unsigned int*)(ab + 40))[itP[k]] = pack_bf16(mx0, mx1);
        ((unsigned int*)(ab + 60))[itP[k]] = pack_bf16(sd0, sd1);
      }
    }
  }
}

// ---------------- FUSED post-MLP + lin + BN colsum (v2: no Wl in LDS) ----------------
// Block = 64 nodes x 4 waves. Phase A: wave=tower, post2 via dot2 -> LDS rows[64][81].
// Phase B: wave=d-chunk, lane=node -> Wl accessed WAVE-UNIFORM (s_load stream, no LDS,
// no sK$ thrash from vector weight loads). LDS 21.1 KB (was 46.4) -> ~2x occupancy.
// Phase C: colsum transpose reduce via rows reused as [80][66].
__global__ __launch_bounds__(256) void k_postlin(
    const float* __restrict__ h, const unsigned short* __restrict__ aggbuf,
    const float* __restrict__ s1a, const float* __restrict__ s2a,
    const float* __restrict__ post_w1, const float* __restrict__ post_b1,
    const unsigned int* __restrict__ q1pk, const unsigned int* __restrict__ q2pk,
    const float* __restrict__ post_b2,
    const float* __restrict__ lin_w, const float* __restrict__ lin_b,
    float* __restrict__ outl, float* __restrict__ colsum, int l) {
  __shared__ float rows[5280];  // phase A/B: [node][81] (5184); phase C: [d][66] (5280)
  int tid = threadIdx.x;
  int t = tid >> 6, lane = tid & 63;
  int t_u = __builtin_amdgcn_readfirstlane(t);
  int wt_u = __builtin_amdgcn_readfirstlane(l * TT + t);
  int n = blockIdx.x * 64 + lane;

  // ---- phase A: post2 for (node=lane, tower=t) ----
  const float* Q1 = post_w1 + (size_t)wt_u * 5200;
  const float* B1 = post_b1 + (size_t)wt_u * FF;
  const float* B2 = post_b2 + (size_t)wt_u * FF;
  const unsigned int* q1 = q1pk + (size_t)t_u * 120 * FF;
  const unsigned int* q2 = q2pk + (size_t)t_u * 10 * FF;
  if (n < NN) {
    float c1 = s1a[n], c2 = s2a[n];
    half2v c1p = pkrtz(c1, c1), c2p = pkrtz(c2, c2);
    float xt[FF];
    {
      const float4* pp = (const float4*)(h + (size_t)n * DD + t_u * FF);
#pragma unroll
      for (int i = 0; i < 5; ++i) { float4 v = pp[i]; xt[i*4]=v.x; xt[i*4+1]=v.y; xt[i*4+2]=v.z; xt[i*4+3]=v.w; }
    }
    half2v a0p[40];
    {
      const uint4* ap = (const uint4*)(aggbuf + ((size_t)n * 4 + t_u) * 80);
#pragma unroll
      for (int q = 0; q < 10; ++q) {
        uint4 v = ap[q];
        unsigned int w[4] = {v.x, v.y, v.z, v.w};
#pragma unroll
        for (int k = 0; k < 4; ++k) {
          unsigned int u = w[k];
          float lo = __uint_as_float(u << 16);
          float hi = __uint_as_float(u & 0xffff0000u);
          a0p[q * 4 + k] = pkrtz(lo, hi);
        }
      }
    }
    float o1[FF];
#pragma unroll
    for (int j = 0; j < FF; ++j) o1[j] = B1[j];
#pragma unroll
    for (int i = 0; i < FF; ++i) {
      float a = xt[i];
#pragma unroll
      for (int j = 0; j < FF; ++j) o1[j] = fmaf(a, Q1[i * FF + j], o1[j]);
    }
#pragma unroll 2
    for (int k = 0; k < 40; ++k) {
      half2v act = a0p[k];
      const unsigned int* wr = q1 + k * FF;
#pragma unroll
      for (int j = 0; j < FF; ++j) o1[j] = fdot2(act, u2h2(wr[j]), o1[j]);
    }
#pragma unroll 2
    for (int k = 0; k < 40; ++k) {
      half2v act = a0p[k] * c1p;
      const unsigned int* wr = q1 + (40 + k) * FF;
#pragma unroll
      for (int j = 0; j < FF; ++j) o1[j] = fdot2(act, u2h2(wr[j]), o1[j]);
    }
#pragma unroll 2
    for (int k = 0; k < 40; ++k) {
      half2v act = a0p[k] * c2p;
      const unsigned int* wr = q1 + (80 + k) * FF;
#pragma unroll
      for (int j = 0; j < FF; ++j) o1[j] = fdot2(act, u2h2(wr[j]), o1[j]);
    }
    half2v o1p[10];
#pragma unroll
    for (int i2 = 0; i2 < 10; ++i2)
      o1p[i2] = pkrtz(fmaxf(o1[2*i2], 0.f), fmaxf(o1[2*i2+1], 0.f));
    float o2[FF];
#pragma unroll
    for (int j = 0; j < FF; ++j) o2[j] = B2[j];
#pragma unroll 2
    for (int i2 = 0; i2 < 10; ++i2) {
      half2v act = o1p[i2];
      const unsigned int* wr = q2 + i2 * FF;
#pragma unroll
      for (int j = 0; j < FF; ++j) o2[j] = fdot2(act, u2h2(wr[j]), o2[j]);
    }
#pragma unroll
    for (int j = 0; j < FF; ++j) rows[lane * 81 + t_u * FF + j] = o2[j];
  } else {
#pragma unroll
    for (int j = 0; j < FF; ++j) rows[lane * 81 + t_u * FF + j] = 0.f;
  }
  __syncthreads();

  // ---- phase B: lin 80x80; wave = d-chunk (Wl wave-uniform -> s_loads) ----
  int n2 = blockIdx.x * 64 + lane;
  const float* WlG = lin_w + (size_t)l * DD * DD + t_u * FF;  // column block of this wave
  float acc[FF];
#pragma unroll
  for (int j = 0; j < FF; ++j) acc[j] = lin_b[l * DD + t_u * FF + j];
  for (int i = 0; i < DD; ++i) {
    float r = rows[lane * 81 + i];
    const float* wl = WlG + i * DD;   // wave-uniform address
#pragma unroll
    for (int j = 0; j < FF; ++j) acc[j] = fmaf(r, wl[j], acc[j]);
  }
  bool valid = (n2 < NN);
  if (valid) {
    float4* op = (float4*)(outl + (size_t)n2 * DD + t_u * FF);
#pragma unroll
    for (int i = 0; i < 5; ++i) op[i] = make_float4(acc[i*4], acc[i*4+1], acc[i*4+2], acc[i*4+3]);
  }
  __syncthreads();   // all reads of rows done before phase C overwrites

  // ---- phase C: BN colsum (two-pass LDS transpose reduce, rows as [80][66]) ----
#pragma unroll
  for (int j = 0; j < FF; ++j) rows[(t_u * FF + j) * 66 + lane] = valid ? acc[j] : 0.f;
  __syncthreads();
  if (tid < DD) {
    float s = 0.f;
    for (int k = 0; k < 64; ++k) s += rows[tid * 66 + k];
    atomicAdd(&colsum[tid], s);
  }
  __syncthreads();
#pragma unroll
  for (int j = 0; j < FF; ++j) rows[(t_u * FF + j) * 66 + lane] = valid ? acc[j] * acc[j] : 0.f;
  __syncthreads();
  if (tid < DD) {
    float s = 0.f;
    for (int k = 0; k < 64; ++k) s += rows[tid * 66 + k];
    atomicAdd(&colsum[DD + tid], s);
  }
}

// ---------------- BN finalize + apply + relu + residual (bnfinal folded in) ----------------
__global__ __launch_bounds__(256) void k_bnapply(const float* __restrict__ outl,
                                                 const float* __restrict__ colsum,
                                                 const float* __restrict__ bn_g,
                                                 const float* __restrict__ bn_b,
                                                 float* __restrict__ h, int l) {
  __shared__ float sc[DD], ofs[DD];
  int tid = threadIdx.x;
  if (tid < DD) {
    float mu = colsum[tid] * (1.0f / NN);
    float var = colsum[DD + tid] * (1.0f / NN) - mu * mu;
    float s = bn_g[l * DD + tid] * rsqrtf(var + 1e-5f);
    sc[tid] = s;
    ofs[tid] = bn_b[l * DD + tid] - mu * s;
  }
  __syncthreads();
  int idx = blockIdx.x * 256 + tid;
  if (idx >= NN * DD) return;
  int d = idx % DD;
  float v = fmaf(outl[idx], sc[d], ofs[d]);
  h[idx] += fmaxf(v, 0.f);
}

// ---------------- graph pooling ----------------
__global__ __launch_bounds__(256) void k_gcnt(const int* __restrict__ batch, int* __restrict__ gcnt) {
  __shared__ int hcnt[GG];
  int tid = threadIdx.x;
  if (tid < GG) hcnt[tid] = 0;
  __syncthreads();
  int n = blockIdx.x * 256 + tid;
  if (n < NN) atomicAdd(&hcnt[batch[n]], 1);
  __syncthreads();
  if (tid < GG && hcnt[tid] > 0) atomicAdd(&gcnt[tid], hcnt[tid]);
}

__global__ void k_gstart(const int* __restrict__ gcnt, int* __restrict__ gstart) {
  if (threadIdx.x == 0 && blockIdx.x == 0) {
    int acc = 0;
    for (int g = 0; g < GG; ++g) { gstart[g] = acc; acc += gcnt[g]; }
  }
}

__global__ __launch_bounds__(320) void k_gmean(const float* __restrict__ h,
                                               const int* __restrict__ gstart,
                                               const int* __restrict__ gcnt,
                                               float* __restrict__ gbuf) {
  __shared__ float red[320];
  int g = blockIdx.x, tid = threadIdx.x;
  int nl = tid / DD, d = tid - nl * DD;
  int start = gstart[g], c = gcnt[g];
  float acc = 0.f;
  for (int r = start + nl; r < start + c; r += 4) acc += h[(size_t)r * DD + d];
  red[tid] = acc;
  __syncthreads();
  if (tid < DD) {
    float s = red[tid] + red[tid + DD] + red[tid + 2 * DD] + red[tid + 3 * DD];
    float cf = (c > 0) ? (float)c : 1.0f;
    gbuf[g * DD + tid] = s / cf;
  }
}

// ---------------- final MLP (tiny) ----------------
__global__ __launch_bounds__(64) void k_mlp(const float* __restrict__ gbuf,
                                            const float* __restrict__ w1, const float* __restrict__ b1,
                                            const float* __restrict__ w2, const float* __restrict__ b2,
                                            const float* __restrict__ w3, const float* __restrict__ b3,
                                            float* __restrict__ out) {
  __shared__ float row[DD];
  __shared__ float t1[40];
  __shared__ float t2[20];
  int g = blockIdx.x, tid = threadIdx.x;
  for (int i = tid; i < DD; i += 64) row[i] = gbuf[g * DD + i];
  __syncthreads();
  if (tid < 40) {
    float acc = b1[tid];
#pragma unroll
    for (int i = 0; i < DD; ++i) acc = fmaf(row[i], w1[i * 40 + tid], acc);
    t1[tid] = fmaxf(acc, 0.f);
  }
  __syncthreads();
  if (tid < 20) {
    float acc = b2[tid];
#pragma unroll
    for (int i = 0; i < 40; ++i) acc = fmaf(t1[i], w2[i * 20 + tid], acc);
    t2[tid] = fmaxf(acc, 0.f);
  }
  __syncthreads();
  if (tid == 0) {
    float acc = b3[0];
#pragma unroll
    for (int i = 0; i < 20; ++i) acc = fmaf(t2[i], w3[i], acc);
    out[g] = acc;
  }
}

extern "C" void kernel_launch(void* const* d_in, const int* in_sizes, int n_in,
                              void* d_out, int out_size, void* d_ws, size_t ws_size,
                              hipStream_t stream) {
  const int*   x         = (const int*)d_in[0];
  const int*   ei        = (const int*)d_in[1];
  const int*   batch     = (const int*)d_in[2];
  const float* edge_attr = (const float*)d_in[3];
  const float* atom_emb  = (const float*)d_in[4];
  const float* edge_w    = (const float*)d_in[5];
  const float* edge_b    = (const float*)d_in[6];
  const float* pre_w1    = (const float*)d_in[7];
  const float* pre_b1    = (const float*)d_in[8];
  const float* pre_w2    = (const float*)d_in[9];
  const float* pre_b2    = (const float*)d_in[10];
  const float* post_w1   = (const float*)d_in[11];
  const float* post_b1   = (const float*)d_in[12];
  const float* post_w2   = (const float*)d_in[13];
  const float* post_b2   = (const float*)d_in[14];
  const float* lin_w     = (const float*)d_in[15];
  const float* lin_b     = (const float*)d_in[16];
  const float* bn_g      = (const float*)d_in[17];
  const float* bn_b      = (const float*)d_in[18];
  const float* mlp_w1    = (const float*)d_in[19];
  const float* mlp_b1    = (const float*)d_in[20];
  const float* mlp_w2    = (const float*)d_in[21];
  const float* mlp_b2    = (const float*)d_in[22];
  const float* mlp_w3    = (const float*)d_in[23];
  const float* mlp_b3    = (const float*)d_in[24];
  float* out = (float*)d_out;

  // workspace carve-up (~116 MB)
  char* ws = (char*)d_ws;
  size_t off = 0;
  auto alloc = [&](size_t bytes) -> void* {
    void* p = ws + off;
    off += (bytes + 15) & ~(size_t)15;
    return p;
  };
  float* h       = (float*)alloc((size_t)NN * DD * 4);           // 16 MB
  float* outl    = (float*)alloc((size_t)NN * DD * 4);           // 16 MB (post-lin output)
  unsigned short* predD = (unsigned short*)alloc((size_t)NN * DD * 2); // 8 MB bf16
  unsigned short* predS = (unsigned short*)alloc((size_t)NN * DD * 2); // 8 MB bf16
  int*   csr_src = (int*)alloc((size_t)EE * 4);                  // 3.2 MB
  int*   csr_eid = (int*)alloc((size_t)EE * 4);                  // 3.2 MB
  int*   csr_dst = (int*)alloc((size_t)EE * 4);                  // 3.2 MB
  unsigned int* ea16 = (unsigned int*)alloc((size_t)EE * 8 * 4); // 25.6 MB f16 CSR-ordered ea
  int*   row_ptr = (int*)alloc((size_t)(NN + 1) * 4);
  int*   cnt     = (int*)alloc((size_t)NN * 4);
  int*   cursor  = (int*)alloc((size_t)NN * 4);
  float* inv_deg = (float*)alloc((size_t)NN * 4);
  float* s1a     = (float*)alloc((size_t)NN * 4);
  float* s2a     = (float*)alloc((size_t)NN * 4);
  float* colsum  = (float*)alloc(2 * DD * 4);
  float* gbuf    = (float*)alloc((size_t)GG * DD * 4);
  unsigned int* wcpk  = (unsigned int*)alloc((size_t)TT * FF * 8 * 4);
  unsigned int* w2pk  = (unsigned int*)alloc((size_t)TT * FF * 10 * 4);
  unsigned int* q1pk  = (unsigned int*)alloc((size_t)TT * 120 * FF * 4);
  unsigned int* q2pk  = (unsigned int*)alloc((size_t)TT * 10 * FF * 4);
  float* biasc   = (float*)alloc((size_t)TT * FF * 4);
  int*   bsum    = (int*)alloc((size_t)SCAN_B * 4);
  int*   boff    = (int*)alloc((size_t)SCAN_B * 4);
  int*   gcnt    = (int*)alloc((size_t)GG * 4);
  int*   gstart  = (int*)alloc((size_t)(GG + 1) * 4);
  unsigned short* aggbuf = (unsigned short*)alloc((size_t)NN * 4 * 80 * 2); // 32 MB bf16
  (void)in_sizes; (void)n_in; (void)out_size; (void)ws_size;

  hipMemsetAsync(cnt, 0, (size_t)NN * 4, stream);
  k_h<<<(NN * DD + 255) / 256, 256, 0, stream>>>(x, atom_emb, h);
  k_deg<<<(EE + 255) / 256, 256, 0, stream>>>(ei, cnt);
  k_scan_sum<<<SCAN_B, 1024, 0, stream>>>(cnt, bsum);
  k_scan_top<<<1, 64, 0, stream>>>(bsum, boff, row_ptr);
  k_scan_apply<<<SCAN_B, 1024, 0, stream>>>(cnt, boff, row_ptr, cursor);
  k_csrfill<<<(EE + 255) / 256, 256, 0, stream>>>(ei, cursor, csr_src, csr_eid, csr_dst);
  k_eagather<<<(EE + 255) / 256, 256, 0, stream>>>(csr_eid, edge_attr, ea16);
  k_nodeparams<<<(NN + 255) / 256, 256, 0, stream>>>(cnt, inv_deg, s1a, s2a);

  int tilesA = (NN + TILE_N - 1) / TILE_N;   // 3125
  int blocksPL = (NN + 63) / 64;             // 782
  for (int l = 0; l < LL; ++l) {
    k_wcomb<<<TT, 64, 0, stream>>>(edge_w, edge_b, pre_w1, pre_b1, pre_w2,
        post_w1, post_w2, wcpk, w2pk, q1pk, q2pk, biasc, colsum, l);
    k_prenode<<<(NN + 63) / 64, 256, 0, stream>>>(h, pre_w1, biasc, predD, predS, l);
    k_preagg<<<tilesA, 256, 0, stream>>>(predD, predS, ea16, csr_src, csr_dst, row_ptr,
        inv_deg, wcpk, w2pk, pre_b2, aggbuf, l);
    k_postlin<<<blocksPL, 256, 0, stream>>>(h, aggbuf, s1a, s2a,
        post_w1, post_b1, q1pk, q2pk, post_b2, lin_w, lin_b, outl, colsum, l);
    k_bnapply<<<(NN * DD + 255) / 256, 256, 0, stream>>>(outl, colsum, bn_g, bn_b, h, l);
  }

  hipMemsetAsync(gcnt, 0, (size_t)GG * 4, stream);
  k_gcnt<<<(NN + 255) / 256, 256, 0, stream>>>(batch, gcnt);
  k_gstart<<<1, 64, 0, stream>>>(gcnt, gstart);
  k_gmean<<<GG, 320, 0, stream>>>(h, gstart, gcnt, gbuf);
  k_mlp<<<GG, 64, 0, stream>>>(gbuf, mlp_w1, mlp_b1, mlp_w2, mlp_b2, mlp_w3, mlp_b3, out);
}

// Round 11
// 1371.015 us; speedup vs baseline: 1.3966x; 1.0327x over previous
//
#include <hip/hip_runtime.h>
#include <hip/hip_bf16.h>

// Problem constants (from reference)
#define NN 50000
#define EE 800000
#define GG 128
#define LL 4
#define TT 4
#define FF 20
#define DD 80
#define SCAN_B ((NN + 1023) / 1024)   // 49
#define TILE_N 16                     // nodes per k_preagg tile (avg 256 slots)
#define ITEMS (TILE_N * 10)           // 160 (node, ch-pair) reduce items per tower
static constexpr float AVG_LOG = 2.8332133440562162f; // ln(17)

typedef __fp16 half2v __attribute__((ext_vector_type(2)));

__device__ __forceinline__ float bf2f(unsigned short u) {
  return __uint_as_float((unsigned)u << 16);
}
__device__ __forceinline__ unsigned short f2bf(float f) {
  __hip_bfloat16 b = __float2bfloat16(f); // RNE
  return *(unsigned short*)&b;
}
__device__ __forceinline__ half2v pkrtz(float a, float b) {
#if __has_builtin(__builtin_amdgcn_cvt_pkrtz)
  return __builtin_amdgcn_cvt_pkrtz(a, b);
#else
  half2v h; h.x = (__fp16)a; h.y = (__fp16)b; return h;
#endif
}
__device__ __forceinline__ float fdot2(half2v a, half2v b, float c) {
#if __has_builtin(__builtin_amdgcn_fdot2)
  return __builtin_amdgcn_fdot2(a, b, c, false);
#else
  return fmaf((float)a.x, (float)b.x, fmaf((float)a.y, (float)b.y, c));
#endif
}
__device__ __forceinline__ half2v u2h2(unsigned int u) {
  return __builtin_bit_cast(half2v, u);
}
__device__ __forceinline__ unsigned int h22u(half2v h) {
  return __builtin_bit_cast(unsigned int, h);
}
__device__ __forceinline__ unsigned int packh2_rne(float a, float b) {
  half2v h; h.x = (__fp16)a; h.y = (__fp16)b; // RNE casts for weights
  return h22u(h);
}
__device__ __forceinline__ unsigned int pack_bf16(float a, float b) {
  return (unsigned int)f2bf(a) | ((unsigned int)f2bf(b) << 16);
}

// ---------------- h init: h[n,d] = sum_i atom_emb[i, x[n,i], d] ----------------
__global__ __launch_bounds__(256) void k_h(const int* __restrict__ x,
                                           const float* __restrict__ atom_emb,
                                           float* __restrict__ h) {
  int idx = blockIdx.x * 256 + threadIdx.x;
  if (idx >= NN * DD) return;
  int n = idx / DD, d = idx - n * DD;
  const int* xr = x + n * 9;
  float acc = 0.f;
#pragma unroll
  for (int i = 0; i < 9; ++i) {
    int v = xr[i];
    acc += atom_emb[(i * 16 + v) * DD + d];
  }
  h[idx] = acc;
}

// ---------------- degree count ----------------
__global__ __launch_bounds__(256) void k_deg(const int* __restrict__ ei, int* __restrict__ cnt) {
  int e = blockIdx.x * 256 + threadIdx.x;
  if (e >= EE) return;
  atomicAdd(&cnt[ei[EE + e]], 1); // dst = edge_index[1][e]
}

// ---------------- hierarchical exclusive scan ----------------
__global__ __launch_bounds__(1024) void k_scan_sum(const int* __restrict__ cnt, int* __restrict__ bsum) {
  __shared__ int red[1024];
  int tid = threadIdx.x;
  int i = blockIdx.x * 1024 + tid;
  red[tid] = (i < NN) ? cnt[i] : 0;
  __syncthreads();
  for (int off = 512; off > 0; off >>= 1) {
    if (tid < off) red[tid] += red[tid + off];
    __syncthreads();
  }
  if (tid == 0) bsum[blockIdx.x] = red[0];
}

__global__ void k_scan_top(const int* __restrict__ bsum, int* __restrict__ boff,
                           int* __restrict__ row_ptr) {
  if (threadIdx.x == 0 && blockIdx.x == 0) {
    int acc = 0;
    for (int b = 0; b < SCAN_B; ++b) { boff[b] = acc; acc += bsum[b]; }
    row_ptr[NN] = acc;
  }
}

__global__ __launch_bounds__(1024) void k_scan_apply(const int* __restrict__ cnt,
                                                     const int* __restrict__ boff,
                                                     int* __restrict__ row_ptr,
                                                     int* __restrict__ cursor) {
  __shared__ int sm[1024];
  int tid = threadIdx.x;
  int i = blockIdx.x * 1024 + tid;
  int v = (i < NN) ? cnt[i] : 0;
  sm[tid] = v;
  __syncthreads();
  for (int off = 1; off < 1024; off <<= 1) {
    int t = (tid >= off) ? sm[tid - off] : 0;
    __syncthreads();
    sm[tid] += t;
    __syncthreads();
  }
  int excl = boff[blockIdx.x] + sm[tid] - v;
  if (i < NN) { row_ptr[i] = excl; cursor[i] = excl; }
}

// ---------------- CSR fill: slot -> src / eid / dst (split arrays) ----------------
__global__ __launch_bounds__(256) void k_csrfill(const int* __restrict__ ei,
                                                 int* __restrict__ cursor,
                                                 int* __restrict__ csr_src,
                                                 int* __restrict__ csr_eid,
                                                 int* __restrict__ csr_dst) {
  int e = blockIdx.x * 256 + threadIdx.x;
  if (e >= EE) return;
  int dst = ei[EE + e];
  int slot = atomicAdd(&cursor[dst], 1);
  csr_src[slot] = ei[e];
  csr_eid[slot] = e;
  csr_dst[slot] = dst;
}

// ---------------- one-time edge_attr gather into CSR slot order, f16 pairs ----------------
__global__ __launch_bounds__(256) void k_eagather(const int* __restrict__ csr_eid,
                                                  const float* __restrict__ edge_attr,
                                                  unsigned int* __restrict__ ea16) {
  int sl = blockIdx.x * 256 + threadIdx.x;
  if (sl >= EE) return;
  int e = csr_eid[sl];
  const float4* ap = (const float4*)(edge_attr + (size_t)e * 16);
  uint4 o0, o1;
  float4 v0 = ap[0], v1 = ap[1], v2 = ap[2], v3 = ap[3];
  o0.x = packh2_rne(v0.x, v0.y); o0.y = packh2_rne(v0.z, v0.w);
  o0.z = packh2_rne(v1.x, v1.y); o0.w = packh2_rne(v1.z, v1.w);
  o1.x = packh2_rne(v2.x, v2.y); o1.y = packh2_rne(v2.z, v2.w);
  o1.z = packh2_rne(v3.x, v3.y); o1.w = packh2_rne(v3.z, v3.w);
  uint4* op = (uint4*)(ea16 + (size_t)sl * 8);
  op[0] = o0; op[1] = o1;
}

// ---------------- per-node params ----------------
__global__ __launch_bounds__(256) void k_nodeparams(const int* __restrict__ cnt,
                                                    float* __restrict__ inv_deg,
                                                    float* __restrict__ s1a,
                                                    float* __restrict__ s2a) {
  int n = blockIdx.x * 256 + threadIdx.x;
  if (n >= NN) return;
  int c = cnt[n];
  float deg = (c > 0) ? (float)c : 1.0f;
  inv_deg[n] = 1.0f / deg;
  float logd = logf(deg + 1.0f);
  s1a[n] = logd / AVG_LOG;
  s2a[n] = AVG_LOG / logd;
}

// ---------------- per-layer weight composition + ALL f16 packing + colsum zero ----------------
__global__ __launch_bounds__(64) void k_wcomb(const float* __restrict__ edge_w,
                                              const float* __restrict__ edge_b,
                                              const float* __restrict__ pre_w1,
                                              const float* __restrict__ pre_b1,
                                              const float* __restrict__ pre_w2,
                                              const float* __restrict__ post_w1,
                                              const float* __restrict__ post_w2,
                                              unsigned int* __restrict__ wcpk,
                                              unsigned int* __restrict__ w2pk,
                                              unsigned int* __restrict__ q1pk,
                                              unsigned int* __restrict__ q2pk,
                                              float* __restrict__ biasc,
                                              float* __restrict__ colsum, int l) {
  int t = blockIdx.x;
  int wt = l * TT + t;
  int j = threadIdx.x;
  if (t == 0) {
    for (int i = threadIdx.x; i < 2 * DD; i += 64) colsum[i] = 0.f;
  }
  if (j >= FF) return;
  const float* W1 = pre_w1 + (size_t)wt * 1200; // [60][20]
  const float* W2 = pre_w2 + (size_t)wt * 400;  // [20][20]
  const float* ew = edge_w + (size_t)l * 16 * FF;
  const float* eb = edge_b + (size_t)l * FF;
  float col[16];
  for (int i = 0; i < 16; ++i) {
    float acc = 0.f;
#pragma unroll
    for (int f = 0; f < FF; ++f) acc = fmaf(ew[i * FF + f], W1[(40 + f) * FF + j], acc);
    col[i] = acc;
  }
#pragma unroll
  for (int i2 = 0; i2 < 8; ++i2)
    wcpk[((size_t)t * FF + j) * 8 + i2] = packh2_rne(col[2 * i2], col[2 * i2 + 1]);
#pragma unroll
  for (int i2 = 0; i2 < 10; ++i2)
    w2pk[((size_t)t * FF + j) * 10 + i2] = packh2_rne(W2[(2 * i2) * FF + j], W2[(2 * i2 + 1) * FF + j]);
  float b = pre_b1[wt * FF + j];
#pragma unroll
  for (int f = 0; f < FF; ++f) b = fmaf(eb[f], W1[(40 + f) * FF + j], b);
  biasc[t * FF + j] = b;
  // post-MLP packing
  const float* Q1 = post_w1 + (size_t)wt * 5200;
  const float* Q2 = post_w2 + (size_t)wt * 400;
  for (int i2 = 0; i2 < 120; ++i2) {
    int blk = i2 / 40, k = i2 - blk * 40;
    int r0 = 20 + 80 * blk + 2 * k;
    q1pk[((size_t)t * 120 + i2) * FF + j] = packh2_rne(Q1[r0 * FF + j], Q1[(r0 + 1) * FF + j]);
  }
#pragma unroll
  for (int i2 = 0; i2 < 10; ++i2)
    q2pk[((size_t)t * 10 + i2) * FF + j] = packh2_rne(Q2[(2 * i2) * FF + j], Q2[(2 * i2 + 1) * FF + j]);
}

// ---------------- per-node pre contributions (bf16 out) ----------------
__global__ __launch_bounds__(256) void k_prenode(
    const float* __restrict__ h, const float* __restrict__ pre_w1,
    const float* __restrict__ biasc,
    unsigned short* __restrict__ predD, unsigned short* __restrict__ predS, int l) {
  int tid = threadIdx.x;
  int t = tid >> 6, lane = tid & 63;
  int n = blockIdx.x * 64 + lane;
  if (n >= NN) return;
  int wt_u = __builtin_amdgcn_readfirstlane(l * TT + t);
  const float* W1 = pre_w1 + (size_t)wt_u * 1200;
  const float* bc = biasc + t * FF;
  float xt[FF];
  {
    const float4* pp = (const float4*)(h + (size_t)n * DD + t * FF);
#pragma unroll
    for (int i = 0; i < 5; ++i) { float4 v = pp[i]; xt[i*4]=v.x; xt[i*4+1]=v.y; xt[i*4+2]=v.z; xt[i*4+3]=v.w; }
  }
  float d[FF], s[FF];
#pragma unroll
  for (int j = 0; j < FF; ++j) { d[j] = bc[j]; s[j] = 0.f; }
#pragma unroll
  for (int i = 0; i < FF; ++i) {
    float a = xt[i];
#pragma unroll
    for (int j = 0; j < FF; ++j) {
      d[j] = fmaf(a, W1[i * FF + j], d[j]);
      s[j] = fmaf(a, W1[(FF + i) * FF + j], s[j]);
    }
  }
  ushort4* pd = (ushort4*)(predD + (size_t)n * DD + t * FF);
  ushort4* ps = (ushort4*)(predS + (size_t)n * DD + t * FF);
#pragma unroll
  for (int i = 0; i < 5; ++i) {
    pd[i] = make_ushort4(f2bf(d[i*4]), f2bf(d[i*4+1]), f2bf(d[i*4+2]), f2bf(d[i*4+3]));
    ps[i] = make_ushort4(f2bf(s[i*4]), f2bf(s[i*4+1]), f2bf(s[i*4+2]), f2bf(s[i*4+3]));
  }
}

// ---------------- FUSED edge pre-MLP + aggregation, tower-colocated, balanced reduce ----------------
// v3: 128-slot windows (2 edges/lane) — halves barriers, amortizes reduce max-divergence,
// and gives the scheduler two independent edge bodies for ILP.
__global__ __launch_bounds__(256, 4) void k_preagg(
    const unsigned short* __restrict__ predD,
    const unsigned short* __restrict__ predS,
    const unsigned int* __restrict__ ea16,
    const int* __restrict__ csr_src,
    const int* __restrict__ csr_dst,
    const int* __restrict__ row_ptr,
    const float* __restrict__ inv_deg,
    const unsigned int* __restrict__ wcpk,
    const unsigned int* __restrict__ w2pk,
    const float* __restrict__ pre_b2,
    unsigned short* __restrict__ aggbuf,
    int l) {
  __shared__ int nbr[TILE_N + 1];
  __shared__ float dDs[TT][TILE_N * FF];       // 5.1 KB
  __shared__ unsigned int m2w[TT][128 * 11];   // 22.5 KB, stride-11: conflict-free
  int tid = threadIdx.x;
  int t = tid >> 6, lane = tid & 63;
  int t_u = __builtin_amdgcn_readfirstlane(t);
  int n0 = blockIdx.x * TILE_N;
  const unsigned int* Wcp = wcpk + (size_t)t_u * FF * 8;
  const unsigned int* W2p = w2pk + (size_t)t_u * FF * 10;
  const float* b2 = pre_b2 + (size_t)(l * TT + t_u) * FF;

  if (tid <= TILE_N) {
    int node = n0 + tid; if (node > NN) node = NN;
    nbr[tid] = row_ptr[node];
  }
  for (int i = lane; i < TILE_N * FF; i += 64) {
    int ni = i / FF, ch = i - ni * FF;
    int node = n0 + ni;
    dDs[t][i] = (node < NN) ? bf2f(predD[(size_t)node * DD + t_u * FF + ch]) : 0.f;
  }
  __syncthreads();
  int tbeg = nbr[0], tend = nbr[TILE_N];

  int itN[3], itP[3], itB[3], itE[3];
#pragma unroll
  for (int k = 0; k < 3; ++k) {
    int it = lane + 64 * k;
    bool v = it < ITEMS;
    int nd = v ? (it / 10) : 0;
    itN[k] = nd;
    itP[k] = v ? (it - nd * 10) : 0;
    itB[k] = v ? nbr[nd] : 0;
    itE[k] = v ? nbr[nd + 1] : 0;
  }
  float sS[3][2], sQ[3][2], sN[3][2], sX[3][2];
#pragma unroll
  for (int k = 0; k < 3; ++k) {
    sS[k][0] = 0.f; sS[k][1] = 0.f; sQ[k][0] = 0.f; sQ[k][1] = 0.f;
    sN[k][0] = 3.4e38f; sN[k][1] = 3.4e38f; sX[k][0] = -3.4e38f; sX[k][1] = -3.4e38f;
  }

  for (int wb = tbeg; wb < tend; wb += 128) {
#pragma unroll
    for (int e = 0; e < 2; ++e) {
      int sl = lane + 64 * e;
      int p = wb + sl;
      if (p < tend) {
        int src = csr_src[p];
        int ni = csr_dst[p] - n0;
        float m1[FF];
        {
          const float4* dd = (const float4*)(&dDs[t][ni * FF]);
          const ushort4* qq = (const ushort4*)(predS + (size_t)src * DD + t_u * FF);
#pragma unroll
          for (int i = 0; i < 5; ++i) {
            float4 d4 = dd[i];
            ushort4 v = qq[i];
            m1[i*4+0] = d4.x + bf2f(v.x);
            m1[i*4+1] = d4.y + bf2f(v.y);
            m1[i*4+2] = d4.z + bf2f(v.z);
            m1[i*4+3] = d4.w + bf2f(v.w);
          }
        }
        half2v eap[8];
        {
          const uint4* ep = (const uint4*)(ea16 + (size_t)p * 8);
          uint4 e0 = ep[0], e1 = ep[1];
          eap[0] = u2h2(e0.x); eap[1] = u2h2(e0.y); eap[2] = u2h2(e0.z); eap[3] = u2h2(e0.w);
          eap[4] = u2h2(e1.x); eap[5] = u2h2(e1.y); eap[6] = u2h2(e1.z); eap[7] = u2h2(e1.w);
        }
#pragma unroll
        for (int j = 0; j < FF; ++j) {
          float c = m1[j];
#pragma unroll
          for (int i2 = 0; i2 < 8; ++i2) c = fdot2(eap[i2], u2h2(Wcp[j * 8 + i2]), c);
          m1[j] = c;
        }
        half2v mp[10];
#pragma unroll
        for (int pr = 0; pr < 10; ++pr)
          mp[pr] = pkrtz(fmaxf(m1[2*pr], 0.f), fmaxf(m1[2*pr+1], 0.f));
        float m2[FF];
#pragma unroll
        for (int j = 0; j < FF; ++j) {
          float c = b2[j];
#pragma unroll
          for (int i2 = 0; i2 < 10; ++i2) c = fdot2(mp[i2], u2h2(W2p[j * 10 + i2]), c);
          m2[j] = c;
        }
        unsigned int* row = &m2w[t][sl * 11];
#pragma unroll
        for (int pr = 0; pr < 10; ++pr) row[pr] = h22u(pkrtz(m2[2*pr], m2[2*pr+1]));
      }
    }
    __syncthreads();
    int we = (wb + 128 < tend) ? (wb + 128) : tend;
#pragma unroll
    for (int k = 0; k < 3; ++k) {
      int lo = itB[k] > wb ? itB[k] : wb;
      int hi = itE[k] < we ? itE[k] : we;
      for (int s = lo; s < hi; ++s) {
        half2v h2 = u2h2(m2w[t][(s - wb) * 11 + itP[k]]);
        float v0 = (float)h2.x, v1 = (float)h2.y;
        sS[k][0] += v0; sQ[k][0] = fmaf(v0, v0, sQ[k][0]);
        sN[k][0] = fminf(sN[k][0], v0); sX[k][0] = fmaxf(sX[k][0], v0);
        sS[k][1] += v1; sQ[k][1] = fmaf(v1, v1, sQ[k][1]);
        sN[k][1] = fminf(sN[k][1], v1); sX[k][1] = fmaxf(sX[k][1], v1);
      }
    }
    __syncthreads();
  }

#pragma unroll
  for (int k = 0; k < 3; ++k) {
    int it = lane + 64 * k;
    if (it < ITEMS) {
      int n = n0 + itN[k];
      if (n < NN) {
        float inv = inv_deg[n];
        bool noe = (itE[k] <= itB[k]);
        float mu0 = sS[k][0] * inv, mu1 = sS[k][1] * inv;
        float sd0 = sqrtf(fmaxf(sQ[k][0] * inv - mu0 * mu0, 0.f) + 1e-5f);
        float sd1 = sqrtf(fmaxf(sQ[k][1] * inv - mu1 * mu1, 0.f) + 1e-5f);
        float mn0 = noe ? 0.f : sN[k][0], mn1 = noe ? 0.f : sN[k][1];
        float mx0 = noe ? 0.f : sX[k][0], mx1 = noe ? 0.f : sX[k][1];
        unsigned short* ab = aggbuf + ((size_t)n * 4 + t_u) * 80;
        ((unsigned int*)(ab))[itP[k]]      = pack_bf16(mu0, mu1);
        ((unsigned int*)(ab + 20))[itP[k]] = pack_bf16(mn0, mn1);
        ((unsigned int*)(ab + 40))[itP[k]] = pack_bf16(mx0, mx1);
        ((unsigned int*)(ab + 60))[itP[k]] = pack_bf16(sd0, sd1);
      }
    }
  }
}

// ---------------- FUSED post-MLP + lin + BN colsum (v3: coalesced outl via transpose) ----------------
// Block = 64 nodes x 4 waves. Phase A: wave=tower, post2 via dot2 -> LDS rows[64][81].
// Phase B: wave=d-chunk, Wl wave-uniform s_loads; acc kept in registers (NO strided store).
// Phase C: transpose acc -> rows[d][66]; colsum + COALESCED outl write from transpose.
__global__ __launch_bounds__(256) void k_postlin(
    const float* __restrict__ h, const unsigned short* __restrict__ aggbuf,
    const float* __restrict__ s1a, const float* __restrict__ s2a,
    const float* __restrict__ post_w1, const float* __restrict__ post_b1,
    const unsigned int* __restrict__ q1pk, const unsigned int* __restrict__ q2pk,
    const float* __restrict__ post_b2,
    const float* __restrict__ lin_w, const float* __restrict__ lin_b,
    float* __restrict__ outl, float* __restrict__ colsum, int l) {
  __shared__ float rows[5280];  // phase A/B: [node][81] (5184); phase C: [d][66] (5280)
  int tid = threadIdx.x;
  int t = tid >> 6, lane = tid & 63;
  int t_u = __builtin_amdgcn_readfirstlane(t);
  int wt_u = __builtin_amdgcn_readfirstlane(l * TT + t);
  int n = blockIdx.x * 64 + lane;

  // ---- phase A: post2 for (node=lane, tower=t) ----
  const float* Q1 = post_w1 + (size_t)wt_u * 5200;
  const float* B1 = post_b1 + (size_t)wt_u * FF;
  const float* B2 = post_b2 + (size_t)wt_u * FF;
  const unsigned int* q1 = q1pk + (size_t)t_u * 120 * FF;
  const unsigned int* q2 = q2pk + (size_t)t_u * 10 * FF;
  if (n < NN) {
    float c1 = s1a[n], c2 = s2a[n];
    half2v c1p = pkrtz(c1, c1), c2p = pkrtz(c2, c2);
    float xt[FF];
    {
      const float4* pp = (const float4*)(h + (size_t)n * DD + t_u * FF);
#pragma unroll
      for (int i = 0; i < 5; ++i) { float4 v = pp[i]; xt[i*4]=v.x; xt[i*4+1]=v.y; xt[i*4+2]=v.z; xt[i*4+3]=v.w; }
    }
    half2v a0p[40];
    {
      const uint4* ap = (const uint4*)(aggbuf + ((size_t)n * 4 + t_u) * 80);
#pragma unroll
      for (int q = 0; q < 10; ++q) {
        uint4 v = ap[q];
        unsigned int w[4] = {v.x, v.y, v.z, v.w};
#pragma unroll
        for (int k = 0; k < 4; ++k) {
          unsigned int u = w[k];
          float lo = __uint_as_float(u << 16);
          float hi = __uint_as_float(u & 0xffff0000u);
          a0p[q * 4 + k] = pkrtz(lo, hi);
        }
      }
    }
    float o1[FF];
#pragma unroll
    for (int j = 0; j < FF; ++j) o1[j] = B1[j];
#pragma unroll
    for (int i = 0; i < FF; ++i) {
      float a = xt[i];
#pragma unroll
      for (int j = 0; j < FF; ++j) o1[j] = fmaf(a, Q1[i * FF + j], o1[j]);
    }
#pragma unroll 2
    for (int k = 0; k < 40; ++k) {
      half2v act = a0p[k];
      const unsigned int* wr = q1 + k * FF;
#pragma unroll
      for (int j = 0; j < FF; ++j) o1[j] = fdot2(act, u2h2(wr[j]), o1[j]);
    }
#pragma unroll 2
    for (int k = 0; k < 40; ++k) {
      half2v act = a0p[k] * c1p;
      const unsigned int* wr = q1 + (40 + k) * FF;
#pragma unroll
      for (int j = 0; j < FF; ++j) o1[j] = fdot2(act, u2h2(wr[j]), o1[j]);
    }
#pragma unroll 2
    for (int k = 0; k < 40; ++k) {
      half2v act = a0p[k] * c2p;
      const unsigned int* wr = q1 + (80 + k) * FF;
#pragma unroll
      for (int j = 0; j < FF; ++j) o1[j] = fdot2(act, u2h2(wr[j]), o1[j]);
    }
    half2v o1p[10];
#pragma unroll
    for (int i2 = 0; i2 < 10; ++i2)
      o1p[i2] = pkrtz(fmaxf(o1[2*i2], 0.f), fmaxf(o1[2*i2+1], 0.f));
    float o2[FF];
#pragma unroll
    for (int j = 0; j < FF; ++j) o2[j] = B2[j];
#pragma unroll 2
    for (int i2 = 0; i2 < 10; ++i2) {
      half2v act = o1p[i2];
      const unsigned int* wr = q2 + i2 * FF;
#pragma unroll
      for (int j = 0; j < FF; ++j) o2[j] = fdot2(act, u2h2(wr[j]), o2[j]);
    }
#pragma unroll
    for (int j = 0; j < FF; ++j) rows[lane * 81 + t_u * FF + j] = o2[j];
  } else {
#pragma unroll
    for (int j = 0; j < FF; ++j) rows[lane * 81 + t_u * FF + j] = 0.f;
  }
  __syncthreads();

  // ---- phase B: lin 80x80; wave = d-chunk (Wl wave-uniform -> s_loads) ----
  int n2 = blockIdx.x * 64 + lane;
  const float* WlG = lin_w + (size_t)l * DD * DD + t_u * FF;  // column block of this wave
  float acc[FF];
#pragma unroll
  for (int j = 0; j < FF; ++j) acc[j] = lin_b[l * DD + t_u * FF + j];
  for (int i = 0; i < DD; ++i) {
    float r = rows[lane * 81 + i];
    const float* wl = WlG + i * DD;   // wave-uniform address
#pragma unroll
    for (int j = 0; j < FF; ++j) acc[j] = fmaf(r, wl[j], acc[j]);
  }
  bool valid = (n2 < NN);
  __syncthreads();   // all reads of rows done before phase C overwrites

  // ---- phase C: transpose acc -> rows[d][66]; colsum + coalesced outl write ----
#pragma unroll
  for (int j = 0; j < FF; ++j) rows[(t_u * FF + j) * 66 + lane] = valid ? acc[j] : 0.f;
  __syncthreads();
  if (tid < DD) {
    float s = 0.f;
    for (int k = 0; k < 64; ++k) s += rows[tid * 66 + k];
    atomicAdd(&colsum[tid], s);
  }
  // coalesced outl write: thread i covers node i/20, float4 chunk (i%20)*4
  {
    int nb = blockIdx.x * 64;
    for (int i = tid; i < 64 * 20; i += 256) {
      int nl = i / 20;
      int c4 = (i - nl * 20) * 4;
      int gn = nb + nl;
      if (gn < NN) {
        float4 v = make_float4(rows[(c4 + 0) * 66 + nl], rows[(c4 + 1) * 66 + nl],
                               rows[(c4 + 2) * 66 + nl], rows[(c4 + 3) * 66 + nl]);
        *(float4*)(outl + (size_t)gn * DD + c4) = v;
      }
    }
  }
  __syncthreads();
#pragma unroll
  for (int j = 0; j < FF; ++j) rows[(t_u * FF + j) * 66 + lane] = valid ? acc[j] * acc[j] : 0.f;
  __syncthreads();
  if (tid < DD) {
    float s = 0.f;
    for (int k = 0; k < 64; ++k) s += rows[tid * 66 + k];
    atomicAdd(&colsum[DD + tid], s);
  }
}

// ---------------- BN finalize + apply + relu + residual ----------------
__global__ __launch_bounds__(256) void k_bnapply(const float* __restrict__ outl,
                                                 const float* __restrict__ colsum,
                                                 const float* __restrict__ bn_g,
                                                 const float* __restrict__ bn_b,
                                                 float* __restrict__ h, int l) {
  __shared__ float sc[DD], ofs[DD];
  int tid = threadIdx.x;
  if (tid < DD) {
    float mu = colsum[tid] * (1.0f / NN);
    float var = colsum[DD + tid] * (1.0f / NN) - mu * mu;
    float s = bn_g[l * DD + tid] * rsqrtf(var + 1e-5f);
    sc[tid] = s;
    ofs[tid] = bn_b[l * DD + tid] - mu * s;
  }
  __syncthreads();
  int idx = blockIdx.x * 256 + tid;
  if (idx >= NN * DD) return;
  int d = idx % DD;
  float v = fmaf(outl[idx], sc[d], ofs[d]);
  h[idx] += fmaxf(v, 0.f);
}

// ---------------- graph pooling ----------------
__global__ __launch_bounds__(256) void k_gcnt(const int* __restrict__ batch, int* __restrict__ gcnt) {
  __shared__ int hcnt[GG];
  int tid = threadIdx.x;
  if (tid < GG) hcnt[tid] = 0;
  __syncthreads();
  int n = blockIdx.x * 256 + tid;
  if (n < NN) atomicAdd(&hcnt[batch[n]], 1);
  __syncthreads();
  if (tid < GG && hcnt[tid] > 0) atomicAdd(&gcnt[tid], hcnt[tid]);
}

__global__ void k_gstart(const int* __restrict__ gcnt, int* __restrict__ gstart) {
  if (threadIdx.x == 0 && blockIdx.x == 0) {
    int acc = 0;
    for (int g = 0; g < GG; ++g) { gstart[g] = acc; acc += gcnt[g]; }
  }
}

__global__ __launch_bounds__(320) void k_gmean(const float* __restrict__ h,
                                               const int* __restrict__ gstart,
                                               const int* __restrict__ gcnt,
                                               float* __restrict__ gbuf) {
  __shared__ float red[320];
  int g = blockIdx.x, tid = threadIdx.x;
  int nl = tid / DD, d = tid - nl * DD;
  int start = gstart[g], c = gcnt[g];
  float acc = 0.f;
  for (int r = start + nl; r < start + c; r += 4) acc += h[(size_t)r * DD + d];
  red[tid] = acc;
  __syncthreads();
  if (tid < DD) {
    float s = red[tid] + red[tid + DD] + red[tid + 2 * DD] + red[tid + 3 * DD];
    float cf = (c > 0) ? (float)c : 1.0f;
    gbuf[g * DD + tid] = s / cf;
  }
}

// ---------------- final MLP (tiny) ----------------
__global__ __launch_bounds__(64) void k_mlp(const float* __restrict__ gbuf,
                                            const float* __restrict__ w1, const float* __restrict__ b1,
                                            const float* __restrict__ w2, const float* __restrict__ b2,
                                            const float* __restrict__ w3, const float* __restrict__ b3,
                                            float* __restrict__ out) {
  __shared__ float row[DD];
  __shared__ float t1[40];
  __shared__ float t2[20];
  int g = blockIdx.x, tid = threadIdx.x;
  for (int i = tid; i < DD; i += 64) row[i] = gbuf[g * DD + i];
  __syncthreads();
  if (tid < 40) {
    float acc = b1[tid];
#pragma unroll
    for (int i = 0; i < DD; ++i) acc = fmaf(row[i], w1[i * 40 + tid], acc);
    t1[tid] = fmaxf(acc, 0.f);
  }
  __syncthreads();
  if (tid < 20) {
    float acc = b2[tid];
#pragma unroll
    for (int i = 0; i < 40; ++i) acc = fmaf(t1[i], w2[i * 20 + tid], acc);
    t2[tid] = fmaxf(acc, 0.f);
  }
  __syncthreads();
  if (tid == 0) {
    float acc = b3[0];
#pragma unroll
    for (int i = 0; i < 20; ++i) acc = fmaf(t2[i], w3[i], acc);
    out[g] = acc;
  }
}

extern "C" void kernel_launch(void* const* d_in, const int* in_sizes, int n_in,
                              void* d_out, int out_size, void* d_ws, size_t ws_size,
                              hipStream_t stream) {
  const int*   x         = (const int*)d_in[0];
  const int*   ei        = (const int*)d_in[1];
  const int*   batch     = (const int*)d_in[2];
  const float* edge_attr = (const float*)d_in[3];
  const float* atom_emb  = (const float*)d_in[4];
  const float* edge_w    = (const float*)d_in[5];
  const float* edge_b    = (const float*)d_in[6];
  const float* pre_w1    = (const float*)d_in[7];
  const float* pre_b1    = (const float*)d_in[8];
  const float* pre_w2    = (const float*)d_in[9];
  const float* pre_b2    = (const float*)d_in[10];
  const float* post_w1   = (const float*)d_in[11];
  const float* post_b1   = (const float*)d_in[12];
  const float* post_w2   = (const float*)d_in[13];
  const float* post_b2   = (const float*)d_in[14];
  const float* lin_w     = (const float*)d_in[15];
  const float* lin_b     = (const float*)d_in[16];
  const float* bn_g      = (const float*)d_in[17];
  const float* bn_b      = (const float*)d_in[18];
  const float* mlp_w1    = (const float*)d_in[19];
  const float* mlp_b1    = (const float*)d_in[20];
  const float* mlp_w2    = (const float*)d_in[21];
  const float* mlp_b2    = (const float*)d_in[22];
  const float* mlp_w3    = (const float*)d_in[23];
  const float* mlp_b3    = (const float*)d_in[24];
  float* out = (float*)d_out;

  // workspace carve-up (~116 MB)
  char* ws = (char*)d_ws;
  size_t off = 0;
  auto alloc = [&](size_t bytes) -> void* {
    void* p = ws + off;
    off += (bytes + 15) & ~(size_t)15;
    return p;
  };
  float* h       = (float*)alloc((size_t)NN * DD * 4);           // 16 MB
  float* outl    = (float*)alloc((size_t)NN * DD * 4);           // 16 MB (post-lin output)
  unsigned short* predD = (unsigned short*)alloc((size_t)NN * DD * 2); // 8 MB bf16
  unsigned short* predS = (unsigned short*)alloc((size_t)NN * DD * 2); // 8 MB bf16
  int*   csr_src = (int*)alloc((size_t)EE * 4);                  // 3.2 MB
  int*   csr_eid = (int*)alloc((size_t)EE * 4);                  // 3.2 MB
  int*   csr_dst = (int*)alloc((size_t)EE * 4);                  // 3.2 MB
  unsigned int* ea16 = (unsigned int*)alloc((size_t)EE * 8 * 4); // 25.6 MB f16 CSR-ordered ea
  int*   row_ptr = (int*)alloc((size_t)(NN + 1) * 4);
  int*   cnt     = (int*)alloc((size_t)NN * 4);
  int*   cursor  = (int*)alloc((size_t)NN * 4);
  float* inv_deg = (float*)alloc((size_t)NN * 4);
  float* s1a     = (float*)alloc((size_t)NN * 4);
  float* s2a     = (float*)alloc((size_t)NN * 4);
  float* colsum  = (float*)alloc(2 * DD * 4);
  float* gbuf    = (float*)alloc((size_t)GG * DD * 4);
  unsigned int* wcpk  = (unsigned int*)alloc((size_t)TT * FF * 8 * 4);
  unsigned int* w2pk  = (unsigned int*)alloc((size_t)TT * FF * 10 * 4);
  unsigned int* q1pk  = (unsigned int*)alloc((size_t)TT * 120 * FF * 4);
  unsigned int* q2pk  = (unsigned int*)alloc((size_t)TT * 10 * FF * 4);
  float* biasc   = (float*)alloc((size_t)TT * FF * 4);
  int*   bsum    = (int*)alloc((size_t)SCAN_B * 4);
  int*   boff    = (int*)alloc((size_t)SCAN_B * 4);
  int*   gcnt    = (int*)alloc((size_t)GG * 4);
  int*   gstart  = (int*)alloc((size_t)(GG + 1) * 4);
  unsigned short* aggbuf = (unsigned short*)alloc((size_t)NN * 4 * 80 * 2); // 32 MB bf16
  (void)in_sizes; (void)n_in; (void)out_size; (void)ws_size;

  hipMemsetAsync(cnt, 0, (size_t)NN * 4, stream);
  k_h<<<(NN * DD + 255) / 256, 256, 0, stream>>>(x, atom_emb, h);
  k_deg<<<(EE + 255) / 256, 256, 0, stream>>>(ei, cnt);
  k_scan_sum<<<SCAN_B, 1024, 0, stream>>>(cnt, bsum);
  k_scan_top<<<1, 64, 0, stream>>>(bsum, boff, row_ptr);
  k_scan_apply<<<SCAN_B, 1024, 0, stream>>>(cnt, boff, row_ptr, cursor);
  k_csrfill<<<(EE + 255) / 256, 256, 0, stream>>>(ei, cursor, csr_src, csr_eid, csr_dst);
  k_eagather<<<(EE + 255) / 256, 256, 0, stream>>>(csr_eid, edge_attr, ea16);
  k_nodeparams<<<(NN + 255) / 256, 256, 0, stream>>>(cnt, inv_deg, s1a, s2a);

  int tilesA = (NN + TILE_N - 1) / TILE_N;   // 3125
  int blocksPL = (NN + 63) / 64;             // 782
  for (int l = 0; l < LL; ++l) {
    k_wcomb<<<TT, 64, 0, stream>>>(edge_w, edge_b, pre_w1, pre_b1, pre_w2,
        post_w1, post_w2, wcpk, w2pk, q1pk, q2pk, biasc, colsum, l);
    k_prenode<<<(NN + 63) / 64, 256, 0, stream>>>(h, pre_w1, biasc, predD, predS, l);
    k_preagg<<<tilesA, 256, 0, stream>>>(predD, predS, ea16, csr_src, csr_dst, row_ptr,
        inv_deg, wcpk, w2pk, pre_b2, aggbuf, l);
    k_postlin<<<blocksPL, 256, 0, stream>>>(h, aggbuf, s1a, s2a,
        post_w1, post_b1, q1pk, q2pk, post_b2, lin_w, lin_b, outl, colsum, l);
    k_bnapply<<<(NN * DD + 255) / 256, 256, 0, stream>>>(outl, colsum, bn_g, bn_b, h, l);
  }

  hipMemsetAsync(gcnt, 0, (size_t)GG * 4, stream);
  k_gcnt<<<(NN + 255) / 256, 256, 0, stream>>>(batch, gcnt);
  k_gstart<<<1, 64, 0, stream>>>(gcnt, gstart);
  k_gmean<<<GG, 320, 0, stream>>>(h, gstart, gcnt, gbuf);
  k_mlp<<<GG, 64, 0, stream>>>(gbuf, mlp_w1, mlp_b1, mlp_w2, mlp_b2, mlp_w3, mlp_b3, out);
}

// Round 12
// 1358.244 us; speedup vs baseline: 1.4098x; 1.0094x over previous
//
#include <hip/hip_runtime.h>
#include <hip/hip_bf16.h>

// Problem constants (from reference)
#define NN 50000
#define EE 800000
#define GG 128
#define LL 4
#define TT 4
#define FF 20
#define DD 80
#define SCAN_B ((NN + 1023) / 1024)   // 49
#define TILE_N 16                     // nodes per k_preagg tile (avg 256 slots)
#define ITEMS (TILE_N * 10)           // 160 (node, ch-pair) reduce items per tower
static constexpr float AVG_LOG = 2.8332133440562162f; // ln(17)

typedef __fp16 half2v __attribute__((ext_vector_type(2)));

__device__ __forceinline__ float bf2f(unsigned short u) {
  return __uint_as_float((unsigned)u << 16);
}
__device__ __forceinline__ unsigned short f2bf(float f) {
  __hip_bfloat16 b = __float2bfloat16(f); // RNE
  return *(unsigned short*)&b;
}
__device__ __forceinline__ half2v pkrtz(float a, float b) {
#if __has_builtin(__builtin_amdgcn_cvt_pkrtz)
  return __builtin_amdgcn_cvt_pkrtz(a, b);
#else
  half2v h; h.x = (__fp16)a; h.y = (__fp16)b; return h;
#endif
}
__device__ __forceinline__ float fdot2(half2v a, half2v b, float c) {
#if __has_builtin(__builtin_amdgcn_fdot2)
  return __builtin_amdgcn_fdot2(a, b, c, false);
#else
  return fmaf((float)a.x, (float)b.x, fmaf((float)a.y, (float)b.y, c));
#endif
}
__device__ __forceinline__ half2v u2h2(unsigned int u) {
  return __builtin_bit_cast(half2v, u);
}
__device__ __forceinline__ unsigned int h22u(half2v h) {
  return __builtin_bit_cast(unsigned int, h);
}
__device__ __forceinline__ unsigned int packh2_rne(float a, float b) {
  half2v h; h.x = (__fp16)a; h.y = (__fp16)b; // RNE casts for weights
  return h22u(h);
}
__device__ __forceinline__ unsigned int pack_bf16(float a, float b) {
  return (unsigned int)f2bf(a) | ((unsigned int)f2bf(b) << 16);
}

// ---------------- h init: h[n,d] = sum_i atom_emb[i, x[n,i], d] ----------------
__global__ __launch_bounds__(256) void k_h(const int* __restrict__ x,
                                           const float* __restrict__ atom_emb,
                                           float* __restrict__ h) {
  int idx = blockIdx.x * 256 + threadIdx.x;
  if (idx >= NN * DD) return;
  int n = idx / DD, d = idx - n * DD;
  const int* xr = x + n * 9;
  float acc = 0.f;
#pragma unroll
  for (int i = 0; i < 9; ++i) {
    int v = xr[i];
    acc += atom_emb[(i * 16 + v) * DD + d];
  }
  h[idx] = acc;
}

// ---------------- degree count ----------------
__global__ __launch_bounds__(256) void k_deg(const int* __restrict__ ei, int* __restrict__ cnt) {
  int e = blockIdx.x * 256 + threadIdx.x;
  if (e >= EE) return;
  atomicAdd(&cnt[ei[EE + e]], 1); // dst = edge_index[1][e]
}

// ---------------- hierarchical exclusive scan ----------------
__global__ __launch_bounds__(1024) void k_scan_sum(const int* __restrict__ cnt, int* __restrict__ bsum) {
  __shared__ int red[1024];
  int tid = threadIdx.x;
  int i = blockIdx.x * 1024 + tid;
  red[tid] = (i < NN) ? cnt[i] : 0;
  __syncthreads();
  for (int off = 512; off > 0; off >>= 1) {
    if (tid < off) red[tid] += red[tid + off];
    __syncthreads();
  }
  if (tid == 0) bsum[blockIdx.x] = red[0];
}

__global__ void k_scan_top(const int* __restrict__ bsum, int* __restrict__ boff,
                           int* __restrict__ row_ptr) {
  if (threadIdx.x == 0 && blockIdx.x == 0) {
    int acc = 0;
    for (int b = 0; b < SCAN_B; ++b) { boff[b] = acc; acc += bsum[b]; }
    row_ptr[NN] = acc;
  }
}

__global__ __launch_bounds__(1024) void k_scan_apply(const int* __restrict__ cnt,
                                                     const int* __restrict__ boff,
                                                     int* __restrict__ row_ptr,
                                                     int* __restrict__ cursor) {
  __shared__ int sm[1024];
  int tid = threadIdx.x;
  int i = blockIdx.x * 1024 + tid;
  int v = (i < NN) ? cnt[i] : 0;
  sm[tid] = v;
  __syncthreads();
  for (int off = 1; off < 1024; off <<= 1) {
    int t = (tid >= off) ? sm[tid - off] : 0;
    __syncthreads();
    sm[tid] += t;
    __syncthreads();
  }
  int excl = boff[blockIdx.x] + sm[tid] - v;
  if (i < NN) { row_ptr[i] = excl; cursor[i] = excl; }
}

// ---------------- CSR fill: slot -> src / eid / dst (split arrays) ----------------
__global__ __launch_bounds__(256) void k_csrfill(const int* __restrict__ ei,
                                                 int* __restrict__ cursor,
                                                 int* __restrict__ csr_src,
                                                 int* __restrict__ csr_eid,
                                                 int* __restrict__ csr_dst) {
  int e = blockIdx.x * 256 + threadIdx.x;
  if (e >= EE) return;
  int dst = ei[EE + e];
  int slot = atomicAdd(&cursor[dst], 1);
  csr_src[slot] = ei[e];
  csr_eid[slot] = e;
  csr_dst[slot] = dst;
}

// ---------------- one-time edge_attr gather into CSR slot order, f16 pairs ----------------
__global__ __launch_bounds__(256) void k_eagather(const int* __restrict__ csr_eid,
                                                  const float* __restrict__ edge_attr,
                                                  unsigned int* __restrict__ ea16) {
  int sl = blockIdx.x * 256 + threadIdx.x;
  if (sl >= EE) return;
  int e = csr_eid[sl];
  const float4* ap = (const float4*)(edge_attr + (size_t)e * 16);
  uint4 o0, o1;
  float4 v0 = ap[0], v1 = ap[1], v2 = ap[2], v3 = ap[3];
  o0.x = packh2_rne(v0.x, v0.y); o0.y = packh2_rne(v0.z, v0.w);
  o0.z = packh2_rne(v1.x, v1.y); o0.w = packh2_rne(v1.z, v1.w);
  o1.x = packh2_rne(v2.x, v2.y); o1.y = packh2_rne(v2.z, v2.w);
  o1.z = packh2_rne(v3.x, v3.y); o1.w = packh2_rne(v3.z, v3.w);
  uint4* op = (uint4*)(ea16 + (size_t)sl * 8);
  op[0] = o0; op[1] = o1;
}

// ---------------- per-node params ----------------
__global__ __launch_bounds__(256) void k_nodeparams(const int* __restrict__ cnt,
                                                    float* __restrict__ inv_deg,
                                                    float* __restrict__ s1a,
                                                    float* __restrict__ s2a) {
  int n = blockIdx.x * 256 + threadIdx.x;
  if (n >= NN) return;
  int c = cnt[n];
  float deg = (c > 0) ? (float)c : 1.0f;
  inv_deg[n] = 1.0f / deg;
  float logd = logf(deg + 1.0f);
  s1a[n] = logd / AVG_LOG;
  s2a[n] = AVG_LOG / logd;
}

// ---------------- per-layer weight composition + ALL f16 packing + colsum zero ----------------
__global__ __launch_bounds__(64) void k_wcomb(const float* __restrict__ edge_w,
                                              const float* __restrict__ edge_b,
                                              const float* __restrict__ pre_w1,
                                              const float* __restrict__ pre_b1,
                                              const float* __restrict__ pre_w2,
                                              const float* __restrict__ post_w1,
                                              const float* __restrict__ post_w2,
                                              unsigned int* __restrict__ wcpk,
                                              unsigned int* __restrict__ w2pk,
                                              unsigned int* __restrict__ q1pk,
                                              unsigned int* __restrict__ q2pk,
                                              float* __restrict__ biasc,
                                              float* __restrict__ colsum, int l) {
  int t = blockIdx.x;
  int wt = l * TT + t;
  int j = threadIdx.x;
  if (t == 0) {
    for (int i = threadIdx.x; i < 2 * DD; i += 64) colsum[i] = 0.f;
  }
  if (j >= FF) return;
  const float* W1 = pre_w1 + (size_t)wt * 1200; // [60][20]
  const float* W2 = pre_w2 + (size_t)wt * 400;  // [20][20]
  const float* ew = edge_w + (size_t)l * 16 * FF;
  const float* eb = edge_b + (size_t)l * FF;
  float col[16];
  for (int i = 0; i < 16; ++i) {
    float acc = 0.f;
#pragma unroll
    for (int f = 0; f < FF; ++f) acc = fmaf(ew[i * FF + f], W1[(40 + f) * FF + j], acc);
    col[i] = acc;
  }
#pragma unroll
  for (int i2 = 0; i2 < 8; ++i2)
    wcpk[((size_t)t * FF + j) * 8 + i2] = packh2_rne(col[2 * i2], col[2 * i2 + 1]);
#pragma unroll
  for (int i2 = 0; i2 < 10; ++i2)
    w2pk[((size_t)t * FF + j) * 10 + i2] = packh2_rne(W2[(2 * i2) * FF + j], W2[(2 * i2 + 1) * FF + j]);
  float b = pre_b1[wt * FF + j];
#pragma unroll
  for (int f = 0; f < FF; ++f) b = fmaf(eb[f], W1[(40 + f) * FF + j], b);
  biasc[t * FF + j] = b;
  // post-MLP packing
  const float* Q1 = post_w1 + (size_t)wt * 5200;
  const float* Q2 = post_w2 + (size_t)wt * 400;
  for (int i2 = 0; i2 < 120; ++i2) {
    int blk = i2 / 40, k = i2 - blk * 40;
    int r0 = 20 + 80 * blk + 2 * k;
    q1pk[((size_t)t * 120 + i2) * FF + j] = packh2_rne(Q1[r0 * FF + j], Q1[(r0 + 1) * FF + j]);
  }
#pragma unroll
  for (int i2 = 0; i2 < 10; ++i2)
    q2pk[((size_t)t * 10 + i2) * FF + j] = packh2_rne(Q2[(2 * i2) * FF + j], Q2[(2 * i2 + 1) * FF + j]);
}

// ---------------- per-node pre contributions (bf16 out) ----------------
__global__ __launch_bounds__(256) void k_prenode(
    const float* __restrict__ h, const float* __restrict__ pre_w1,
    const float* __restrict__ biasc,
    unsigned short* __restrict__ predD, unsigned short* __restrict__ predS, int l) {
  int tid = threadIdx.x;
  int t = tid >> 6, lane = tid & 63;
  int n = blockIdx.x * 64 + lane;
  if (n >= NN) return;
  int wt_u = __builtin_amdgcn_readfirstlane(l * TT + t);
  const float* W1 = pre_w1 + (size_t)wt_u * 1200;
  const float* bc = biasc + t * FF;
  float xt[FF];
  {
    const float4* pp = (const float4*)(h + (size_t)n * DD + t * FF);
#pragma unroll
    for (int i = 0; i < 5; ++i) { float4 v = pp[i]; xt[i*4]=v.x; xt[i*4+1]=v.y; xt[i*4+2]=v.z; xt[i*4+3]=v.w; }
  }
  float d[FF], s[FF];
#pragma unroll
  for (int j = 0; j < FF; ++j) { d[j] = bc[j]; s[j] = 0.f; }
#pragma unroll
  for (int i = 0; i < FF; ++i) {
    float a = xt[i];
#pragma unroll
    for (int j = 0; j < FF; ++j) {
      d[j] = fmaf(a, W1[i * FF + j], d[j]);
      s[j] = fmaf(a, W1[(FF + i) * FF + j], s[j]);
    }
  }
  ushort4* pd = (ushort4*)(predD + (size_t)n * DD + t * FF);
  ushort4* ps = (ushort4*)(predS + (size_t)n * DD + t * FF);
#pragma unroll
  for (int i = 0; i < 5; ++i) {
    pd[i] = make_ushort4(f2bf(d[i*4]), f2bf(d[i*4+1]), f2bf(d[i*4+2]), f2bf(d[i*4+3]));
    ps[i] = make_ushort4(f2bf(s[i*4]), f2bf(s[i*4+1]), f2bf(s[i*4+2]), f2bf(s[i*4+3]));
  }
}

// ---------------- FUSED edge pre-MLP + aggregation, tower-colocated, balanced reduce ----------------
// v3: 128-slot windows (2 edges/lane) — halves barriers, amortizes reduce max-divergence.
__global__ __launch_bounds__(256, 4) void k_preagg(
    const unsigned short* __restrict__ predD,
    const unsigned short* __restrict__ predS,
    const unsigned int* __restrict__ ea16,
    const int* __restrict__ csr_src,
    const int* __restrict__ csr_dst,
    const int* __restrict__ row_ptr,
    const float* __restrict__ inv_deg,
    const unsigned int* __restrict__ wcpk,
    const unsigned int* __restrict__ w2pk,
    const float* __restrict__ pre_b2,
    unsigned short* __restrict__ aggbuf,
    int l) {
  __shared__ int nbr[TILE_N + 1];
  __shared__ float dDs[TT][TILE_N * FF];       // 5.1 KB
  __shared__ unsigned int m2w[TT][128 * 11];   // 22.5 KB, stride-11: conflict-free
  int tid = threadIdx.x;
  int t = tid >> 6, lane = tid & 63;
  int t_u = __builtin_amdgcn_readfirstlane(t);
  int n0 = blockIdx.x * TILE_N;
  const unsigned int* Wcp = wcpk + (size_t)t_u * FF * 8;
  const unsigned int* W2p = w2pk + (size_t)t_u * FF * 10;
  const float* b2 = pre_b2 + (size_t)(l * TT + t_u) * FF;

  if (tid <= TILE_N) {
    int node = n0 + tid; if (node > NN) node = NN;
    nbr[tid] = row_ptr[node];
  }
  for (int i = lane; i < TILE_N * FF; i += 64) {
    int ni = i / FF, ch = i - ni * FF;
    int node = n0 + ni;
    dDs[t][i] = (node < NN) ? bf2f(predD[(size_t)node * DD + t_u * FF + ch]) : 0.f;
  }
  __syncthreads();
  int tbeg = nbr[0], tend = nbr[TILE_N];

  int itN[3], itP[3], itB[3], itE[3];
#pragma unroll
  for (int k = 0; k < 3; ++k) {
    int it = lane + 64 * k;
    bool v = it < ITEMS;
    int nd = v ? (it / 10) : 0;
    itN[k] = nd;
    itP[k] = v ? (it - nd * 10) : 0;
    itB[k] = v ? nbr[nd] : 0;
    itE[k] = v ? nbr[nd + 1] : 0;
  }
  float sS[3][2], sQ[3][2], sN[3][2], sX[3][2];
#pragma unroll
  for (int k = 0; k < 3; ++k) {
    sS[k][0] = 0.f; sS[k][1] = 0.f; sQ[k][0] = 0.f; sQ[k][1] = 0.f;
    sN[k][0] = 3.4e38f; sN[k][1] = 3.4e38f; sX[k][0] = -3.4e38f; sX[k][1] = -3.4e38f;
  }

  for (int wb = tbeg; wb < tend; wb += 128) {
#pragma unroll
    for (int e = 0; e < 2; ++e) {
      int sl = lane + 64 * e;
      int p = wb + sl;
      if (p < tend) {
        int src = csr_src[p];
        int ni = csr_dst[p] - n0;
        float m1[FF];
        {
          const float4* dd = (const float4*)(&dDs[t][ni * FF]);
          const ushort4* qq = (const ushort4*)(predS + (size_t)src * DD + t_u * FF);
#pragma unroll
          for (int i = 0; i < 5; ++i) {
            float4 d4 = dd[i];
            ushort4 v = qq[i];
            m1[i*4+0] = d4.x + bf2f(v.x);
            m1[i*4+1] = d4.y + bf2f(v.y);
            m1[i*4+2] = d4.z + bf2f(v.z);
            m1[i*4+3] = d4.w + bf2f(v.w);
          }
        }
        half2v eap[8];
        {
          const uint4* ep = (const uint4*)(ea16 + (size_t)p * 8);
          uint4 e0 = ep[0], e1 = ep[1];
          eap[0] = u2h2(e0.x); eap[1] = u2h2(e0.y); eap[2] = u2h2(e0.z); eap[3] = u2h2(e0.w);
          eap[4] = u2h2(e1.x); eap[5] = u2h2(e1.y); eap[6] = u2h2(e1.z); eap[7] = u2h2(e1.w);
        }
#pragma unroll
        for (int j = 0; j < FF; ++j) {
          float c = m1[j];
#pragma unroll
          for (int i2 = 0; i2 < 8; ++i2) c = fdot2(eap[i2], u2h2(Wcp[j * 8 + i2]), c);
          m1[j] = c;
        }
        half2v mp[10];
#pragma unroll
        for (int pr = 0; pr < 10; ++pr)
          mp[pr] = pkrtz(fmaxf(m1[2*pr], 0.f), fmaxf(m1[2*pr+1], 0.f));
        float m2[FF];
#pragma unroll
        for (int j = 0; j < FF; ++j) {
          float c = b2[j];
#pragma unroll
          for (int i2 = 0; i2 < 10; ++i2) c = fdot2(mp[i2], u2h2(W2p[j * 10 + i2]), c);
          m2[j] = c;
        }
        unsigned int* row = &m2w[t][sl * 11];
#pragma unroll
        for (int pr = 0; pr < 10; ++pr) row[pr] = h22u(pkrtz(m2[2*pr], m2[2*pr+1]));
      }
    }
    __syncthreads();
    int we = (wb + 128 < tend) ? (wb + 128) : tend;
#pragma unroll
    for (int k = 0; k < 3; ++k) {
      int lo = itB[k] > wb ? itB[k] : wb;
      int hi = itE[k] < we ? itE[k] : we;
      for (int s = lo; s < hi; ++s) {
        half2v h2 = u2h2(m2w[t][(s - wb) * 11 + itP[k]]);
        float v0 = (float)h2.x, v1 = (float)h2.y;
        sS[k][0] += v0; sQ[k][0] = fmaf(v0, v0, sQ[k][0]);
        sN[k][0] = fminf(sN[k][0], v0); sX[k][0] = fmaxf(sX[k][0], v0);
        sS[k][1] += v1; sQ[k][1] = fmaf(v1, v1, sQ[k][1]);
        sN[k][1] = fminf(sN[k][1], v1); sX[k][1] = fmaxf(sX[k][1], v1);
      }
    }
    __syncthreads();
  }

#pragma unroll
  for (int k = 0; k < 3; ++k) {
    int it = lane + 64 * k;
    if (it < ITEMS) {
      int n = n0 + itN[k];
      if (n < NN) {
        float inv = inv_deg[n];
        bool noe = (itE[k] <= itB[k]);
        float mu0 = sS[k][0] * inv, mu1 = sS[k][1] * inv;
        float sd0 = sqrtf(fmaxf(sQ[k][0] * inv - mu0 * mu0, 0.f) + 1e-5f);
        float sd1 = sqrtf(fmaxf(sQ[k][1] * inv - mu1 * mu1, 0.f) + 1e-5f);
        float mn0 = noe ? 0.f : sN[k][0], mn1 = noe ? 0.f : sN[k][1];
        float mx0 = noe ? 0.f : sX[k][0], mx1 = noe ? 0.f : sX[k][1];
        unsigned short* ab = aggbuf + ((size_t)n * 4 + t_u) * 80;
        ((unsigned int*)(ab))[itP[k]]      = pack_bf16(mu0, mu1);
        ((unsigned int*)(ab + 20))[itP[k]] = pack_bf16(mn0, mn1);
        ((unsigned int*)(ab + 40))[itP[k]] = pack_bf16(mx0, mx1);
        ((unsigned int*)(ab + 60))[itP[k]] = pack_bf16(sd0, sd1);
      }
    }
  }
}

// ---------------- FUSED post-MLP + lin + BN colsum (v4: LDS-staged post weights) ----------------
// r11 diagnosis: q1pk/q2pk s_load streams = 41.6 KB per block over 4 towers thrash the
// 16 KB per-CU scalar cache (VALUBusy 19%). Fix: cooperative-stage them into LDS once per
// block; phase A reads weights via wave-uniform ds_read (broadcast, no miss latency).
// Per-thread h/aggbuf gathers issue BEFORE the staging loop so HBM latency hides under it.
__global__ __launch_bounds__(256) void k_postlin(
    const float* __restrict__ h, const unsigned short* __restrict__ aggbuf,
    const float* __restrict__ s1a, const float* __restrict__ s2a,
    const float* __restrict__ post_w1, const float* __restrict__ post_b1,
    const unsigned int* __restrict__ q1pk, const unsigned int* __restrict__ q2pk,
    const float* __restrict__ post_b2,
    const float* __restrict__ lin_w, const float* __restrict__ lin_b,
    float* __restrict__ outl, float* __restrict__ colsum, int l) {
  __shared__ float rows[5280];                 // 21.1 KB: [node][81] in A/B, [d][66] in C
  __shared__ unsigned int lq1[TT * 120 * FF];  // 38.4 KB
  __shared__ unsigned int lq2[TT * 10 * FF];   // 3.2 KB
  int tid = threadIdx.x;
  int t = tid >> 6, lane = tid & 63;
  int t_u = __builtin_amdgcn_readfirstlane(t);
  int wt_u = __builtin_amdgcn_readfirstlane(l * TT + t);
  int n = blockIdx.x * 64 + lane;
  bool nvalid = (n < NN);

  // ---- issue per-thread activation loads FIRST (overlap with weight staging) ----
  float xt[FF];
  uint4 araw[10];
  {
    const float4* pp = (const float4*)(h + (size_t)(nvalid ? n : 0) * DD + t_u * FF);
#pragma unroll
    for (int i = 0; i < 5; ++i) { float4 v = pp[i]; xt[i*4]=v.x; xt[i*4+1]=v.y; xt[i*4+2]=v.z; xt[i*4+3]=v.w; }
    const uint4* ap = (const uint4*)(aggbuf + ((size_t)(nvalid ? n : 0) * 4 + t_u) * 80);
#pragma unroll
    for (int q = 0; q < 10; ++q) araw[q] = ap[q];
  }
  float c1 = s1a[nvalid ? n : 0], c2 = s2a[nvalid ? n : 0];

  // ---- cooperative weight staging into LDS (q1pk: 2400 uint4, q2pk: 200 uint4) ----
  {
    const uint4* s1p = (const uint4*)q1pk;
    uint4* d1 = (uint4*)lq1;
    for (int i = tid; i < TT * 120 * FF / 4; i += 256) d1[i] = s1p[i];
    const uint4* s2p = (const uint4*)q2pk;
    uint4* d2 = (uint4*)lq2;
    for (int i = tid; i < TT * 10 * FF / 4; i += 256) d2[i] = s2p[i];
  }
  __syncthreads();

  // ---- phase A: post2 for (node=lane, tower=t), weights from LDS ----
  const float* Q1 = post_w1 + (size_t)wt_u * 5200;  // fp32 rows [0,20): small, sK$-friendly
  const float* B1 = post_b1 + (size_t)wt_u * FF;
  const float* B2 = post_b2 + (size_t)wt_u * FF;
  const unsigned int* q1 = lq1 + t_u * 120 * FF;
  const unsigned int* q2 = lq2 + t_u * 10 * FF;
  if (nvalid) {
    half2v c1p = pkrtz(c1, c1), c2p = pkrtz(c2, c2);
    half2v a0p[40];
#pragma unroll
    for (int q = 0; q < 10; ++q) {
      unsigned int w[4] = {araw[q].x, araw[q].y, araw[q].z, araw[q].w};
#pragma unroll
      for (int k = 0; k < 4; ++k) {
        unsigned int u = w[k];
        float lo = __uint_as_float(u << 16);
        float hi = __uint_as_float(u & 0xffff0000u);
        a0p[q * 4 + k] = pkrtz(lo, hi);
      }
    }
    float o1[FF];
#pragma unroll
    for (int j = 0; j < FF; ++j) o1[j] = B1[j];
#pragma unroll
    for (int i = 0; i < FF; ++i) {
      float a = xt[i];
#pragma unroll
      for (int j = 0; j < FF; ++j) o1[j] = fmaf(a, Q1[i * FF + j], o1[j]);
    }
#pragma unroll 2
    for (int k = 0; k < 40; ++k) {
      half2v act = a0p[k];
      const unsigned int* wr = q1 + k * FF;
#pragma unroll
      for (int j = 0; j < FF; ++j) o1[j] = fdot2(act, u2h2(wr[j]), o1[j]);
    }
#pragma unroll 2
    for (int k = 0; k < 40; ++k) {
      half2v act = a0p[k] * c1p;
      const unsigned int* wr = q1 + (40 + k) * FF;
#pragma unroll
      for (int j = 0; j < FF; ++j) o1[j] = fdot2(act, u2h2(wr[j]), o1[j]);
    }
#pragma unroll 2
    for (int k = 0; k < 40; ++k) {
      half2v act = a0p[k] * c2p;
      const unsigned int* wr = q1 + (80 + k) * FF;
#pragma unroll
      for (int j = 0; j < FF; ++j) o1[j] = fdot2(act, u2h2(wr[j]), o1[j]);
    }
    half2v o1p[10];
#pragma unroll
    for (int i2 = 0; i2 < 10; ++i2)
      o1p[i2] = pkrtz(fmaxf(o1[2*i2], 0.f), fmaxf(o1[2*i2+1], 0.f));
    float o2[FF];
#pragma unroll
    for (int j = 0; j < FF; ++j) o2[j] = B2[j];
#pragma unroll 2
    for (int i2 = 0; i2 < 10; ++i2) {
      half2v act = o1p[i2];
      const unsigned int* wr = q2 + i2 * FF;
#pragma unroll
      for (int j = 0; j < FF; ++j) o2[j] = fdot2(act, u2h2(wr[j]), o2[j]);
    }
#pragma unroll
    for (int j = 0; j < FF; ++j) rows[lane * 81 + t_u * FF + j] = o2[j];
  } else {
#pragma unroll
    for (int j = 0; j < FF; ++j) rows[lane * 81 + t_u * FF + j] = 0.f;
  }
  __syncthreads();

  // ---- phase B: lin 80x80; wave = d-chunk (Wl wave-uniform -> s_loads, L2-shared) ----
  int n2 = blockIdx.x * 64 + lane;
  const float* WlG = lin_w + (size_t)l * DD * DD + t_u * FF;  // column block of this wave
  float acc[FF];
#pragma unroll
  for (int j = 0; j < FF; ++j) acc[j] = lin_b[l * DD + t_u * FF + j];
  for (int i = 0; i < DD; ++i) {
    float r = rows[lane * 81 + i];
    const float* wl = WlG + i * DD;   // wave-uniform address
#pragma unroll
    for (int j = 0; j < FF; ++j) acc[j] = fmaf(r, wl[j], acc[j]);
  }
  bool valid = (n2 < NN);
  __syncthreads();   // all reads of rows done before phase C overwrites

  // ---- phase C: transpose acc -> rows[d][66]; colsum + coalesced outl write ----
#pragma unroll
  for (int j = 0; j < FF; ++j) rows[(t_u * FF + j) * 66 + lane] = valid ? acc[j] : 0.f;
  __syncthreads();
  if (tid < DD) {
    float s = 0.f;
    for (int k = 0; k < 64; ++k) s += rows[tid * 66 + k];
    atomicAdd(&colsum[tid], s);
  }
  // coalesced outl write: thread i covers node i/20, float4 chunk (i%20)*4
  {
    int nb = blockIdx.x * 64;
    for (int i = tid; i < 64 * 20; i += 256) {
      int nl = i / 20;
      int c4 = (i - nl * 20) * 4;
      int gn = nb + nl;
      if (gn < NN) {
        float4 v = make_float4(rows[(c4 + 0) * 66 + nl], rows[(c4 + 1) * 66 + nl],
                               rows[(c4 + 2) * 66 + nl], rows[(c4 + 3) * 66 + nl]);
        *(float4*)(outl + (size_t)gn * DD + c4) = v;
      }
    }
  }
  __syncthreads();
#pragma unroll
  for (int j = 0; j < FF; ++j) rows[(t_u * FF + j) * 66 + lane] = valid ? acc[j] * acc[j] : 0.f;
  __syncthreads();
  if (tid < DD) {
    float s = 0.f;
    for (int k = 0; k < 64; ++k) s += rows[tid * 66 + k];
    atomicAdd(&colsum[DD + tid], s);
  }
}

// ---------------- BN finalize + apply + relu + residual ----------------
__global__ __launch_bounds__(256) void k_bnapply(const float* __restrict__ outl,
                                                 const float* __restrict__ colsum,
                                                 const float* __restrict__ bn_g,
                                                 const float* __restrict__ bn_b,
                                                 float* __restrict__ h, int l) {
  __shared__ float sc[DD], ofs[DD];
  int tid = threadIdx.x;
  if (tid < DD) {
    float mu = colsum[tid] * (1.0f / NN);
    float var = colsum[DD + tid] * (1.0f / NN) - mu * mu;
    float s = bn_g[l * DD + tid] * rsqrtf(var + 1e-5f);
    sc[tid] = s;
    ofs[tid] = bn_b[l * DD + tid] - mu * s;
  }
  __syncthreads();
  int idx = blockIdx.x * 256 + tid;
  if (idx >= NN * DD) return;
  int d = idx % DD;
  float v = fmaf(outl[idx], sc[d], ofs[d]);
  h[idx] += fmaxf(v, 0.f);
}

// ---------------- graph pooling ----------------
__global__ __launch_bounds__(256) void k_gcnt(const int* __restrict__ batch, int* __restrict__ gcnt) {
  __shared__ int hcnt[GG];
  int tid = threadIdx.x;
  if (tid < GG) hcnt[tid] = 0;
  __syncthreads();
  int n = blockIdx.x * 256 + tid;
  if (n < NN) atomicAdd(&hcnt[batch[n]], 1);
  __syncthreads();
  if (tid < GG && hcnt[tid] > 0) atomicAdd(&gcnt[tid], hcnt[tid]);
}

__global__ void k_gstart(const int* __restrict__ gcnt, int* __restrict__ gstart) {
  if (threadIdx.x == 0 && blockIdx.x == 0) {
    int acc = 0;
    for (int g = 0; g < GG; ++g) { gstart[g] = acc; acc += gcnt[g]; }
  }
}

__global__ __launch_bounds__(320) void k_gmean(const float* __restrict__ h,
                                               const int* __restrict__ gstart,
                                               const int* __restrict__ gcnt,
                                               float* __restrict__ gbuf) {
  __shared__ float red[320];
  int g = blockIdx.x, tid = threadIdx.x;
  int nl = tid / DD, d = tid - nl * DD;
  int start = gstart[g], c = gcnt[g];
  float acc = 0.f;
  for (int r = start + nl; r < start + c; r += 4) acc += h[(size_t)r * DD + d];
  red[tid] = acc;
  __syncthreads();
  if (tid < DD) {
    float s = red[tid] + red[tid + DD] + red[tid + 2 * DD] + red[tid + 3 * DD];
    float cf = (c > 0) ? (float)c : 1.0f;
    gbuf[g * DD + tid] = s / cf;
  }
}

// ---------------- final MLP (tiny) ----------------
__global__ __launch_bounds__(64) void k_mlp(const float* __restrict__ gbuf,
                                            const float* __restrict__ w1, const float* __restrict__ b1,
                                            const float* __restrict__ w2, const float* __restrict__ b2,
                                            const float* __restrict__ w3, const float* __restrict__ b3,
                                            float* __restrict__ out) {
  __shared__ float row[DD];
  __shared__ float t1[40];
  __shared__ float t2[20];
  int g = blockIdx.x, tid = threadIdx.x;
  for (int i = tid; i < DD; i += 64) row[i] = gbuf[g * DD + i];
  __syncthreads();
  if (tid < 40) {
    float acc = b1[tid];
#pragma unroll
    for (int i = 0; i < DD; ++i) acc = fmaf(row[i], w1[i * 40 + tid], acc);
    t1[tid] = fmaxf(acc, 0.f);
  }
  __syncthreads();
  if (tid < 20) {
    float acc = b2[tid];
#pragma unroll
    for (int i = 0; i < 40; ++i) acc = fmaf(t1[i], w2[i * 20 + tid], acc);
    t2[tid] = fmaxf(acc, 0.f);
  }
  __syncthreads();
  if (tid == 0) {
    float acc = b3[0];
#pragma unroll
    for (int i = 0; i < 20; ++i) acc = fmaf(t2[i], w3[i], acc);
    out[g] = acc;
  }
}

extern "C" void kernel_launch(void* const* d_in, const int* in_sizes, int n_in,
                              void* d_out, int out_size, void* d_ws, size_t ws_size,
                              hipStream_t stream) {
  const int*   x         = (const int*)d_in[0];
  const int*   ei        = (const int*)d_in[1];
  const int*   batch     = (const int*)d_in[2];
  const float* edge_attr = (const float*)d_in[3];
  const float* atom_emb  = (const float*)d_in[4];
  const float* edge_w    = (const float*)d_in[5];
  const float* edge_b    = (const float*)d_in[6];
  const float* pre_w1    = (const float*)d_in[7];
  const float* pre_b1    = (const float*)d_in[8];
  const float* pre_w2    = (const float*)d_in[9];
  const float* pre_b2    = (const float*)d_in[10];
  const float* post_w1   = (const float*)d_in[11];
  const float* post_b1   = (const float*)d_in[12];
  const float* post_w2   = (const float*)d_in[13];
  const float* post_b2   = (const float*)d_in[14];
  const float* lin_w     = (const float*)d_in[15];
  const float* lin_b     = (const float*)d_in[16];
  const float* bn_g      = (const float*)d_in[17];
  const float* bn_b      = (const float*)d_in[18];
  const float* mlp_w1    = (const float*)d_in[19];
  const float* mlp_b1    = (const float*)d_in[20];
  const float* mlp_w2    = (const float*)d_in[21];
  const float* mlp_b2    = (const float*)d_in[22];
  const float* mlp_w3    = (const float*)d_in[23];
  const float* mlp_b3    = (const float*)d_in[24];
  float* out = (float*)d_out;

  // workspace carve-up (~116 MB)
  char* ws = (char*)d_ws;
  size_t off = 0;
  auto alloc = [&](size_t bytes) -> void* {
    void* p = ws + off;
    off += (bytes + 15) & ~(size_t)15;
    return p;
  };
  float* h       = (float*)alloc((size_t)NN * DD * 4);           // 16 MB
  float* outl    = (float*)alloc((size_t)NN * DD * 4);           // 16 MB (post-lin output)
  unsigned short* predD = (unsigned short*)alloc((size_t)NN * DD * 2); // 8 MB bf16
  unsigned short* predS = (unsigned short*)alloc((size_t)NN * DD * 2); // 8 MB bf16
  int*   csr_src = (int*)alloc((size_t)EE * 4);                  // 3.2 MB
  int*   csr_eid = (int*)alloc((size_t)EE * 4);                  // 3.2 MB
  int*   csr_dst = (int*)alloc((size_t)EE * 4);                  // 3.2 MB
  unsigned int* ea16 = (unsigned int*)alloc((size_t)EE * 8 * 4); // 25.6 MB f16 CSR-ordered ea
  int*   row_ptr = (int*)alloc((size_t)(NN + 1) * 4);
  int*   cnt     = (int*)alloc((size_t)NN * 4);
  int*   cursor  = (int*)alloc((size_t)NN * 4);
  float* inv_deg = (float*)alloc((size_t)NN * 4);
  float* s1a     = (float*)alloc((size_t)NN * 4);
  float* s2a     = (float*)alloc((size_t)NN * 4);
  float* colsum  = (float*)alloc(2 * DD * 4);
  float* gbuf    = (float*)alloc((size_t)GG * DD * 4);
  unsigned int* wcpk  = (unsigned int*)alloc((size_t)TT * FF * 8 * 4);
  unsigned int* w2pk  = (unsigned int*)alloc((size_t)TT * FF * 10 * 4);
  unsigned int* q1pk  = (unsigned int*)alloc((size_t)TT * 120 * FF * 4);
  unsigned int* q2pk  = (unsigned int*)alloc((size_t)TT * 10 * FF * 4);
  float* biasc   = (float*)alloc((size_t)TT * FF * 4);
  int*   bsum    = (int*)alloc((size_t)SCAN_B * 4);
  int*   boff    = (int*)alloc((size_t)SCAN_B * 4);
  int*   gcnt    = (int*)alloc((size_t)GG * 4);
  int*   gstart  = (int*)alloc((size_t)(GG + 1) * 4);
  unsigned short* aggbuf = (unsigned short*)alloc((size_t)NN * 4 * 80 * 2); // 32 MB bf16
  (void)in_sizes; (void)n_in; (void)out_size; (void)ws_size;

  hipMemsetAsync(cnt, 0, (size_t)NN * 4, stream);
  k_h<<<(NN * DD + 255) / 256, 256, 0, stream>>>(x, atom_emb, h);
  k_deg<<<(EE + 255) / 256, 256, 0, stream>>>(ei, cnt);
  k_scan_sum<<<SCAN_B, 1024, 0, stream>>>(cnt, bsum);
  k_scan_top<<<1, 64, 0, stream>>>(bsum, boff, row_ptr);
  k_scan_apply<<<SCAN_B, 1024, 0, stream>>>(cnt, boff, row_ptr, cursor);
  k_csrfill<<<(EE + 255) / 256, 256, 0, stream>>>(ei, cursor, csr_src, csr_eid, csr_dst);
  k_eagather<<<(EE + 255) / 256, 256, 0, stream>>>(csr_eid, edge_attr, ea16);
  k_nodeparams<<<(NN + 255) / 256, 256, 0, stream>>>(cnt, inv_deg, s1a, s2a);

  int tilesA = (NN + TILE_N - 1) / TILE_N;   // 3125
  int blocksPL = (NN + 63) / 64;             // 782
  for (int l = 0; l < LL; ++l) {
    k_wcomb<<<TT, 64, 0, stream>>>(edge_w, edge_b, pre_w1, pre_b1, pre_w2,
        post_w1, post_w2, wcpk, w2pk, q1pk, q2pk, biasc, colsum, l);
    k_prenode<<<(NN + 63) / 64, 256, 0, stream>>>(h, pre_w1, biasc, predD, predS, l);
    k_preagg<<<tilesA, 256, 0, stream>>>(predD, predS, ea16, csr_src, csr_dst, row_ptr,
        inv_deg, wcpk, w2pk, pre_b2, aggbuf, l);
    k_postlin<<<blocksPL, 256, 0, stream>>>(h, aggbuf, s1a, s2a,
        post_w1, post_b1, q1pk, q2pk, post_b2, lin_w, lin_b, outl, colsum, l);
    k_bnapply<<<(NN * DD + 255) / 256, 256, 0, stream>>>(outl, colsum, bn_g, bn_b, h, l);
  }

  hipMemsetAsync(gcnt, 0, (size_t)GG * 4, stream);
  k_gcnt<<<(NN + 255) / 256, 256, 0, stream>>>(batch, gcnt);
  k_gstart<<<1, 64, 0, stream>>>(gcnt, gstart);
  k_gmean<<<GG, 320, 0, stream>>>(h, gstart, gcnt, gbuf);
  k_mlp<<<GG, 64, 0, stream>>>(gbuf, mlp_w1, mlp_b1, mlp_w2, mlp_b2, mlp_w3, mlp_b3, out);
}